// Round 10
// baseline (488.916 us; speedup 1.0000x reference)
//
#include <hip/hip_runtime.h>
#include <hip/hip_bf16.h>
#include <cstddef>

typedef __hip_bfloat16 bf16;
typedef __attribute__((ext_vector_type(8))) short short8;
typedef __attribute__((ext_vector_type(4))) float float4v;
typedef __attribute__((ext_vector_type(4))) unsigned short ushort4v;

static __device__ __forceinline__ float b2f(bf16 v) { return __bfloat162float(v); }
static __device__ __forceinline__ float bits2f(unsigned int u) { return __uint_as_float(u); }
static __device__ __forceinline__ unsigned short f2bfbits(float f) {
  bf16 h = __float2bfloat16(f);
  return *reinterpret_cast<unsigned short*>(&h);
}
static __device__ __forceinline__ float ld_any(const void* p, long i, int flag) {
  return flag ? b2f(((const bf16*)p)[i]) : ((const float*)p)[i];
}
static __device__ __forceinline__ void unpack_u4(uint4 u, float* f) {
  f[0] = bits2f(u.x << 16); f[1] = bits2f(u.x & 0xffff0000u);
  f[2] = bits2f(u.y << 16); f[3] = bits2f(u.y & 0xffff0000u);
  f[4] = bits2f(u.z << 16); f[5] = bits2f(u.z & 0xffff0000u);
  f[6] = bits2f(u.w << 16); f[7] = bits2f(u.w & 0xffff0000u);
}

// --------------------------------- dtype detection (+ loss accumulator zero)
__global__ void detect_dtype_kernel(const void* __restrict__ x, int* __restrict__ flag,
                                    float* __restrict__ lacc) {
  if (threadIdx.x < 2) lacc[threadIdx.x] = 0.f;
  __shared__ int ok;
  if (threadIdx.x == 0) ok = 1;
  __syncthreads();
  float v = b2f(((const bf16*)x)[threadIdx.x]);
  if (!(v >= 0.f && v <= 1.0009765625f)) ok = 0;
  __syncthreads();
  if (threadIdx.x == 0) *flag = ok;
}

// ------------------------------------------------- halo-ring zeroing helper
static __device__ __forceinline__ void halo_seg(bf16* p0, bf16* p1, bf16* p2,
                                                int np, int H, int W, int C8,
                                                long imgS, int gpi, int r) {
  int total = 16 * gpi;
  int which = r / total;
  if (which >= np) return;
  int rr = r - which * total;
  int img = rr / gpi, g = rr % gpi;
  int pos = g / C8, c8 = g % C8;
  int row, col;
  if (pos < W) { row = 0; col = pos; }
  else if (pos < 2 * W) { row = H - 1; col = pos - W; }
  else { int s = pos - 2 * W; row = 1 + (s >> 1); col = (s & 1) ? (W - 1) : 0; }
  bf16* base = (which == 0) ? p0 : ((which == 1) ? p1 : p2);
  uint4* dst = (uint4*)(base + (long)img * imgS + ((long)row * W + col) * (C8 * 8) + (long)c8 * 8);
  *dst = uint4{0u, 0u, 0u, 0u};
}

// ---------------- all converts / repacks + halo zeroing in one kernel.
// seg0 (sqAll) is wave-parallel: one 64-lane wave per codebook row.
__global__ __launch_bounds__(256) void setup_all(
    const void* s2, const void* s4, const void* s6,
    const void* s10, const void* s12, const void* s14,
    const void* sT, const void* sB, const void* c1s,
    const void* fins, const void* d1s, const void* t2s,
    const void* tts, const void* dts,
    float* __restrict__ biasAll, bf16* __restrict__ embTB,
    float* __restrict__ sqAll, bf16* __restrict__ Wc1,
    bf16* __restrict__ Wfin, bf16* __restrict__ Wd1f,
    bf16* __restrict__ Wt2f, bf16* __restrict__ Wttf,
    bf16* __restrict__ Wdtf, const int* __restrict__ flag,
    bf16* act1p, bf16* hp, bf16* zbp, bf16* eup, bf16* fqp, bf16* zqtp) {
  long i = (long)blockIdx.x * 256 + threadIdx.x;
  const int fl = *flag;
  // seg0: emb row sum-of-squares, wave-parallel [65536 = 1024 rows x 64 lanes]
  if (i < 65536) {
    int k = (int)(i >> 6), lane = (int)(i & 63);
    const void* s = (k < 512) ? sT : sB;
    long base = (long)(k & 511) * 128 + lane * 2;
    float v0 = b2f(__float2bfloat16(ld_any(s, base, fl)));
    float v1 = b2f(__float2bfloat16(ld_any(s, base + 1, fl)));
    float acc = fmaf(v1, v1, v0 * v0);
    #pragma unroll
    for (int o = 32; o > 0; o >>= 1) acc += __shfl_down(acc, o, 64);
    if (lane == 0) sqAll[k] = acc;
    return;
  }
  i -= 65536;
  // seg1: 6 conv biases -> one fp32 buffer [515]
  if (i < 515) {
    const void* s; long off;
    if (i < 64)       { s = s2;  off = i; }
    else if (i < 192) { s = s4;  off = i - 64; }
    else if (i < 320) { s = s6;  off = i - 192; }
    else if (i < 448) { s = s10; off = i - 320; }
    else if (i < 512) { s = s12; off = i - 448; }
    else              { s = s14; off = i - 512; }
    biasAll[i] = ld_any(s, off, fl);
    return;
  }
  i -= 515;
  // seg2: both codebooks -> contiguous bf16 [1024][128]
  if (i < 131072) {
    const void* s = (i < 65536) ? sT : sB;
    long off = i & 65535;
    embTB[i] = fl ? ((const bf16*)s)[off] : __float2bfloat16(((const float*)s)[off]);
    return;
  }
  i -= 131072;
  // seg3: conv1 weights [64][3][4][4] -> [co][k], K padded 48->64 [4096]
  if (i < 4096) {
    int co = (int)i >> 6, k = (int)i & 63;
    float v = (k < 48) ? ld_any(c1s, co * 48 + k, fl) : 0.f;
    Wc1[i] = __float2bfloat16(v);
    return;
  }
  i -= 4096;
  // seg4: final convT weights -> A[m=cls*4+co][d=dy*3+dx][64ci] [9216]
  if (i < 9216) {
    int m = (int)i / 576, rem = (int)i % 576;
    int d = rem >> 6, ci = rem & 63;
    int cls = m >> 2, co = m & 3;
    int p = cls >> 1, q = cls & 1;
    int dy = d / 3, dx = d % 3;
    int s_ = p - dy + 1, t_ = q - dx + 1;
    float v = 0.f;
    if (co < 3 && s_ >= 0 && s_ <= 1 && t_ >= 0 && t_ <= 1) {
      int kh = 2 * s_ + 1 - p, kw = 2 * t_ + 1 - q;
      v = ld_any(fins, ci * 48 + co * 16 + kh * 4 + kw, fl);
    }
    Wfin[i] = __float2bfloat16(v);
    return;
  }
  i -= 9216;
  // seg5: d1 weights [256ci][64co][4][4] -> frag [262144]
  if (i < 262144) {
    int low = (int)i & 511;
    int ln = low >> 5, cl = low & 31;
    int c2 = (int)(i >> 9);
    int j = c2 & 3;
    int kc = (c2 >> 2) & 7;
    int t = (c2 >> 5) & 3;
    int cls = c2 >> 7;
    int p = cls >> 1, q = cls & 1;
    int s_ = t >> 1, t2 = t & 1;
    int kh = 2 * s_ + 1 - p, kw = 2 * t2 + 1 - q;
    int co = j * 16 + ln, ci = kc * 32 + cl;
    Wd1f[i] = __float2bfloat16(ld_any(d1s, (long)ci * 1024 + co * 16 + kh * 4 + kw, fl));
    return;
  }
  i -= 262144;
  // seg6: conv2 weights OIHW[128][64][4][4] -> frag direct (MC=4,KC=2) [131072]
  if (i < 131072) {
    int low = (int)i & 511;
    int ln = low >> 5, cl = low & 31;
    int c2 = (int)(i >> 9);
    int j = c2 & 1, c3 = c2 >> 1;
    int kc = c3 & 1, c4 = c3 >> 1;
    int mc = c4 & 3, tg = c4 >> 2;
    int co = mc * 32 + j * 16 + ln, ci = kc * 32 + cl;
    Wt2f[i] = __float2bfloat16(ld_any(t2s, (long)co * 1024 + ci * 16 + tg, fl));
    return;
  }
  i -= 131072;
  // seg7: conv_t weights OIHW[128][128][4][4] -> frag direct (MC=4,KC=4) [262144]
  if (i < 262144) {
    int low = (int)i & 511;
    int ln = low >> 5, cl = low & 31;
    int c2 = (int)(i >> 9);
    int j = c2 & 1, c3 = c2 >> 1;
    int kc = c3 & 3, c4 = c3 >> 2;
    int mc = c4 & 3, tg = c4 >> 2;
    int co = mc * 32 + j * 16 + ln, ci = kc * 32 + cl;
    Wttf[i] = __float2bfloat16(ld_any(tts, (long)co * 2048 + ci * 16 + tg, fl));
    return;
  }
  i -= 262144;
  // seg8: convT dt weights [128ci][128co][4][4] -> class frag direct [262144]
  if (i < 262144) {
    int low = (int)i & 511;
    int ln = low >> 5, cl = low & 31;
    int c2 = (int)(i >> 9);
    int j = c2 & 1, c3 = c2 >> 1;
    int kc = c3 & 3, c4 = c3 >> 2;
    int mc = c4 & 3, tg = c4 >> 2;
    int co = mc * 32 + j * 16 + ln, ci = kc * 32 + cl;
    int cls = tg >> 2, st = tg & 3;
    int p = cls >> 1, q = cls & 1;
    int s_ = st >> 1, tt_ = st & 1;
    int kh = 2 * s_ + 1 - p, kw = 2 * tt_ + 1 - q;
    Wdtf[i] = __float2bfloat16(ld_any(dts, (long)ci * 2048 + co * 16 + kh * 4 + kw, fl));
    return;
  }
  i -= 262144;
  // seg9-11: halo-ring zeroing (independent of flag)
  if (i < 132096) { halo_seg(act1p, hp, nullptr, 2, 130, 130, 8, 1081600, 4128, (int)i); return; }
  i -= 132096;
  if (i < 199680) { halo_seg(zbp, eup, fqp, 3, 66, 66, 16, 557568, 4160, (int)i); return; }
  i -= 199680;
  if (i < 33792)  { halo_seg(zqtp, nullptr, nullptr, 1, 34, 34, 16, 147968, 2112, (int)i); }
}

// -------------------- conv1: LDS-staged im2col + MFMA GEMM.
__global__ __launch_bounds__(256) void gemm1_lds(
    const void* __restrict__ x, const int* __restrict__ flag,
    const bf16* __restrict__ w, const float* __restrict__ bias,
    bf16* __restrict__ act1p) {
  __shared__ unsigned short xs[3 * 4 * 260];   // [ci][r][px], px = iw+1
  const int lane = threadIdx.x & 63, wv = threadIdx.x >> 6;
  const int wm = wv & 1, wn = wv >> 1;
  const int ln = lane & 15, quad = lane >> 4;
  const int n0 = blockIdx.x * 128;
  const int oh = (n0 >> 7) & 127, b = n0 >> 14;
  const int fl = *flag;
  const int ih0 = 2 * oh - 1;

  for (int i = threadIdx.x; i < 3120; i += 256) {
    int px = i % 260;
    int t = i / 260;
    int r = t & 3, ci = t >> 2;
    int ih = ih0 + r;
    int iw = px - 1;
    float v = ((unsigned)ih < 256u && (unsigned)iw < 256u)
                ? ld_any(x, (((long)(b * 3 + ci)) << 16) + ((long)ih << 8) + iw, fl) : 0.f;
    xs[i] = f2bfbits(v);
  }
  __syncthreads();

  float4v acc[2][4];
  #pragma unroll
  for (int i = 0; i < 2; ++i)
    #pragma unroll
    for (int j = 0; j < 4; ++j) acc[i][j] = {0.f, 0.f, 0.f, 0.f};

  const int ow_base = wn * 64;
  #pragma unroll
  for (int kc = 0; kc < 2; ++kc) {
    const bf16* wk = w + (wm * 32 + ln) * 64 + kc * 32 + quad * 8;
    short8 a0 = *(const short8*)(wk);
    short8 a1 = *(const short8*)(wk + 16 * 64);
    const int k0 = kc * 32 + quad * 8;      // 0,8,...,56; >=48 is zero-pad
    const int ci = k0 >> 4;
    const int kh0 = (k0 & 15) >> 2;         // 0 or 2
    #pragma unroll
    for (int bf = 0; bf < 4; ++bf) {
      short8 bv;
      if (k0 >= 48) {
        bv = (short8){0, 0, 0, 0, 0, 0, 0, 0};
      } else {
        int ow = ow_base + bf * 16 + ln;
        union { uint2 u2[2]; short8 s8; } u;
        u.u2[0] = *(const uint2*)(xs + (ci * 4 + kh0) * 260 + ow * 2);
        u.u2[1] = *(const uint2*)(xs + (ci * 4 + kh0 + 1) * 260 + ow * 2);
        bv = u.s8;
      }
      acc[0][bf] = __builtin_amdgcn_mfma_f32_16x16x32_bf16(a0, bv, acc[0][bf], 0, 0, 0);
      acc[1][bf] = __builtin_amdgcn_mfma_f32_16x16x32_bf16(a1, bv, acc[1][bf], 0, 0, 0);
    }
  }
  #pragma unroll
  for (int mf = 0; mf < 2; ++mf) {
    int coB = wm * 32 + mf * 16 + quad * 4;
    float4v bv4 = *(const float4v*)(bias + coB);
    #pragma unroll
    for (int bf = 0; bf < 4; ++bf) {
      int ow = ow_base + bf * 16 + ln;
      int xx = ow + 1;   // parity-split column
      long oaddr = ((long)(b * 130 + oh + 1)) * 8320 +
                   (long)(((xx & 1) * 65) + (xx >> 1)) * 64 + coB;
      float4v v = acc[mf][bf];
      ushort4v o;
      #pragma unroll
      for (int e = 0; e < 4; ++e) o[e] = f2bfbits(fmaxf(v[e] + bv4[e], 0.f));
      *(ushort4v*)(act1p + oaddr) = o;
    }
  }
}

// ------------------------------------------- MFMA implicit-GEMM tap conv
template <int COUT, int CINT, int TC, int S, int NT, int INC, int NBF, int PXW>
__global__ __launch_bounds__(256) void mfma_conv(
    const bf16* __restrict__ in1, const bf16* __restrict__ in2,
    long inImgS, int inRowS,
    const bf16* __restrict__ wf, const float* __restrict__ bias,
    bf16* __restrict__ outp, long outImgS, int oRS, int oCS,
    int nxb, long po, long qo, int oPXW) {
  constexpr int TR = (2 * NBF * 16) / TC;
  constexpr int KC = CINT / 32;
  constexpr int MC = COUT / 32;
  constexpr int KSPLIT = (CINT > INC) ? (INC / 32) : KC;
  const int lane = threadIdx.x & 63;
  const int wv = threadIdx.x >> 6;
  const int wm = wv & 1, wn = wv >> 1;
  const int ln = lane & 15, quad = lane >> 4;
  const int cls = blockIdx.x >> nxb;
  const int xb = blockIdx.x & ((1u << nxb) - 1u);
  const int mTile = blockIdx.y * 64;
  const int mc = blockIdx.y * 2 + wm;
  const int oh0 = xb * TR;
  const int b = blockIdx.z;
  const int p = cls >> 1, q = cls & 1;
  const long ooff = (long)(p + 1) * po + (long)(q + 1) * qo;

  long posOff[NBF];
  int rr[NBF], cc[NBF];
  #pragma unroll
  for (int bf = 0; bf < NBF; ++bf) {
    int n = wn * (NBF * 16) + bf * 16 + ln;
    int r = n / TC, c = n % TC;
    rr[bf] = r; cc[bf] = c;
    posOff[bf] = (long)(S * (oh0 + r)) * inRowS +
                 (PXW ? (long)c * INC : (long)(S * c) * INC);
  }
  const bf16* inb1 = in1 + (long)b * inImgS;
  const bf16* inb2 = in2 + (long)b * inImgS;

  float4v acc[2][NBF];
  #pragma unroll
  for (int i = 0; i < 2; ++i)
    #pragma unroll
    for (int j = 0; j < NBF; ++j) acc[i][j] = {0.f, 0.f, 0.f, 0.f};

  for (int t = 0; t < NT; ++t) {
    int dy, dx;
    if (S == 2) { dy = t >> 2; dx = t & 3; }
    else        { dy = p - (t >> 1) + 1; dx = q - (t & 1) + 1; }
    const int dxo = PXW ? ((dx & 1) * PXW + (dx >> 1)) : dx;
    const long tapOff = (long)dy * inRowS + (long)dxo * INC;
    const bf16* wt = wf + ((long)(cls * NT + t) * MC + mc) * (KC * 1024) + ln * 32 + quad * 8;
    #pragma unroll
    for (int kc = 0; kc < KC; ++kc) {
      short8 a0 = *(const short8*)(wt + kc * 1024);
      short8 a1 = *(const short8*)(wt + kc * 1024 + 512);
      const bf16* bp = (kc < KSPLIT) ? inb1 : inb2;
      int kOff = (kc < KSPLIT ? kc : kc - KSPLIT) * 32 + quad * 8;
      #pragma unroll
      for (int bf = 0; bf < NBF; ++bf) {
        short8 bv = *(const short8*)(bp + posOff[bf] + tapOff + kOff);
        acc[0][bf] = __builtin_amdgcn_mfma_f32_16x16x32_bf16(a0, bv, acc[0][bf], 0, 0, 0);
        acc[1][bf] = __builtin_amdgcn_mfma_f32_16x16x32_bf16(a1, bv, acc[1][bf], 0, 0, 0);
      }
    }
  }

  bf16* outb = outp + (long)b * outImgS + ooff;
  #pragma unroll
  for (int mf = 0; mf < 2; ++mf) {
    int coB = mTile + wm * 32 + mf * 16 + quad * 4;
    float4v bv4 = *(const float4v*)(bias + coB);
    #pragma unroll
    for (int bf = 0; bf < NBF; ++bf) {
      float4v v = acc[mf][bf];
      ushort4v o;
      #pragma unroll
      for (int e = 0; e < 4; ++e)
        o[e] = f2bfbits(fmaxf(v[e] + bv4[e], 0.f));
      long coff = oPXW ? (long)((((cc[bf] + 1) & 1) * oPXW) + ((cc[bf] + 1) >> 1)) * oCS
                       : (long)cc[bf] * oCS;
      long oaddr = (long)(oh0 + rr[bf]) * oRS + coff + oCS * 0 + coB;
      *(ushort4v*)(outb + oaddr) = o;
    }
  }
}

// ---------- conv2 (64 -> 128, s2): LDS-staged + T14, 4 waves (co-quartered)
__global__ __launch_bounds__(256) void conv2_lds(
    const bf16* __restrict__ in, const bf16* __restrict__ wf,
    const float* __restrict__ bias, bf16* __restrict__ outp) {
  __shared__ short8 lds8[2 * 130 * 9];   // 37440 B
  const int lane = threadIdx.x & 63;
  const int w = threadIdx.x >> 6;        // co-quarter (wave id, mc=w)
  const int ln = lane & 15, quad = lane >> 4;
  const int oh = blockIdx.x;             // output row 0..63
  const int b = blockIdx.z;

  const bf16* img = in + (long)b * 1081600;
  const short8* s0 = (const short8*)(img + (long)(2 * oh) * 8320);      // rows 2oh,2oh+1
  const short8* s1 = (const short8*)(img + (long)(2 * oh + 2) * 8320);  // rows 2oh+2,2oh+3

  float4v acc[2][4];   // [j (16-co frag)][bf (pos chunk)]
  #pragma unroll
  for (int j = 0; j < 2; ++j)
    #pragma unroll
    for (int bf = 0; bf < 4; ++bf) acc[j][bf] = {0.f, 0.f, 0.f, 0.f};

  auto compute = [&](int f) {
    #pragma unroll
    for (int tl = 0; tl < 8; ++tl) {
      const int t = 8 * f + tl;
      const int r = (t >> 2) & 1;        // row within phase
      const int dx = t & 3;
      const int pp = dx & 1, cb = dx >> 1;
      const int lbase = (r * 130 + pp * 65 + cb) * 9 + quad;
      #pragma unroll
      for (int kc = 0; kc < 2; ++kc) {
        const bf16* wk = wf + (long)((t * 4 + w) * 2 + kc) * 1024 + ln * 32 + quad * 8;
        short8 a0 = *(const short8*)(wk);          // j=0
        short8 a1 = *(const short8*)(wk + 512);    // j=1
        #pragma unroll
        for (int bf = 0; bf < 4; ++bf) {
          short8 bv = lds8[lbase + (bf * 16 + ln) * 9 + kc * 4];
          acc[0][bf] = __builtin_amdgcn_mfma_f32_16x16x32_bf16(a0, bv, acc[0][bf], 0, 0, 0);
          acc[1][bf] = __builtin_amdgcn_mfma_f32_16x16x32_bf16(a1, bv, acc[1][bf], 0, 0, 0);
        }
      }
    }
  };

  // stage phase 0 directly
  for (int i = threadIdx.x; i < 2080; i += 256) {   // 2 rows x 130 pos x 8
    lds8[(i >> 3) * 9 + (i & 7)] = s0[i];
  }
  // T14: issue phase-1 loads now (9 x 16B regs); latency hides under compute(0)
  short8 pre[9];
  #pragma unroll
  for (int it = 0; it < 9; ++it) {
    int i = threadIdx.x + it * 256;
    if (i < 2080) pre[it] = s1[i];
  }
  __syncthreads();
  compute(0);
  __syncthreads();
  #pragma unroll
  for (int it = 0; it < 9; ++it) {
    int i = threadIdx.x + it * 256;
    if (i < 2080) lds8[(i >> 3) * 9 + (i & 7)] = pre[it];
  }
  __syncthreads();
  compute(1);

  // store: zbp parity layout, row oh+1, col map x -> ((x+1)&1)*33 + ((x+1)>>1)
  bf16* outb = outp + (long)b * 557568 + (long)(oh + 1) * 8448;
  #pragma unroll
  for (int j = 0; j < 2; ++j) {
    int co = w * 32 + j * 16 + quad * 4;
    float4v bv4 = *(const float4v*)(bias + co);
    #pragma unroll
    for (int bf = 0; bf < 4; ++bf) {
      int x = bf * 16 + ln;
      int col = (((x + 1) & 1) * 33) + ((x + 1) >> 1);
      float4v v = acc[j][bf];
      ushort4v o;
      #pragma unroll
      for (int e = 0; e < 4; ++e)
        o[e] = f2bfbits(fmaxf(v[e] + bv4[e], 0.f));
      *(ushort4v*)(outb + (long)col * 128 + co) = o;
    }
  }
}

// ------ d1 (concat 256 -> 64): 8-wave blocks, wave = (class, row). Frozen.
__global__ __launch_bounds__(512) void mfma_d1_lds(
    const bf16* __restrict__ in1, const bf16* __restrict__ in2,
    const bf16* __restrict__ wf, const float* __restrict__ bias,
    bf16* __restrict__ outp) {
  __shared__ short8 lds8[264 * 17];   // 4 rows x 66 pos x 16 chunks, pad 17
  const int lane = threadIdx.x & 63, wv = threadIdx.x >> 6;   // 0..7
  const int ln = lane & 15, quad = lane >> 4;
  const int r0 = blockIdx.x * 2;     // output class-rows r0, r0+1
  const int b = blockIdx.z;
  const int cls = wv & 3, rr = wv >> 2;   // wave = (class, row)
  const int p = cls >> 1, q = cls & 1;

  const bf16* src1 = in1 + (long)b * 557568 + (long)r0 * 8448;  // rows r0..r0+3
  const bf16* src2 = in2 + (long)b * 557568 + (long)r0 * 8448;

  float4v acc[4][4];
  #pragma unroll
  for (int j = 0; j < 4; ++j)
    #pragma unroll
    for (int bf = 0; bf < 4; ++bf) acc[j][bf] = {0.f, 0.f, 0.f, 0.f};

  auto compute = [&](int phase) {
    #pragma unroll
    for (int t = 0; t < 4; ++t) {
      int dy = p - (t >> 1) + 1, dx = q - (t & 1) + 1;
      const bf16* wt = wf + (long)(cls * 4 + t) * 16384 + (long)(phase * 4) * 2048 +
                       ln * 32 + quad * 8;
      const int lbase = ((rr + dy) * 66 + dx) * 17 + quad;
      #pragma unroll
      for (int kc = 0; kc < 4; ++kc) {
        const bf16* wk = wt + kc * 2048;
        short8 a0 = *(const short8*)(wk);
        short8 a1 = *(const short8*)(wk + 512);
        short8 a2 = *(const short8*)(wk + 1024);
        short8 a3 = *(const short8*)(wk + 1536);
        #pragma unroll
        for (int bf = 0; bf < 4; ++bf) {
          short8 bv = lds8[lbase + kc * 4 + (bf * 16 + ln) * 17];
          acc[0][bf] = __builtin_amdgcn_mfma_f32_16x16x32_bf16(a0, bv, acc[0][bf], 0, 0, 0);
          acc[1][bf] = __builtin_amdgcn_mfma_f32_16x16x32_bf16(a1, bv, acc[1][bf], 0, 0, 0);
          acc[2][bf] = __builtin_amdgcn_mfma_f32_16x16x32_bf16(a2, bv, acc[2][bf], 0, 0, 0);
          acc[3][bf] = __builtin_amdgcn_mfma_f32_16x16x32_bf16(a3, bv, acc[3][bf], 0, 0, 0);
        }
      }
    }
  };

  // stage phase 0 (fqp): 264 pos x 16 chunks with 512 threads
  for (int i = threadIdx.x; i < 4224; i += 512) {
    lds8[(i >> 4) * 17 + (i & 15)] = *(const short8*)(src1 + (long)(i >> 4) * 128 + (i & 15) * 8);
  }
  // T14: issue phase-1 (eup) loads now; latency hides under compute(0)
  short8 pre[9];
  #pragma unroll
  for (int it = 0; it < 9; ++it) {
    int i = threadIdx.x + it * 512;
    if (i < 4224) pre[it] = *(const short8*)(src2 + (long)(i >> 4) * 128 + (i & 15) * 8);
  }
  __syncthreads();
  compute(0);
  __syncthreads();
  #pragma unroll
  for (int it = 0; it < 9; ++it) {
    int i = threadIdx.x + it * 512;
    if (i < 4224) lds8[(i >> 4) * 17 + (i & 15)] = pre[it];
  }
  __syncthreads();
  compute(1);

  bf16* outb = outp + (long)b * 1081600 + (long)(p + 1) * 8320 + (long)(q + 1) * 64 +
               (long)(r0 + rr) * 16640;
  #pragma unroll
  for (int j = 0; j < 4; ++j) {
    int co = j * 16 + quad * 4;
    float4v bv4 = *(const float4v*)(bias + co);
    #pragma unroll
    for (int bf = 0; bf < 4; ++bf) {
      float4v v = acc[j][bf];
      ushort4v o;
      #pragma unroll
      for (int e = 0; e < 4; ++e)
        o[e] = f2bfbits(fmaxf(v[e] + bv4[e], 0.f));
      *(ushort4v*)(outb + (long)(bf * 16 + ln) * 128 + co) = o;
    }
  }
}

// ---------- VQ, 16 positions/wave (full-chip grid); ipxw = parity input.
// Wave handles 16 positions (one B fragment); quads split the code subsets;
// cross-quad shuffle reduce; copy/loss split 4 chunks/lane.
__global__ __launch_bounds__(256) void vq_mfma16(
    const bf16* __restrict__ z, long zImgS, int zRowS,
    const bf16* __restrict__ emb, const float* __restrict__ embsq,
    bf16* __restrict__ zq, long qImgS, int qRowS,
    float* __restrict__ loss_acc, int wb, int hwb, int ipxw) {
  const int lane = threadIdx.x & 63, wv = threadIdx.x >> 6;
  const int ln = lane & 15, quad = lane >> 4;
  const int base = blockIdx.x * 64 + wv * 16;   // 16 positions per wave

  const int n = base + ln;
  const int b = n >> hwb;
  const int rem = n & ((1 << hwb) - 1);
  const int y = rem >> wb, x = rem & ((1 << wb) - 1);
  const int xcol = ipxw ? ((((x + 1) & 1) * ipxw) + ((x + 1) >> 1)) : x;
  const bf16* zrow = z + (long)b * zImgS + (long)y * zRowS + (long)xcol * 128;
  short8 bfrag[4];
  #pragma unroll
  for (int kc = 0; kc < 4; ++kc)
    bfrag[kc] = *(const short8*)(zrow + kc * 32 + quad * 8);

  float best = 3.4e38f;
  int bk = 0;
  for (int ct = 0; ct < 32; ++ct) {
    const bf16* erow = emb + (long)(ct * 16 + ln) * 128 + quad * 8;
    short8 a0 = *(const short8*)(erow);
    short8 a1 = *(const short8*)(erow + 32);
    short8 a2 = *(const short8*)(erow + 64);
    short8 a3 = *(const short8*)(erow + 96);
    float4v sq4 = *(const float4v*)(embsq + ct * 16 + quad * 4);
    float4v acc = {0.f, 0.f, 0.f, 0.f};
    acc = __builtin_amdgcn_mfma_f32_16x16x32_bf16(a0, bfrag[0], acc, 0, 0, 0);
    acc = __builtin_amdgcn_mfma_f32_16x16x32_bf16(a1, bfrag[1], acc, 0, 0, 0);
    acc = __builtin_amdgcn_mfma_f32_16x16x32_bf16(a2, bfrag[2], acc, 0, 0, 0);
    acc = __builtin_amdgcn_mfma_f32_16x16x32_bf16(a3, bfrag[3], acc, 0, 0, 0);
    int kb = ct * 16 + quad * 4;
    #pragma unroll
    for (int r = 0; r < 4; ++r) {
      float s = fmaf(-2.f, acc[r], sq4[r]);
      if (s < best) { best = s; bk = kb + r; }
    }
  }
  // reduce across quads (lanes sharing ln)
  #pragma unroll
  for (int m = 16; m <= 32; m <<= 1) {
    float os = __shfl_xor(best, m, 64);
    int ok = __shfl_xor(bk, m, 64);
    if (os < best || (os == best && ok < bk)) { best = os; bk = ok; }
  }
  // copy + loss: quads split the 16 uint4 chunks of position n
  const uint4* zr = (const uint4*)zrow;
  uint4* qr = (uint4*)(zq + (long)b * qImgS + (long)y * qRowS + (long)x * 128);
  const uint4* er = (const uint4*)(emb + (long)bk * 128);
  float lsum = 0.f;
  #pragma unroll
  for (int t = 0; t < 4; ++t) {
    int j = quad * 4 + t;
    uint4 ue = er[j];
    uint4 uz = zr[j];
    qr[j] = ue;
    float ev[8], zv[8];
    unpack_u4(ue, ev);
    unpack_u4(uz, zv);
    #pragma unroll
    for (int e = 0; e < 8; ++e) {
      float dv = ev[e] - zv[e];
      lsum = fmaf(dv, dv, lsum);
    }
  }
  for (int o = 32; o > 0; o >>= 1) lsum += __shfl_down(lsum, o, 64);
  if (lane == 0) atomicAdd(loss_acc, lsum);
}

// --------------------- final convT(64->3)+sigmoid via class-packed MFMA
__global__ __launch_bounds__(256) void final_convt_mfma(
    const bf16* __restrict__ hp, const bf16* __restrict__ wfin,
    const float* __restrict__ bf_, float* __restrict__ out) {
  const int lane = threadIdx.x & 63, wv = threadIdx.x >> 6;
  const int ln = lane & 15, quad = lane >> 4;
  const int base = blockIdx.x * 256 + wv * 64;   // 262144 positions total

  short8 afr[18];
  #pragma unroll
  for (int kc = 0; kc < 18; ++kc)
    afr[kc] = *(const short8*)(wfin + ln * 576 + kc * 32 + quad * 8);

  float4v acc[4];
  #pragma unroll
  for (int bf = 0; bf < 4; ++bf) acc[bf] = {0.f, 0.f, 0.f, 0.f};

  #pragma unroll
  for (int bf = 0; bf < 4; ++bf) {
    int n = base + bf * 16 + ln;
    int xx = n & 127, y = (n >> 7) & 127, b = n >> 14;
    const bf16* hb = hp + (long)b * 1081600 + (long)y * 8320 + (long)xx * 64;
    #pragma unroll
    for (int kc = 0; kc < 18; ++kc) {
      int d = kc >> 1;
      const bf16* bp = hb + (long)(d / 3) * 8320 + (d % 3) * 64 + (kc & 1) * 32 + quad * 8;
      short8 bv = *(const short8*)bp;
      acc[bf] = __builtin_amdgcn_mfma_f32_16x16x32_bf16(afr[kc], bv, acc[bf], 0, 0, 0);
    }
  }

  const int p = quad >> 1, q = quad & 1;
  float b0 = bf_[0], b1 = bf_[1], b2 = bf_[2];
  #pragma unroll
  for (int bf = 0; bf < 4; ++bf) {
    int n = base + bf * 16 + ln;
    int xx = n & 127, y = (n >> 7) & 127, b = n >> 14;
    long ob = (long)b * 196608 + (long)(2 * y + p) * 256 + (2 * xx + q);
    float v0 = acc[bf][0] + b0, v1 = acc[bf][1] + b1, v2 = acc[bf][2] + b2;
    out[ob]          = 1.f / (1.f + expf(-v0));
    out[ob + 65536]  = 1.f / (1.f + expf(-v1));
    out[ob + 131072] = 1.f / (1.f + expf(-v2));
  }
}

__global__ void finalize_loss_kernel(const float* __restrict__ lacc, float* __restrict__ out) {
  if (threadIdx.x == 0) {
    float lt = lacc[0] * (1.5f / 2097152.f);
    float lb = lacc[1] * (1.5f / 8388608.f);
    *out = lt + lb;
  }
}

// ------------------------------------------------------------------ launch
extern "C" void kernel_launch(void* const* d_in, const int* in_sizes, int n_in,
                              void* d_out, int out_size, void* d_ws, size_t ws_size,
                              hipStream_t stream) {
  float* out = (float*)d_out;
  char* base = (char*)d_ws;
  size_t off = 0;
  auto alloc = [&](size_t bytes) {
    void* pp = base + off;
    off = (off + bytes + 255) & ~(size_t)255;
    return pp;
  };

  int* flag = (int*)alloc(256);
  float* biasAll = (float*)alloc(515 * 4);
  float* beB1f = biasAll + 0;
  float* beB2f = biasAll + 64;
  float* beTf  = biasAll + 192;
  float* bdTf  = biasAll + 320;
  float* bd1f  = biasAll + 448;
  float* bd2f  = biasAll + 512;
  float* sqAll = (float*)alloc(1024 * 4);
  float* sqT = sqAll, *sqB = sqAll + 512;
  float* lacc = (float*)alloc(2 * 4);
  bf16* Wc1  = (bf16*)alloc((size_t)4096 * 2);
  bf16* Wt2f = (bf16*)alloc((size_t)131072 * 2);
  bf16* Wttf = (bf16*)alloc((size_t)262144 * 2);
  bf16* Wdtf = (bf16*)alloc((size_t)262144 * 2);
  bf16* Wd1f = (bf16*)alloc((size_t)262144 * 2);
  bf16* Wfin = (bf16*)alloc((size_t)9216 * 2);
  bf16* embTB = (bf16*)alloc((size_t)131072 * 2);
  bf16* embT = embTB, *embB = embTB + 65536;
  bf16* act1p = (bf16*)alloc((size_t)17305600 * 2);  // [16][130][2][65][64] parity
  bf16* zbp   = (bf16*)alloc((size_t)8921088 * 2);   // [16][66][2][33][128] parity
  bf16* zqtp  = (bf16*)alloc((size_t)2367488 * 2);   // [16][34][34][128]
  bf16* eup   = (bf16*)alloc((size_t)8921088 * 2);   // [16][66][66][128]
  bf16* fqp   = (bf16*)alloc((size_t)8921088 * 2);   // [16][66][66][128]
  bf16* hp    = (bf16*)alloc((size_t)17305600 * 2);  // [16][130][130][64]
  bf16* ztp   = (bf16*)alloc((size_t)2097152 * 2);   // [16][32][32][128]

  // 2 setup launches
  detect_dtype_kernel<<<1, 256, 0, stream>>>(d_in[0], flag, lacc);
  setup_all<<<5835, 256, 0, stream>>>(
      d_in[2], d_in[4], d_in[6], d_in[10], d_in[12], d_in[14],
      d_in[7], d_in[8], d_in[1], d_in[13], d_in[11], d_in[3],
      d_in[5], d_in[9],
      biasAll, embTB, sqAll, Wc1, Wfin, Wd1f, Wt2f, Wttf, Wdtf, flag,
      act1p, hp, zbp, eup, fqp, zqtp);

  // encoder: conv1 = LDS-staged im2col + MFMA GEMM (parity-split store)
  gemm1_lds<<<2048, 256, 0, stream>>>(d_in[0], flag, Wc1, beB1f, act1p);
  // conv2: LDS-staged + T14, 4 waves/block (co-quartered), 1024 x 256 thr
  conv2_lds<<<dim3(64, 1, 16), 256, 0, stream>>>(act1p, Wt2f, beB2f, zbp);
  // conv_t: PXW=33 (zbp parity), output ztp row-major
  mfma_conv<128, 128, 32, 2, 16, 128, 2, 33><<<dim3(16, 2, 16), 256, 0, stream>>>(
      zbp, zbp, 557568, 8448, Wttf, beTf, ztp, 131072, 4096, 128, 30, 0, 0, 0);

  // VQ top (16384 positions, row-major): 16 pos/wave -> 256 blocks
  vq_mfma16<<<256, 256, 0, stream>>>(ztp, 131072, 4096, embT, sqT,
                                     zqtp + 4480, 147968, 4352, lacc + 0, 5, 10, 0);

  // decoder_top upsample: 4 classes in one launch (row-major in/out)
  mfma_conv<128, 128, 32, 1, 4, 128, 2, 0><<<dim3(64, 2, 16), 256, 0, stream>>>(
      zqtp, zqtp, 147968, 4352, Wdtf, bdTf, eup, 557568, 16896, 256, 4, 8448, 128, 0);

  // VQ bottom (65536 positions; zbp parity in, fqp row-major out):
  // 16 pos/wave -> 1024 blocks, 16 waves/CU (was 4 -- latency-bound fix)
  vq_mfma16<<<1024, 256, 0, stream>>>(zbp + 8448, 557568, 8448, embB, sqB,
                                      fqp + 8576, 557568, 8448, lacc + 1, 6, 12, 33);

  // decoder conv d1: 8-wave blocks, wave=(class,row), 512 blocks x 512 thr
  mfma_d1_lds<<<dim3(32, 1, 16), 512, 0, stream>>>(fqp, eup, Wd1f, bd1f, hp);

  // final convT + sigmoid via MFMA -> fp32 NCHW output
  final_convt_mfma<<<1024, 256, 0, stream>>>(hp, Wfin, bd2f, out);
  finalize_loss_kernel<<<1, 64, 0, stream>>>(lacc, out + 3145728);
}

// Round 11
// 404.922 us; speedup vs baseline: 1.2074x; 1.2074x over previous
//
#include <hip/hip_runtime.h>
#include <hip/hip_bf16.h>
#include <cstddef>

typedef __hip_bfloat16 bf16;
typedef __attribute__((ext_vector_type(8))) short short8;
typedef __attribute__((ext_vector_type(4))) float float4v;
typedef __attribute__((ext_vector_type(4))) unsigned short ushort4v;

static __device__ __forceinline__ float b2f(bf16 v) { return __bfloat162float(v); }
static __device__ __forceinline__ float bits2f(unsigned int u) { return __uint_as_float(u); }
static __device__ __forceinline__ unsigned short f2bfbits(float f) {
  bf16 h = __float2bfloat16(f);
  return *reinterpret_cast<unsigned short*>(&h);
}
static __device__ __forceinline__ float ld_any(const void* p, long i, int flag) {
  return flag ? b2f(((const bf16*)p)[i]) : ((const float*)p)[i];
}
static __device__ __forceinline__ void unpack_u4(uint4 u, float* f) {
  f[0] = bits2f(u.x << 16); f[1] = bits2f(u.x & 0xffff0000u);
  f[2] = bits2f(u.y << 16); f[3] = bits2f(u.y & 0xffff0000u);
  f[4] = bits2f(u.z << 16); f[5] = bits2f(u.z & 0xffff0000u);
  f[6] = bits2f(u.w << 16); f[7] = bits2f(u.w & 0xffff0000u);
}

// --------------------------------------------------------- dtype detection
__global__ void detect_dtype_kernel(const void* __restrict__ x, int* __restrict__ flag) {
  __shared__ int ok;
  if (threadIdx.x == 0) ok = 1;
  __syncthreads();
  float v = b2f(((const bf16*)x)[threadIdx.x]);
  if (!(v >= 0.f && v <= 1.0009765625f)) ok = 0;
  __syncthreads();
  if (threadIdx.x == 0) *flag = ok;
}

// ------------------------------------------------- halo-ring zeroing helper
static __device__ __forceinline__ void halo_seg(bf16* p0, bf16* p1, bf16* p2,
                                                int np, int H, int W, int C8,
                                                long imgS, int gpi, int r) {
  int total = 16 * gpi;
  int which = r / total;
  if (which >= np) return;
  int rr = r - which * total;
  int img = rr / gpi, g = rr % gpi;
  int pos = g / C8, c8 = g % C8;
  int row, col;
  if (pos < W) { row = 0; col = pos; }
  else if (pos < 2 * W) { row = H - 1; col = pos - W; }
  else { int s = pos - 2 * W; row = 1 + (s >> 1); col = (s & 1) ? (W - 1) : 0; }
  bf16* base = (which == 0) ? p0 : ((which == 1) ? p1 : p2);
  uint4* dst = (uint4*)(base + (long)img * imgS + ((long)row * W + col) * (C8 * 8) + (long)c8 * 8);
  *dst = uint4{0u, 0u, 0u, 0u};
}

// ---------------- all converts / repacks + halo zeroing in one kernel.
// seg0 (sqAll) is wave-parallel: one 64-lane wave per codebook row.
__global__ __launch_bounds__(256) void setup_all(
    const void* s2, const void* s4, const void* s6,
    const void* s10, const void* s12, const void* s14,
    const void* sT, const void* sB, const void* c1s,
    const void* fins, const void* d1s, const void* t2s,
    const void* tts, const void* dts,
    float* __restrict__ biasAll, bf16* __restrict__ embTB,
    float* __restrict__ sqAll, bf16* __restrict__ Wc1,
    bf16* __restrict__ Wfin, bf16* __restrict__ Wd1f,
    bf16* __restrict__ Wt2f, bf16* __restrict__ Wttf,
    bf16* __restrict__ Wdtf, const int* __restrict__ flag,
    bf16* act1p, bf16* hp, bf16* zbp, bf16* eup, bf16* fqp, bf16* zqtp) {
  long i = (long)blockIdx.x * 256 + threadIdx.x;
  const int fl = *flag;
  // seg0: emb row sum-of-squares, wave-parallel [65536 = 1024 rows x 64 lanes]
  if (i < 65536) {
    int k = (int)(i >> 6), lane = (int)(i & 63);
    const void* s = (k < 512) ? sT : sB;
    long base = (long)(k & 511) * 128 + lane * 2;
    float v0 = b2f(__float2bfloat16(ld_any(s, base, fl)));
    float v1 = b2f(__float2bfloat16(ld_any(s, base + 1, fl)));
    float acc = fmaf(v1, v1, v0 * v0);
    #pragma unroll
    for (int o = 32; o > 0; o >>= 1) acc += __shfl_down(acc, o, 64);
    if (lane == 0) sqAll[k] = acc;
    return;
  }
  i -= 65536;
  // seg1: 6 conv biases -> one fp32 buffer [515]
  if (i < 515) {
    const void* s; long off;
    if (i < 64)       { s = s2;  off = i; }
    else if (i < 192) { s = s4;  off = i - 64; }
    else if (i < 320) { s = s6;  off = i - 192; }
    else if (i < 448) { s = s10; off = i - 320; }
    else if (i < 512) { s = s12; off = i - 448; }
    else              { s = s14; off = i - 512; }
    biasAll[i] = ld_any(s, off, fl);
    return;
  }
  i -= 515;
  // seg2: both codebooks -> contiguous bf16 [1024][128]
  if (i < 131072) {
    const void* s = (i < 65536) ? sT : sB;
    long off = i & 65535;
    embTB[i] = fl ? ((const bf16*)s)[off] : __float2bfloat16(((const float*)s)[off]);
    return;
  }
  i -= 131072;
  // seg3: conv1 weights [64][3][4][4] -> [co][k], K padded 48->64 [4096]
  if (i < 4096) {
    int co = (int)i >> 6, k = (int)i & 63;
    float v = (k < 48) ? ld_any(c1s, co * 48 + k, fl) : 0.f;
    Wc1[i] = __float2bfloat16(v);
    return;
  }
  i -= 4096;
  // seg4: final convT weights -> A[m=cls*4+co][d=dy*3+dx][64ci] [9216]
  if (i < 9216) {
    int m = (int)i / 576, rem = (int)i % 576;
    int d = rem >> 6, ci = rem & 63;
    int cls = m >> 2, co = m & 3;
    int p = cls >> 1, q = cls & 1;
    int dy = d / 3, dx = d % 3;
    int s_ = p - dy + 1, t_ = q - dx + 1;
    float v = 0.f;
    if (co < 3 && s_ >= 0 && s_ <= 1 && t_ >= 0 && t_ <= 1) {
      int kh = 2 * s_ + 1 - p, kw = 2 * t_ + 1 - q;
      v = ld_any(fins, ci * 48 + co * 16 + kh * 4 + kw, fl);
    }
    Wfin[i] = __float2bfloat16(v);
    return;
  }
  i -= 9216;
  // seg5: d1 weights [256ci][64co][4][4] -> frag [262144]
  if (i < 262144) {
    int low = (int)i & 511;
    int ln = low >> 5, cl = low & 31;
    int c2 = (int)(i >> 9);
    int j = c2 & 3;
    int kc = (c2 >> 2) & 7;
    int t = (c2 >> 5) & 3;
    int cls = c2 >> 7;
    int p = cls >> 1, q = cls & 1;
    int s_ = t >> 1, t2 = t & 1;
    int kh = 2 * s_ + 1 - p, kw = 2 * t2 + 1 - q;
    int co = j * 16 + ln, ci = kc * 32 + cl;
    Wd1f[i] = __float2bfloat16(ld_any(d1s, (long)ci * 1024 + co * 16 + kh * 4 + kw, fl));
    return;
  }
  i -= 262144;
  // seg6: conv2 weights OIHW[128][64][4][4] -> frag direct (MC=4,KC=2) [131072]
  if (i < 131072) {
    int low = (int)i & 511;
    int ln = low >> 5, cl = low & 31;
    int c2 = (int)(i >> 9);
    int j = c2 & 1, c3 = c2 >> 1;
    int kc = c3 & 1, c4 = c3 >> 1;
    int mc = c4 & 3, tg = c4 >> 2;
    int co = mc * 32 + j * 16 + ln, ci = kc * 32 + cl;
    Wt2f[i] = __float2bfloat16(ld_any(t2s, (long)co * 1024 + ci * 16 + tg, fl));
    return;
  }
  i -= 131072;
  // seg7: conv_t weights OIHW[128][128][4][4] -> frag direct (MC=4,KC=4) [262144]
  if (i < 262144) {
    int low = (int)i & 511;
    int ln = low >> 5, cl = low & 31;
    int c2 = (int)(i >> 9);
    int j = c2 & 1, c3 = c2 >> 1;
    int kc = c3 & 3, c4 = c3 >> 2;
    int mc = c4 & 3, tg = c4 >> 2;
    int co = mc * 32 + j * 16 + ln, ci = kc * 32 + cl;
    Wttf[i] = __float2bfloat16(ld_any(tts, (long)co * 2048 + ci * 16 + tg, fl));
    return;
  }
  i -= 262144;
  // seg8: convT dt weights [128ci][128co][4][4] -> class frag direct [262144]
  if (i < 262144) {
    int low = (int)i & 511;
    int ln = low >> 5, cl = low & 31;
    int c2 = (int)(i >> 9);
    int j = c2 & 1, c3 = c2 >> 1;
    int kc = c3 & 3, c4 = c3 >> 2;
    int mc = c4 & 3, tg = c4 >> 2;
    int co = mc * 32 + j * 16 + ln, ci = kc * 32 + cl;
    int cls = tg >> 2, st = tg & 3;
    int p = cls >> 1, q = cls & 1;
    int s_ = st >> 1, tt_ = st & 1;
    int kh = 2 * s_ + 1 - p, kw = 2 * tt_ + 1 - q;
    Wdtf[i] = __float2bfloat16(ld_any(dts, (long)ci * 2048 + co * 16 + kh * 4 + kw, fl));
    return;
  }
  i -= 262144;
  // seg9-11: halo-ring zeroing (independent of flag)
  if (i < 132096) { halo_seg(act1p, hp, nullptr, 2, 130, 130, 8, 1081600, 4128, (int)i); return; }
  i -= 132096;
  if (i < 199680) { halo_seg(zbp, eup, fqp, 3, 66, 66, 16, 557568, 4160, (int)i); return; }
  i -= 199680;
  if (i < 33792)  { halo_seg(zqtp, nullptr, nullptr, 1, 34, 34, 16, 147968, 2112, (int)i); }
}

// -------------------- conv1: LDS-staged im2col + MFMA GEMM.
__global__ __launch_bounds__(256) void gemm1_lds(
    const void* __restrict__ x, const int* __restrict__ flag,
    const bf16* __restrict__ w, const float* __restrict__ bias,
    bf16* __restrict__ act1p) {
  __shared__ unsigned short xs[3 * 4 * 260];   // [ci][r][px], px = iw+1
  const int lane = threadIdx.x & 63, wv = threadIdx.x >> 6;
  const int wm = wv & 1, wn = wv >> 1;
  const int ln = lane & 15, quad = lane >> 4;
  const int n0 = blockIdx.x * 128;
  const int oh = (n0 >> 7) & 127, b = n0 >> 14;
  const int fl = *flag;
  const int ih0 = 2 * oh - 1;

  for (int i = threadIdx.x; i < 3120; i += 256) {
    int px = i % 260;
    int t = i / 260;
    int r = t & 3, ci = t >> 2;
    int ih = ih0 + r;
    int iw = px - 1;
    float v = ((unsigned)ih < 256u && (unsigned)iw < 256u)
                ? ld_any(x, (((long)(b * 3 + ci)) << 16) + ((long)ih << 8) + iw, fl) : 0.f;
    xs[i] = f2bfbits(v);
  }
  __syncthreads();

  float4v acc[2][4];
  #pragma unroll
  for (int i = 0; i < 2; ++i)
    #pragma unroll
    for (int j = 0; j < 4; ++j) acc[i][j] = {0.f, 0.f, 0.f, 0.f};

  const int ow_base = wn * 64;
  #pragma unroll
  for (int kc = 0; kc < 2; ++kc) {
    const bf16* wk = w + (wm * 32 + ln) * 64 + kc * 32 + quad * 8;
    short8 a0 = *(const short8*)(wk);
    short8 a1 = *(const short8*)(wk + 16 * 64);
    const int k0 = kc * 32 + quad * 8;      // 0,8,...,56; >=48 is zero-pad
    const int ci = k0 >> 4;
    const int kh0 = (k0 & 15) >> 2;         // 0 or 2
    #pragma unroll
    for (int bf = 0; bf < 4; ++bf) {
      short8 bv;
      if (k0 >= 48) {
        bv = (short8){0, 0, 0, 0, 0, 0, 0, 0};
      } else {
        int ow = ow_base + bf * 16 + ln;
        union { uint2 u2[2]; short8 s8; } u;
        u.u2[0] = *(const uint2*)(xs + (ci * 4 + kh0) * 260 + ow * 2);
        u.u2[1] = *(const uint2*)(xs + (ci * 4 + kh0 + 1) * 260 + ow * 2);
        bv = u.s8;
      }
      acc[0][bf] = __builtin_amdgcn_mfma_f32_16x16x32_bf16(a0, bv, acc[0][bf], 0, 0, 0);
      acc[1][bf] = __builtin_amdgcn_mfma_f32_16x16x32_bf16(a1, bv, acc[1][bf], 0, 0, 0);
    }
  }
  #pragma unroll
  for (int mf = 0; mf < 2; ++mf) {
    int coB = wm * 32 + mf * 16 + quad * 4;
    float4v bv4 = *(const float4v*)(bias + coB);
    #pragma unroll
    for (int bf = 0; bf < 4; ++bf) {
      int ow = ow_base + bf * 16 + ln;
      int xx = ow + 1;   // parity-split column
      long oaddr = ((long)(b * 130 + oh + 1)) * 8320 +
                   (long)(((xx & 1) * 65) + (xx >> 1)) * 64 + coB;
      float4v v = acc[mf][bf];
      ushort4v o;
      #pragma unroll
      for (int e = 0; e < 4; ++e) o[e] = f2bfbits(fmaxf(v[e] + bv4[e], 0.f));
      *(ushort4v*)(act1p + oaddr) = o;
    }
  }
}

// ------------------------------------------- MFMA implicit-GEMM tap conv
template <int COUT, int CINT, int TC, int S, int NT, int INC, int NBF, int PXW>
__global__ __launch_bounds__(256) void mfma_conv(
    const bf16* __restrict__ in1, const bf16* __restrict__ in2,
    long inImgS, int inRowS,
    const bf16* __restrict__ wf, const float* __restrict__ bias,
    bf16* __restrict__ outp, long outImgS, int oRS, int oCS,
    int nxb, long po, long qo, int oPXW) {
  constexpr int TR = (2 * NBF * 16) / TC;
  constexpr int KC = CINT / 32;
  constexpr int MC = COUT / 32;
  constexpr int KSPLIT = (CINT > INC) ? (INC / 32) : KC;
  const int lane = threadIdx.x & 63;
  const int wv = threadIdx.x >> 6;
  const int wm = wv & 1, wn = wv >> 1;
  const int ln = lane & 15, quad = lane >> 4;
  const int cls = blockIdx.x >> nxb;
  const int xb = blockIdx.x & ((1u << nxb) - 1u);
  const int mTile = blockIdx.y * 64;
  const int mc = blockIdx.y * 2 + wm;
  const int oh0 = xb * TR;
  const int b = blockIdx.z;
  const int p = cls >> 1, q = cls & 1;
  const long ooff = (long)(p + 1) * po + (long)(q + 1) * qo;

  long posOff[NBF];
  int rr[NBF], cc[NBF];
  #pragma unroll
  for (int bf = 0; bf < NBF; ++bf) {
    int n = wn * (NBF * 16) + bf * 16 + ln;
    int r = n / TC, c = n % TC;
    rr[bf] = r; cc[bf] = c;
    posOff[bf] = (long)(S * (oh0 + r)) * inRowS +
                 (PXW ? (long)c * INC : (long)(S * c) * INC);
  }
  const bf16* inb1 = in1 + (long)b * inImgS;
  const bf16* inb2 = in2 + (long)b * inImgS;

  float4v acc[2][NBF];
  #pragma unroll
  for (int i = 0; i < 2; ++i)
    #pragma unroll
    for (int j = 0; j < NBF; ++j) acc[i][j] = {0.f, 0.f, 0.f, 0.f};

  for (int t = 0; t < NT; ++t) {
    int dy, dx;
    if (S == 2) { dy = t >> 2; dx = t & 3; }
    else        { dy = p - (t >> 1) + 1; dx = q - (t & 1) + 1; }
    const int dxo = PXW ? ((dx & 1) * PXW + (dx >> 1)) : dx;
    const long tapOff = (long)dy * inRowS + (long)dxo * INC;
    const bf16* wt = wf + ((long)(cls * NT + t) * MC + mc) * (KC * 1024) + ln * 32 + quad * 8;
    #pragma unroll
    for (int kc = 0; kc < KC; ++kc) {
      short8 a0 = *(const short8*)(wt + kc * 1024);
      short8 a1 = *(const short8*)(wt + kc * 1024 + 512);
      const bf16* bp = (kc < KSPLIT) ? inb1 : inb2;
      int kOff = (kc < KSPLIT ? kc : kc - KSPLIT) * 32 + quad * 8;
      #pragma unroll
      for (int bf = 0; bf < NBF; ++bf) {
        short8 bv = *(const short8*)(bp + posOff[bf] + tapOff + kOff);
        acc[0][bf] = __builtin_amdgcn_mfma_f32_16x16x32_bf16(a0, bv, acc[0][bf], 0, 0, 0);
        acc[1][bf] = __builtin_amdgcn_mfma_f32_16x16x32_bf16(a1, bv, acc[1][bf], 0, 0, 0);
      }
    }
  }

  bf16* outb = outp + (long)b * outImgS + ooff;
  #pragma unroll
  for (int mf = 0; mf < 2; ++mf) {
    int coB = mTile + wm * 32 + mf * 16 + quad * 4;
    float4v bv4 = *(const float4v*)(bias + coB);
    #pragma unroll
    for (int bf = 0; bf < NBF; ++bf) {
      float4v v = acc[mf][bf];
      ushort4v o;
      #pragma unroll
      for (int e = 0; e < 4; ++e)
        o[e] = f2bfbits(fmaxf(v[e] + bv4[e], 0.f));
      long coff = oPXW ? (long)((((cc[bf] + 1) & 1) * oPXW) + ((cc[bf] + 1) >> 1)) * oCS
                       : (long)cc[bf] * oCS;
      long oaddr = (long)(oh0 + rr[bf]) * oRS + coff + oCS * 0 + coB;
      *(ushort4v*)(outb + oaddr) = o;
    }
  }
}

// ---------- conv2 (64 -> 128, s2): LDS-staged + T14, 4 waves (co-quartered)
__global__ __launch_bounds__(256) void conv2_lds(
    const bf16* __restrict__ in, const bf16* __restrict__ wf,
    const float* __restrict__ bias, bf16* __restrict__ outp) {
  __shared__ short8 lds8[2 * 130 * 9];   // 37440 B
  const int lane = threadIdx.x & 63;
  const int w = threadIdx.x >> 6;        // co-quarter (wave id, mc=w)
  const int ln = lane & 15, quad = lane >> 4;
  const int oh = blockIdx.x;             // output row 0..63
  const int b = blockIdx.z;

  const bf16* img = in + (long)b * 1081600;
  const short8* s0 = (const short8*)(img + (long)(2 * oh) * 8320);      // rows 2oh,2oh+1
  const short8* s1 = (const short8*)(img + (long)(2 * oh + 2) * 8320);  // rows 2oh+2,2oh+3

  float4v acc[2][4];   // [j (16-co frag)][bf (pos chunk)]
  #pragma unroll
  for (int j = 0; j < 2; ++j)
    #pragma unroll
    for (int bf = 0; bf < 4; ++bf) acc[j][bf] = {0.f, 0.f, 0.f, 0.f};

  auto compute = [&](int f) {
    #pragma unroll
    for (int tl = 0; tl < 8; ++tl) {
      const int t = 8 * f + tl;
      const int r = (t >> 2) & 1;        // row within phase
      const int dx = t & 3;
      const int pp = dx & 1, cb = dx >> 1;
      const int lbase = (r * 130 + pp * 65 + cb) * 9 + quad;
      #pragma unroll
      for (int kc = 0; kc < 2; ++kc) {
        const bf16* wk = wf + (long)((t * 4 + w) * 2 + kc) * 1024 + ln * 32 + quad * 8;
        short8 a0 = *(const short8*)(wk);          // j=0
        short8 a1 = *(const short8*)(wk + 512);    // j=1
        #pragma unroll
        for (int bf = 0; bf < 4; ++bf) {
          short8 bv = lds8[lbase + (bf * 16 + ln) * 9 + kc * 4];
          acc[0][bf] = __builtin_amdgcn_mfma_f32_16x16x32_bf16(a0, bv, acc[0][bf], 0, 0, 0);
          acc[1][bf] = __builtin_amdgcn_mfma_f32_16x16x32_bf16(a1, bv, acc[1][bf], 0, 0, 0);
        }
      }
    }
  };

  // stage phase 0 directly
  for (int i = threadIdx.x; i < 2080; i += 256) {   // 2 rows x 130 pos x 8
    lds8[(i >> 3) * 9 + (i & 7)] = s0[i];
  }
  // T14: issue phase-1 loads now (9 x 16B regs); latency hides under compute(0)
  short8 pre[9];
  #pragma unroll
  for (int it = 0; it < 9; ++it) {
    int i = threadIdx.x + it * 256;
    if (i < 2080) pre[it] = s1[i];
  }
  __syncthreads();
  compute(0);
  __syncthreads();
  #pragma unroll
  for (int it = 0; it < 9; ++it) {
    int i = threadIdx.x + it * 256;
    if (i < 2080) lds8[(i >> 3) * 9 + (i & 7)] = pre[it];
  }
  __syncthreads();
  compute(1);

  // store: zbp parity layout, row oh+1, col map x -> ((x+1)&1)*33 + ((x+1)>>1)
  bf16* outb = outp + (long)b * 557568 + (long)(oh + 1) * 8448;
  #pragma unroll
  for (int j = 0; j < 2; ++j) {
    int co = w * 32 + j * 16 + quad * 4;
    float4v bv4 = *(const float4v*)(bias + co);
    #pragma unroll
    for (int bf = 0; bf < 4; ++bf) {
      int x = bf * 16 + ln;
      int col = (((x + 1) & 1) * 33) + ((x + 1) >> 1);
      float4v v = acc[j][bf];
      ushort4v o;
      #pragma unroll
      for (int e = 0; e < 4; ++e)
        o[e] = f2bfbits(fmaxf(v[e] + bv4[e], 0.f));
      *(ushort4v*)(outb + (long)col * 128 + co) = o;
    }
  }
}

// ------ d1 (concat 256 -> 64): 8-wave blocks, wave = (class, row). Frozen.
__global__ __launch_bounds__(512) void mfma_d1_lds(
    const bf16* __restrict__ in1, const bf16* __restrict__ in2,
    const bf16* __restrict__ wf, const float* __restrict__ bias,
    bf16* __restrict__ outp) {
  __shared__ short8 lds8[264 * 17];   // 4 rows x 66 pos x 16 chunks, pad 17
  const int lane = threadIdx.x & 63, wv = threadIdx.x >> 6;   // 0..7
  const int ln = lane & 15, quad = lane >> 4;
  const int r0 = blockIdx.x * 2;     // output class-rows r0, r0+1
  const int b = blockIdx.z;
  const int cls = wv & 3, rr = wv >> 2;   // wave = (class, row)
  const int p = cls >> 1, q = cls & 1;

  const bf16* src1 = in1 + (long)b * 557568 + (long)r0 * 8448;  // rows r0..r0+3
  const bf16* src2 = in2 + (long)b * 557568 + (long)r0 * 8448;

  float4v acc[4][4];
  #pragma unroll
  for (int j = 0; j < 4; ++j)
    #pragma unroll
    for (int bf = 0; bf < 4; ++bf) acc[j][bf] = {0.f, 0.f, 0.f, 0.f};

  auto compute = [&](int phase) {
    #pragma unroll
    for (int t = 0; t < 4; ++t) {
      int dy = p - (t >> 1) + 1, dx = q - (t & 1) + 1;
      const bf16* wt = wf + (long)(cls * 4 + t) * 16384 + (long)(phase * 4) * 2048 +
                       ln * 32 + quad * 8;
      const int lbase = ((rr + dy) * 66 + dx) * 17 + quad;
      #pragma unroll
      for (int kc = 0; kc < 4; ++kc) {
        const bf16* wk = wt + kc * 2048;
        short8 a0 = *(const short8*)(wk);
        short8 a1 = *(const short8*)(wk + 512);
        short8 a2 = *(const short8*)(wk + 1024);
        short8 a3 = *(const short8*)(wk + 1536);
        #pragma unroll
        for (int bf = 0; bf < 4; ++bf) {
          short8 bv = lds8[lbase + kc * 4 + (bf * 16 + ln) * 17];
          acc[0][bf] = __builtin_amdgcn_mfma_f32_16x16x32_bf16(a0, bv, acc[0][bf], 0, 0, 0);
          acc[1][bf] = __builtin_amdgcn_mfma_f32_16x16x32_bf16(a1, bv, acc[1][bf], 0, 0, 0);
          acc[2][bf] = __builtin_amdgcn_mfma_f32_16x16x32_bf16(a2, bv, acc[2][bf], 0, 0, 0);
          acc[3][bf] = __builtin_amdgcn_mfma_f32_16x16x32_bf16(a3, bv, acc[3][bf], 0, 0, 0);
        }
      }
    }
  };

  // stage phase 0 (fqp): 264 pos x 16 chunks with 512 threads
  for (int i = threadIdx.x; i < 4224; i += 512) {
    lds8[(i >> 4) * 17 + (i & 15)] = *(const short8*)(src1 + (long)(i >> 4) * 128 + (i & 15) * 8);
  }
  // T14: issue phase-1 (eup) loads now; latency hides under compute(0)
  short8 pre[9];
  #pragma unroll
  for (int it = 0; it < 9; ++it) {
    int i = threadIdx.x + it * 512;
    if (i < 4224) pre[it] = *(const short8*)(src2 + (long)(i >> 4) * 128 + (i & 15) * 8);
  }
  __syncthreads();
  compute(0);
  __syncthreads();
  #pragma unroll
  for (int it = 0; it < 9; ++it) {
    int i = threadIdx.x + it * 512;
    if (i < 4224) lds8[(i >> 4) * 17 + (i & 15)] = pre[it];
  }
  __syncthreads();
  compute(1);

  bf16* outb = outp + (long)b * 1081600 + (long)(p + 1) * 8320 + (long)(q + 1) * 64 +
               (long)(r0 + rr) * 16640;
  #pragma unroll
  for (int j = 0; j < 4; ++j) {
    int co = j * 16 + quad * 4;
    float4v bv4 = *(const float4v*)(bias + co);
    #pragma unroll
    for (int bf = 0; bf < 4; ++bf) {
      float4v v = acc[j][bf];
      ushort4v o;
      #pragma unroll
      for (int e = 0; e < 4; ++e)
        o[e] = f2bfbits(fmaxf(v[e] + bv4[e], 0.f));
      *(ushort4v*)(outb + (long)(bf * 16 + ln) * 128 + co) = o;
    }
  }
}

// ---------------------------------------------------- VQ via MFMA GEMM
// 64 pos/wave (ILP-4 over 4 position fragments); per-block partial loss sum
// written to loss_part[blockIdx] -- NO global atomics (Guideline 12: 1024
// same-address device atomics serialize at the home L2 and dominate drain).
__global__ __launch_bounds__(256) void vq_mfma(
    const bf16* __restrict__ z, long zImgS, int zRowS,
    const bf16* __restrict__ emb, const float* __restrict__ embsq,
    bf16* __restrict__ zq, long qImgS, int qRowS,
    float* __restrict__ loss_part, int wb, int hwb, int ipxw) {
  __shared__ float ws[4];
  const int lane = threadIdx.x & 63, wv = threadIdx.x >> 6;
  const int ln = lane & 15, quad = lane >> 4;
  const int base = blockIdx.x * 256 + wv * 64;

  short8 bfrag[4][4];
  #pragma unroll
  for (int bf = 0; bf < 4; ++bf) {
    int n = base + bf * 16 + ln;
    int b = n >> hwb;
    int rem = n & ((1 << hwb) - 1);
    int y = rem >> wb, x = rem & ((1 << wb) - 1);
    int xcol = ipxw ? ((((x + 1) & 1) * ipxw) + ((x + 1) >> 1)) : x;
    const bf16* zrow = z + (long)b * zImgS + (long)y * zRowS + (long)xcol * 128;
    #pragma unroll
    for (int kc = 0; kc < 4; ++kc)
      bfrag[bf][kc] = *(const short8*)(zrow + kc * 32 + quad * 8);
  }

  float best0 = 3.4e38f, best1 = 3.4e38f, best2 = 3.4e38f, best3 = 3.4e38f;
  int bk0 = 0, bk1 = 0, bk2 = 0, bk3 = 0;
  for (int ct = 0; ct < 32; ++ct) {
    const bf16* erow = emb + (long)(ct * 16 + ln) * 128 + quad * 8;
    short8 a0 = *(const short8*)(erow);
    short8 a1 = *(const short8*)(erow + 32);
    short8 a2 = *(const short8*)(erow + 64);
    short8 a3 = *(const short8*)(erow + 96);
    float4v sq4 = *(const float4v*)(embsq + ct * 16 + quad * 4);
    #pragma unroll
    for (int bf = 0; bf < 4; ++bf) {
      float4v acc = {0.f, 0.f, 0.f, 0.f};
      acc = __builtin_amdgcn_mfma_f32_16x16x32_bf16(a0, bfrag[bf][0], acc, 0, 0, 0);
      acc = __builtin_amdgcn_mfma_f32_16x16x32_bf16(a1, bfrag[bf][1], acc, 0, 0, 0);
      acc = __builtin_amdgcn_mfma_f32_16x16x32_bf16(a2, bfrag[bf][2], acc, 0, 0, 0);
      acc = __builtin_amdgcn_mfma_f32_16x16x32_bf16(a3, bfrag[bf][3], acc, 0, 0, 0);
      int kb = ct * 16 + quad * 4;
      #pragma unroll
      for (int r = 0; r < 4; ++r) {
        float s = fmaf(-2.f, acc[r], sq4[r]);
        if (bf == 0) { if (s < best0) { best0 = s; bk0 = kb + r; } }
        if (bf == 1) { if (s < best1) { best1 = s; bk1 = kb + r; } }
        if (bf == 2) { if (s < best2) { best2 = s; bk2 = kb + r; } }
        if (bf == 3) { if (s < best3) { best3 = s; bk3 = kb + r; } }
      }
    }
  }
  float bs[4] = {best0, best1, best2, best3};
  int bk[4] = {bk0, bk1, bk2, bk3};
  #pragma unroll
  for (int bf = 0; bf < 4; ++bf) {
    #pragma unroll
    for (int m = 16; m <= 32; m <<= 1) {
      float os = __shfl_xor(bs[bf], m, 64);
      int ok = __shfl_xor(bk[bf], m, 64);
      if (os < bs[bf] || (os == bs[bf] && ok < bk[bf])) { bs[bf] = os; bk[bf] = ok; }
    }
  }
  int myk = (quad == 0) ? bk[0] : (quad == 1) ? bk[1] : (quad == 2) ? bk[2] : bk[3];
  int n = base + quad * 16 + ln;
  int b = n >> hwb;
  int rem = n & ((1 << hwb) - 1);
  int y = rem >> wb, x = rem & ((1 << wb) - 1);
  int xcol = ipxw ? ((((x + 1) & 1) * ipxw) + ((x + 1) >> 1)) : x;
  const uint4* zr = (const uint4*)(z + (long)b * zImgS + (long)y * zRowS + (long)xcol * 128);
  uint4* qr = (uint4*)(zq + (long)b * qImgS + (long)y * qRowS + (long)x * 128);
  const uint4* er = (const uint4*)(emb + (long)myk * 128);
  float lsum = 0.f;
  #pragma unroll
  for (int j = 0; j < 16; ++j) {
    uint4 ue = er[j];
    uint4 uz = zr[j];
    qr[j] = ue;
    float ev[8], zv[8];
    unpack_u4(ue, ev);
    unpack_u4(uz, zv);
    #pragma unroll
    for (int e = 0; e < 8; ++e) {
      float dv = ev[e] - zv[e];
      lsum = fmaf(dv, dv, lsum);
    }
  }
  for (int o = 32; o > 0; o >>= 1) lsum += __shfl_down(lsum, o, 64);
  if (lane == 0) ws[wv] = lsum;
  __syncthreads();
  if (threadIdx.x == 0)
    loss_part[blockIdx.x] = ws[0] + ws[1] + ws[2] + ws[3];
}

// ---------- VQ, 16 positions/wave (small-N full-chip variant, top only).
// Per-block partial loss -> loss_part[blockIdx]; no global atomics.
__global__ __launch_bounds__(256) void vq_mfma16(
    const bf16* __restrict__ z, long zImgS, int zRowS,
    const bf16* __restrict__ emb, const float* __restrict__ embsq,
    bf16* __restrict__ zq, long qImgS, int qRowS,
    float* __restrict__ loss_part, int wb, int hwb) {
  __shared__ float ws[4];
  const int lane = threadIdx.x & 63, wv = threadIdx.x >> 6;
  const int ln = lane & 15, quad = lane >> 4;
  const int base = blockIdx.x * 64 + wv * 16;   // 16 positions per wave

  const int n = base + ln;
  const int b = n >> hwb;
  const int rem = n & ((1 << hwb) - 1);
  const int y = rem >> wb, x = rem & ((1 << wb) - 1);
  const bf16* zrow = z + (long)b * zImgS + (long)y * zRowS + (long)x * 128;
  short8 bfrag[4];
  #pragma unroll
  for (int kc = 0; kc < 4; ++kc)
    bfrag[kc] = *(const short8*)(zrow + kc * 32 + quad * 8);

  float best = 3.4e38f;
  int bk = 0;
  for (int ct = 0; ct < 32; ++ct) {
    const bf16* erow = emb + (long)(ct * 16 + ln) * 128 + quad * 8;
    short8 a0 = *(const short8*)(erow);
    short8 a1 = *(const short8*)(erow + 32);
    short8 a2 = *(const short8*)(erow + 64);
    short8 a3 = *(const short8*)(erow + 96);
    float4v sq4 = *(const float4v*)(embsq + ct * 16 + quad * 4);
    float4v acc = {0.f, 0.f, 0.f, 0.f};
    acc = __builtin_amdgcn_mfma_f32_16x16x32_bf16(a0, bfrag[0], acc, 0, 0, 0);
    acc = __builtin_amdgcn_mfma_f32_16x16x32_bf16(a1, bfrag[1], acc, 0, 0, 0);
    acc = __builtin_amdgcn_mfma_f32_16x16x32_bf16(a2, bfrag[2], acc, 0, 0, 0);
    acc = __builtin_amdgcn_mfma_f32_16x16x32_bf16(a3, bfrag[3], acc, 0, 0, 0);
    int kb = ct * 16 + quad * 4;
    #pragma unroll
    for (int r = 0; r < 4; ++r) {
      float s = fmaf(-2.f, acc[r], sq4[r]);
      if (s < best) { best = s; bk = kb + r; }
    }
  }
  // reduce across quads (lanes sharing ln)
  #pragma unroll
  for (int m = 16; m <= 32; m <<= 1) {
    float os = __shfl_xor(best, m, 64);
    int ok = __shfl_xor(bk, m, 64);
    if (os < best || (os == best && ok < bk)) { best = os; bk = ok; }
  }
  // copy + loss: quads split the 16 uint4 chunks of position n
  const uint4* zr = (const uint4*)zrow;
  uint4* qr = (uint4*)(zq + (long)b * qImgS + (long)y * qRowS + (long)x * 128);
  const uint4* er = (const uint4*)(emb + (long)bk * 128);
  float lsum = 0.f;
  #pragma unroll
  for (int t = 0; t < 4; ++t) {
    int j = quad * 4 + t;
    uint4 ue = er[j];
    uint4 uz = zr[j];
    qr[j] = ue;
    float ev[8], zv[8];
    unpack_u4(ue, ev);
    unpack_u4(uz, zv);
    #pragma unroll
    for (int e = 0; e < 8; ++e) {
      float dv = ev[e] - zv[e];
      lsum = fmaf(dv, dv, lsum);
    }
  }
  for (int o = 32; o > 0; o >>= 1) lsum += __shfl_down(lsum, o, 64);
  if (lane == 0) ws[wv] = lsum;
  __syncthreads();
  if (threadIdx.x == 0)
    loss_part[blockIdx.x] = ws[0] + ws[1] + ws[2] + ws[3];
}

// --------------------- final convT(64->3)+sigmoid via class-packed MFMA
__global__ __launch_bounds__(256) void final_convt_mfma(
    const bf16* __restrict__ hp, const bf16* __restrict__ wfin,
    const float* __restrict__ bf_, float* __restrict__ out) {
  const int lane = threadIdx.x & 63, wv = threadIdx.x >> 6;
  const int ln = lane & 15, quad = lane >> 4;
  const int base = blockIdx.x * 256 + wv * 64;   // 262144 positions total

  short8 afr[18];
  #pragma unroll
  for (int kc = 0; kc < 18; ++kc)
    afr[kc] = *(const short8*)(wfin + ln * 576 + kc * 32 + quad * 8);

  float4v acc[4];
  #pragma unroll
  for (int bf = 0; bf < 4; ++bf) acc[bf] = {0.f, 0.f, 0.f, 0.f};

  #pragma unroll
  for (int bf = 0; bf < 4; ++bf) {
    int n = base + bf * 16 + ln;
    int xx = n & 127, y = (n >> 7) & 127, b = n >> 14;
    const bf16* hb = hp + (long)b * 1081600 + (long)y * 8320 + (long)xx * 64;
    #pragma unroll
    for (int kc = 0; kc < 18; ++kc) {
      int d = kc >> 1;
      const bf16* bp = hb + (long)(d / 3) * 8320 + (d % 3) * 64 + (kc & 1) * 32 + quad * 8;
      short8 bv = *(const short8*)bp;
      acc[bf] = __builtin_amdgcn_mfma_f32_16x16x32_bf16(afr[kc], bv, acc[bf], 0, 0, 0);
    }
  }

  const int p = quad >> 1, q = quad & 1;
  float b0 = bf_[0], b1 = bf_[1], b2 = bf_[2];
  #pragma unroll
  for (int bf = 0; bf < 4; ++bf) {
    int n = base + bf * 16 + ln;
    int xx = n & 127, y = (n >> 7) & 127, b = n >> 14;
    long ob = (long)b * 196608 + (long)(2 * y + p) * 256 + (2 * xx + q);
    float v0 = acc[bf][0] + b0, v1 = acc[bf][1] + b1, v2 = acc[bf][2] + b2;
    out[ob]          = 1.f / (1.f + expf(-v0));
    out[ob + 65536]  = 1.f / (1.f + expf(-v1));
    out[ob + 131072] = 1.f / (1.f + expf(-v2));
  }
}

// ----------- loss finalize: reduce 2x256 per-block partials (no atomics)
__global__ void finalize_loss_kernel(const float* __restrict__ pTop,
                                     const float* __restrict__ pBot,
                                     float* __restrict__ out) {
  __shared__ float ws[8];
  const int t = threadIdx.x;           // 256 threads
  const int lane = t & 63, wv = t >> 6;
  float a = pTop[t];
  float b = pBot[t];
  #pragma unroll
  for (int o = 32; o > 0; o >>= 1) {
    a += __shfl_down(a, o, 64);
    b += __shfl_down(b, o, 64);
  }
  if (lane == 0) { ws[wv] = a; ws[4 + wv] = b; }
  __syncthreads();
  if (t == 0) {
    float lt = (ws[0] + ws[1] + ws[2] + ws[3]) * (1.5f / 2097152.f);
    float lb = (ws[4] + ws[5] + ws[6] + ws[7]) * (1.5f / 8388608.f);
    *out = lt + lb;
  }
}

// ------------------------------------------------------------------ launch
extern "C" void kernel_launch(void* const* d_in, const int* in_sizes, int n_in,
                              void* d_out, int out_size, void* d_ws, size_t ws_size,
                              hipStream_t stream) {
  float* out = (float*)d_out;
  char* base = (char*)d_ws;
  size_t off = 0;
  auto alloc = [&](size_t bytes) {
    void* pp = base + off;
    off = (off + bytes + 255) & ~(size_t)255;
    return pp;
  };

  int* flag = (int*)alloc(256);
  float* biasAll = (float*)alloc(515 * 4);
  float* beB1f = biasAll + 0;
  float* beB2f = biasAll + 64;
  float* beTf  = biasAll + 192;
  float* bdTf  = biasAll + 320;
  float* bd1f  = biasAll + 448;
  float* bd2f  = biasAll + 512;
  float* sqAll = (float*)alloc(1024 * 4);
  float* sqT = sqAll, *sqB = sqAll + 512;
  float* pTop = (float*)alloc(256 * 4);
  float* pBot = (float*)alloc(256 * 4);
  bf16* Wc1  = (bf16*)alloc((size_t)4096 * 2);
  bf16* Wt2f = (bf16*)alloc((size_t)131072 * 2);
  bf16* Wttf = (bf16*)alloc((size_t)262144 * 2);
  bf16* Wdtf = (bf16*)alloc((size_t)262144 * 2);
  bf16* Wd1f = (bf16*)alloc((size_t)262144 * 2);
  bf16* Wfin = (bf16*)alloc((size_t)9216 * 2);
  bf16* embTB = (bf16*)alloc((size_t)131072 * 2);
  bf16* embT = embTB, *embB = embTB + 65536;
  bf16* act1p = (bf16*)alloc((size_t)17305600 * 2);  // [16][130][2][65][64] parity
  bf16* zbp   = (bf16*)alloc((size_t)8921088 * 2);   // [16][66][2][33][128] parity
  bf16* zqtp  = (bf16*)alloc((size_t)2367488 * 2);   // [16][34][34][128]
  bf16* eup   = (bf16*)alloc((size_t)8921088 * 2);   // [16][66][66][128]
  bf16* fqp   = (bf16*)alloc((size_t)8921088 * 2);   // [16][66][66][128]
  bf16* hp    = (bf16*)alloc((size_t)17305600 * 2);  // [16][130][130][64]
  bf16* ztp   = (bf16*)alloc((size_t)2097152 * 2);   // [16][32][32][128]

  // 2 setup launches
  detect_dtype_kernel<<<1, 256, 0, stream>>>(d_in[0], flag);
  setup_all<<<5835, 256, 0, stream>>>(
      d_in[2], d_in[4], d_in[6], d_in[10], d_in[12], d_in[14],
      d_in[7], d_in[8], d_in[1], d_in[13], d_in[11], d_in[3],
      d_in[5], d_in[9],
      biasAll, embTB, sqAll, Wc1, Wfin, Wd1f, Wt2f, Wttf, Wdtf, flag,
      act1p, hp, zbp, eup, fqp, zqtp);

  // encoder: conv1 = LDS-staged im2col + MFMA GEMM (parity-split store)
  gemm1_lds<<<2048, 256, 0, stream>>>(d_in[0], flag, Wc1, beB1f, act1p);
  // conv2: LDS-staged + T14, 4 waves/block (co-quartered), 1024 x 256 thr
  conv2_lds<<<dim3(64, 1, 16), 256, 0, stream>>>(act1p, Wt2f, beB2f, zbp);
  // conv_t: PXW=33 (zbp parity), output ztp row-major
  mfma_conv<128, 128, 32, 2, 16, 128, 2, 33><<<dim3(16, 2, 16), 256, 0, stream>>>(
      zbp, zbp, 557568, 8448, Wttf, beTf, ztp, 131072, 4096, 128, 30, 0, 0, 0);

  // VQ top (16384 positions, row-major): 16 pos/wave -> 256 blocks
  vq_mfma16<<<256, 256, 0, stream>>>(ztp, 131072, 4096, embT, sqT,
                                     zqtp + 4480, 147968, 4352, pTop, 5, 10);

  // decoder_top upsample: 4 classes in one launch (row-major in/out)
  mfma_conv<128, 128, 32, 1, 4, 128, 2, 0><<<dim3(64, 2, 16), 256, 0, stream>>>(
      zqtp, zqtp, 147968, 4352, Wdtf, bdTf, eup, 557568, 16896, 256, 4, 8448, 128, 0);

  // VQ bottom (65536 positions; zbp parity in, fqp row-major out):
  // proven 64 pos/wave ILP-4 structure, per-block partial loss (no atomics)
  vq_mfma<<<256, 256, 0, stream>>>(zbp + 8448, 557568, 8448, embB, sqB,
                                   fqp + 8576, 557568, 8448, pBot, 6, 12, 33);

  // decoder conv d1: 8-wave blocks, wave=(class,row), 512 blocks x 512 thr
  mfma_d1_lds<<<dim3(32, 1, 16), 512, 0, stream>>>(fqp, eup, Wd1f, bd1f, hp);

  // final convT + sigmoid via MFMA -> fp32 NCHW output
  final_convt_mfma<<<1024, 256, 0, stream>>>(hp, Wfin, bd2f, out);
  finalize_loss_kernel<<<1, 256, 0, stream>>>(pTop, pBot, out + 3145728);
}

// Round 12
// 391.554 us; speedup vs baseline: 1.2487x; 1.0341x over previous
//
#include <hip/hip_runtime.h>
#include <hip/hip_bf16.h>
#include <cstddef>

typedef __hip_bfloat16 bf16;
typedef __attribute__((ext_vector_type(8))) short short8;
typedef __attribute__((ext_vector_type(4))) float float4v;
typedef __attribute__((ext_vector_type(4))) unsigned short ushort4v;

static __device__ __forceinline__ float b2f(bf16 v) { return __bfloat162float(v); }
static __device__ __forceinline__ float bits2f(unsigned int u) { return __uint_as_float(u); }
static __device__ __forceinline__ unsigned short f2bfbits(float f) {
  bf16 h = __float2bfloat16(f);
  return *reinterpret_cast<unsigned short*>(&h);
}
static __device__ __forceinline__ float ld_any(const void* p, long i, int flag) {
  return flag ? b2f(((const bf16*)p)[i]) : ((const float*)p)[i];
}
static __device__ __forceinline__ void unpack_u4(uint4 u, float* f) {
  f[0] = bits2f(u.x << 16); f[1] = bits2f(u.x & 0xffff0000u);
  f[2] = bits2f(u.y << 16); f[3] = bits2f(u.y & 0xffff0000u);
  f[4] = bits2f(u.z << 16); f[5] = bits2f(u.z & 0xffff0000u);
  f[6] = bits2f(u.w << 16); f[7] = bits2f(u.w & 0xffff0000u);
}

// --------------------------------------------------------- dtype detection
__global__ void detect_dtype_kernel(const void* __restrict__ x, int* __restrict__ flag) {
  __shared__ int ok;
  if (threadIdx.x == 0) ok = 1;
  __syncthreads();
  float v = b2f(((const bf16*)x)[threadIdx.x]);
  if (!(v >= 0.f && v <= 1.0009765625f)) ok = 0;
  __syncthreads();
  if (threadIdx.x == 0) *flag = ok;
}

// ------------------------------------------------- halo-ring zeroing helper
static __device__ __forceinline__ void halo_seg(bf16* p0, bf16* p1, bf16* p2,
                                                int np, int H, int W, int C8,
                                                long imgS, int gpi, int r) {
  int total = 16 * gpi;
  int which = r / total;
  if (which >= np) return;
  int rr = r - which * total;
  int img = rr / gpi, g = rr % gpi;
  int pos = g / C8, c8 = g % C8;
  int row, col;
  if (pos < W) { row = 0; col = pos; }
  else if (pos < 2 * W) { row = H - 1; col = pos - W; }
  else { int s = pos - 2 * W; row = 1 + (s >> 1); col = (s & 1) ? (W - 1) : 0; }
  bf16* base = (which == 0) ? p0 : ((which == 1) ? p1 : p2);
  uint4* dst = (uint4*)(base + (long)img * imgS + ((long)row * W + col) * (C8 * 8) + (long)c8 * 8);
  *dst = uint4{0u, 0u, 0u, 0u};
}

// ---------------- all converts / repacks + halo zeroing in one kernel.
__global__ __launch_bounds__(256) void setup_all(
    const void* s2, const void* s4, const void* s6,
    const void* s10, const void* s12, const void* s14,
    const void* sT, const void* sB, const void* c1s,
    const void* fins, const void* d1s, const void* t2s,
    const void* tts, const void* dts,
    float* __restrict__ biasAll, bf16* __restrict__ embTB,
    float* __restrict__ sqAll, bf16* __restrict__ Wc1,
    bf16* __restrict__ Wfin, bf16* __restrict__ Wd1f,
    bf16* __restrict__ Wt2f, bf16* __restrict__ Wttf,
    bf16* __restrict__ Wdtf, const int* __restrict__ flag,
    bf16* act1p, bf16* hp, bf16* zbp, bf16* eup, bf16* fqp, bf16* zqtp) {
  long i = (long)blockIdx.x * 256 + threadIdx.x;
  const int fl = *flag;
  // seg0: emb row sum-of-squares, wave-parallel [65536 = 1024 rows x 64 lanes]
  if (i < 65536) {
    int k = (int)(i >> 6), lane = (int)(i & 63);
    const void* s = (k < 512) ? sT : sB;
    long base = (long)(k & 511) * 128 + lane * 2;
    float v0 = b2f(__float2bfloat16(ld_any(s, base, fl)));
    float v1 = b2f(__float2bfloat16(ld_any(s, base + 1, fl)));
    float acc = fmaf(v1, v1, v0 * v0);
    #pragma unroll
    for (int o = 32; o > 0; o >>= 1) acc += __shfl_down(acc, o, 64);
    if (lane == 0) sqAll[k] = acc;
    return;
  }
  i -= 65536;
  // seg1: 6 conv biases -> one fp32 buffer [515]
  if (i < 515) {
    const void* s; long off;
    if (i < 64)       { s = s2;  off = i; }
    else if (i < 192) { s = s4;  off = i - 64; }
    else if (i < 320) { s = s6;  off = i - 192; }
    else if (i < 448) { s = s10; off = i - 320; }
    else if (i < 512) { s = s12; off = i - 448; }
    else              { s = s14; off = i - 512; }
    biasAll[i] = ld_any(s, off, fl);
    return;
  }
  i -= 515;
  // seg2: both codebooks -> contiguous bf16 [1024][128]
  if (i < 131072) {
    const void* s = (i < 65536) ? sT : sB;
    long off = i & 65535;
    embTB[i] = fl ? ((const bf16*)s)[off] : __float2bfloat16(((const float*)s)[off]);
    return;
  }
  i -= 131072;
  // seg3: conv1 weights [64][3][4][4] -> [co][k], K padded 48->64 [4096]
  if (i < 4096) {
    int co = (int)i >> 6, k = (int)i & 63;
    float v = (k < 48) ? ld_any(c1s, co * 48 + k, fl) : 0.f;
    Wc1[i] = __float2bfloat16(v);
    return;
  }
  i -= 4096;
  // seg4: final convT weights -> A[m=cls*4+co][d=dy*3+dx][64ci] [9216]
  if (i < 9216) {
    int m = (int)i / 576, rem = (int)i % 576;
    int d = rem >> 6, ci = rem & 63;
    int cls = m >> 2, co = m & 3;
    int p = cls >> 1, q = cls & 1;
    int dy = d / 3, dx = d % 3;
    int s_ = p - dy + 1, t_ = q - dx + 1;
    float v = 0.f;
    if (co < 3 && s_ >= 0 && s_ <= 1 && t_ >= 0 && t_ <= 1) {
      int kh = 2 * s_ + 1 - p, kw = 2 * t_ + 1 - q;
      v = ld_any(fins, ci * 48 + co * 16 + kh * 4 + kw, fl);
    }
    Wfin[i] = __float2bfloat16(v);
    return;
  }
  i -= 9216;
  // seg5: d1 weights [256ci][64co][4][4] -> frag [262144]
  if (i < 262144) {
    int low = (int)i & 511;
    int ln = low >> 5, cl = low & 31;
    int c2 = (int)(i >> 9);
    int j = c2 & 3;
    int kc = (c2 >> 2) & 7;
    int t = (c2 >> 5) & 3;
    int cls = c2 >> 7;
    int p = cls >> 1, q = cls & 1;
    int s_ = t >> 1, t2 = t & 1;
    int kh = 2 * s_ + 1 - p, kw = 2 * t2 + 1 - q;
    int co = j * 16 + ln, ci = kc * 32 + cl;
    Wd1f[i] = __float2bfloat16(ld_any(d1s, (long)ci * 1024 + co * 16 + kh * 4 + kw, fl));
    return;
  }
  i -= 262144;
  // seg6: conv2 weights OIHW[128][64][4][4] -> frag direct (MC=4,KC=2) [131072]
  if (i < 131072) {
    int low = (int)i & 511;
    int ln = low >> 5, cl = low & 31;
    int c2 = (int)(i >> 9);
    int j = c2 & 1, c3 = c2 >> 1;
    int kc = c3 & 1, c4 = c3 >> 1;
    int mc = c4 & 3, tg = c4 >> 2;
    int co = mc * 32 + j * 16 + ln, ci = kc * 32 + cl;
    Wt2f[i] = __float2bfloat16(ld_any(t2s, (long)co * 1024 + ci * 16 + tg, fl));
    return;
  }
  i -= 131072;
  // seg7: conv_t weights OIHW[128][128][4][4] -> frag direct (MC=4,KC=4) [262144]
  if (i < 262144) {
    int low = (int)i & 511;
    int ln = low >> 5, cl = low & 31;
    int c2 = (int)(i >> 9);
    int j = c2 & 1, c3 = c2 >> 1;
    int kc = c3 & 3, c4 = c3 >> 2;
    int mc = c4 & 3, tg = c4 >> 2;
    int co = mc * 32 + j * 16 + ln, ci = kc * 32 + cl;
    Wttf[i] = __float2bfloat16(ld_any(tts, (long)co * 2048 + ci * 16 + tg, fl));
    return;
  }
  i -= 262144;
  // seg8: convT dt weights [128ci][128co][4][4] -> class frag direct [262144]
  if (i < 262144) {
    int low = (int)i & 511;
    int ln = low >> 5, cl = low & 31;
    int c2 = (int)(i >> 9);
    int j = c2 & 1, c3 = c2 >> 1;
    int kc = c3 & 3, c4 = c3 >> 2;
    int mc = c4 & 3, tg = c4 >> 2;
    int co = mc * 32 + j * 16 + ln, ci = kc * 32 + cl;
    int cls = tg >> 2, st = tg & 3;
    int p = cls >> 1, q = cls & 1;
    int s_ = st >> 1, tt_ = st & 1;
    int kh = 2 * s_ + 1 - p, kw = 2 * tt_ + 1 - q;
    Wdtf[i] = __float2bfloat16(ld_any(dts, (long)ci * 2048 + co * 16 + kh * 4 + kw, fl));
    return;
  }
  i -= 262144;
  // seg9-11: halo-ring zeroing (independent of flag)
  if (i < 132096) { halo_seg(act1p, hp, nullptr, 2, 130, 130, 8, 1081600, 4128, (int)i); return; }
  i -= 132096;
  if (i < 199680) { halo_seg(zbp, eup, fqp, 3, 66, 66, 16, 557568, 4160, (int)i); return; }
  i -= 199680;
  if (i < 33792)  { halo_seg(zqtp, nullptr, nullptr, 1, 34, 34, 16, 147968, 2112, (int)i); }
}

// -------------------- conv1: LDS-staged im2col + MFMA GEMM.
__global__ __launch_bounds__(256) void gemm1_lds(
    const void* __restrict__ x, const int* __restrict__ flag,
    const bf16* __restrict__ w, const float* __restrict__ bias,
    bf16* __restrict__ act1p) {
  __shared__ unsigned short xs[3 * 4 * 260];   // [ci][r][px], px = iw+1
  const int lane = threadIdx.x & 63, wv = threadIdx.x >> 6;
  const int wm = wv & 1, wn = wv >> 1;
  const int ln = lane & 15, quad = lane >> 4;
  const int n0 = blockIdx.x * 128;
  const int oh = (n0 >> 7) & 127, b = n0 >> 14;
  const int fl = *flag;
  const int ih0 = 2 * oh - 1;

  for (int i = threadIdx.x; i < 3120; i += 256) {
    int px = i % 260;
    int t = i / 260;
    int r = t & 3, ci = t >> 2;
    int ih = ih0 + r;
    int iw = px - 1;
    float v = ((unsigned)ih < 256u && (unsigned)iw < 256u)
                ? ld_any(x, (((long)(b * 3 + ci)) << 16) + ((long)ih << 8) + iw, fl) : 0.f;
    xs[i] = f2bfbits(v);
  }
  __syncthreads();

  float4v acc[2][4];
  #pragma unroll
  for (int i = 0; i < 2; ++i)
    #pragma unroll
    for (int j = 0; j < 4; ++j) acc[i][j] = {0.f, 0.f, 0.f, 0.f};

  const int ow_base = wn * 64;
  #pragma unroll
  for (int kc = 0; kc < 2; ++kc) {
    const bf16* wk = w + (wm * 32 + ln) * 64 + kc * 32 + quad * 8;
    short8 a0 = *(const short8*)(wk);
    short8 a1 = *(const short8*)(wk + 16 * 64);
    const int k0 = kc * 32 + quad * 8;      // 0,8,...,56; >=48 is zero-pad
    const int ci = k0 >> 4;
    const int kh0 = (k0 & 15) >> 2;         // 0 or 2
    #pragma unroll
    for (int bf = 0; bf < 4; ++bf) {
      short8 bv;
      if (k0 >= 48) {
        bv = (short8){0, 0, 0, 0, 0, 0, 0, 0};
      } else {
        int ow = ow_base + bf * 16 + ln;
        union { uint2 u2[2]; short8 s8; } u;
        u.u2[0] = *(const uint2*)(xs + (ci * 4 + kh0) * 260 + ow * 2);
        u.u2[1] = *(const uint2*)(xs + (ci * 4 + kh0 + 1) * 260 + ow * 2);
        bv = u.s8;
      }
      acc[0][bf] = __builtin_amdgcn_mfma_f32_16x16x32_bf16(a0, bv, acc[0][bf], 0, 0, 0);
      acc[1][bf] = __builtin_amdgcn_mfma_f32_16x16x32_bf16(a1, bv, acc[1][bf], 0, 0, 0);
    }
  }
  #pragma unroll
  for (int mf = 0; mf < 2; ++mf) {
    int coB = wm * 32 + mf * 16 + quad * 4;
    float4v bv4 = *(const float4v*)(bias + coB);
    #pragma unroll
    for (int bf = 0; bf < 4; ++bf) {
      int ow = ow_base + bf * 16 + ln;
      int xx = ow + 1;   // parity-split column
      long oaddr = ((long)(b * 130 + oh + 1)) * 8320 +
                   (long)(((xx & 1) * 65) + (xx >> 1)) * 64 + coB;
      float4v v = acc[mf][bf];
      ushort4v o;
      #pragma unroll
      for (int e = 0; e < 4; ++e) o[e] = f2bfbits(fmaxf(v[e] + bv4[e], 0.f));
      *(ushort4v*)(act1p + oaddr) = o;
    }
  }
}

// ------------------------------------ MFMA implicit-GEMM tap conv (body)
template <int COUT, int CINT, int TC, int S, int NT, int INC, int NBF, int PXW>
static __device__ __forceinline__ void mfma_conv_body(
    int bx, int by, int bz, int tid,
    const bf16* __restrict__ in1, const bf16* __restrict__ in2,
    long inImgS, int inRowS,
    const bf16* __restrict__ wf, const float* __restrict__ bias,
    bf16* __restrict__ outp, long outImgS, int oRS, int oCS,
    int nxb, long po, long qo, int oPXW) {
  constexpr int TR = (2 * NBF * 16) / TC;
  constexpr int KC = CINT / 32;
  constexpr int MC = COUT / 32;
  constexpr int KSPLIT = (CINT > INC) ? (INC / 32) : KC;
  const int lane = tid & 63;
  const int wv = tid >> 6;
  const int wm = wv & 1, wn = wv >> 1;
  const int ln = lane & 15, quad = lane >> 4;
  const int cls = bx >> nxb;
  const int xb = bx & ((1u << nxb) - 1u);
  const int mTile = by * 64;
  const int mc = by * 2 + wm;
  const int oh0 = xb * TR;
  const int b = bz;
  const int p = cls >> 1, q = cls & 1;
  const long ooff = (long)(p + 1) * po + (long)(q + 1) * qo;

  long posOff[NBF];
  int rr[NBF], cc[NBF];
  #pragma unroll
  for (int bf = 0; bf < NBF; ++bf) {
    int n = wn * (NBF * 16) + bf * 16 + ln;
    int r = n / TC, c = n % TC;
    rr[bf] = r; cc[bf] = c;
    posOff[bf] = (long)(S * (oh0 + r)) * inRowS +
                 (PXW ? (long)c * INC : (long)(S * c) * INC);
  }
  const bf16* inb1 = in1 + (long)b * inImgS;
  const bf16* inb2 = in2 + (long)b * inImgS;

  float4v acc[2][NBF];
  #pragma unroll
  for (int i = 0; i < 2; ++i)
    #pragma unroll
    for (int j = 0; j < NBF; ++j) acc[i][j] = {0.f, 0.f, 0.f, 0.f};

  for (int t = 0; t < NT; ++t) {
    int dy, dx;
    if (S == 2) { dy = t >> 2; dx = t & 3; }
    else        { dy = p - (t >> 1) + 1; dx = q - (t & 1) + 1; }
    const int dxo = PXW ? ((dx & 1) * PXW + (dx >> 1)) : dx;
    const long tapOff = (long)dy * inRowS + (long)dxo * INC;
    const bf16* wt = wf + ((long)(cls * NT + t) * MC + mc) * (KC * 1024) + ln * 32 + quad * 8;
    #pragma unroll
    for (int kc = 0; kc < KC; ++kc) {
      short8 a0 = *(const short8*)(wt + kc * 1024);
      short8 a1 = *(const short8*)(wt + kc * 1024 + 512);
      const bf16* bp = (kc < KSPLIT) ? inb1 : inb2;
      int kOff = (kc < KSPLIT ? kc : kc - KSPLIT) * 32 + quad * 8;
      #pragma unroll
      for (int bf = 0; bf < NBF; ++bf) {
        short8 bv = *(const short8*)(bp + posOff[bf] + tapOff + kOff);
        acc[0][bf] = __builtin_amdgcn_mfma_f32_16x16x32_bf16(a0, bv, acc[0][bf], 0, 0, 0);
        acc[1][bf] = __builtin_amdgcn_mfma_f32_16x16x32_bf16(a1, bv, acc[1][bf], 0, 0, 0);
      }
    }
  }

  bf16* outb = outp + (long)b * outImgS + ooff;
  #pragma unroll
  for (int mf = 0; mf < 2; ++mf) {
    int coB = mTile + wm * 32 + mf * 16 + quad * 4;
    float4v bv4 = *(const float4v*)(bias + coB);
    #pragma unroll
    for (int bf = 0; bf < NBF; ++bf) {
      float4v v = acc[mf][bf];
      ushort4v o;
      #pragma unroll
      for (int e = 0; e < 4; ++e)
        o[e] = f2bfbits(fmaxf(v[e] + bv4[e], 0.f));
      long coff = oPXW ? (long)((((cc[bf] + 1) & 1) * oPXW) + ((cc[bf] + 1) >> 1)) * oCS
                       : (long)cc[bf] * oCS;
      long oaddr = (long)(oh0 + rr[bf]) * oRS + coff + oCS * 0 + coB;
      *(ushort4v*)(outb + oaddr) = o;
    }
  }
}

template <int COUT, int CINT, int TC, int S, int NT, int INC, int NBF, int PXW>
__global__ __launch_bounds__(256) void mfma_conv(
    const bf16* __restrict__ in1, const bf16* __restrict__ in2,
    long inImgS, int inRowS,
    const bf16* __restrict__ wf, const float* __restrict__ bias,
    bf16* __restrict__ outp, long outImgS, int oRS, int oCS,
    int nxb, long po, long qo, int oPXW) {
  mfma_conv_body<COUT, CINT, TC, S, NT, INC, NBF, PXW>(
      blockIdx.x, blockIdx.y, blockIdx.z, threadIdx.x,
      in1, in2, inImgS, inRowS, wf, bias, outp, outImgS, oRS, oCS,
      nxb, po, qo, oPXW);
}

// ---------------------------------------------- VQ 64 pos/wave (body)
// ILP-4 over 4 position fragments; per-block partial loss (no atomics).
static __device__ __forceinline__ void vq_mfma_body(
    int bid, int tid,
    const bf16* __restrict__ z, long zImgS, int zRowS,
    const bf16* __restrict__ emb, const float* __restrict__ embsq,
    bf16* __restrict__ zq, long qImgS, int qRowS,
    float* __restrict__ loss_part, int wb, int hwb, int ipxw) {
  __shared__ float ws[4];
  const int lane = tid & 63, wv = tid >> 6;
  const int ln = lane & 15, quad = lane >> 4;
  const int base = bid * 256 + wv * 64;

  short8 bfrag[4][4];
  #pragma unroll
  for (int bf = 0; bf < 4; ++bf) {
    int n = base + bf * 16 + ln;
    int b = n >> hwb;
    int rem = n & ((1 << hwb) - 1);
    int y = rem >> wb, x = rem & ((1 << wb) - 1);
    int xcol = ipxw ? ((((x + 1) & 1) * ipxw) + ((x + 1) >> 1)) : x;
    const bf16* zrow = z + (long)b * zImgS + (long)y * zRowS + (long)xcol * 128;
    #pragma unroll
    for (int kc = 0; kc < 4; ++kc)
      bfrag[bf][kc] = *(const short8*)(zrow + kc * 32 + quad * 8);
  }

  float best0 = 3.4e38f, best1 = 3.4e38f, best2 = 3.4e38f, best3 = 3.4e38f;
  int bk0 = 0, bk1 = 0, bk2 = 0, bk3 = 0;
  for (int ct = 0; ct < 32; ++ct) {
    const bf16* erow = emb + (long)(ct * 16 + ln) * 128 + quad * 8;
    short8 a0 = *(const short8*)(erow);
    short8 a1 = *(const short8*)(erow + 32);
    short8 a2 = *(const short8*)(erow + 64);
    short8 a3 = *(const short8*)(erow + 96);
    float4v sq4 = *(const float4v*)(embsq + ct * 16 + quad * 4);
    #pragma unroll
    for (int bf = 0; bf < 4; ++bf) {
      float4v acc = {0.f, 0.f, 0.f, 0.f};
      acc = __builtin_amdgcn_mfma_f32_16x16x32_bf16(a0, bfrag[bf][0], acc, 0, 0, 0);
      acc = __builtin_amdgcn_mfma_f32_16x16x32_bf16(a1, bfrag[bf][1], acc, 0, 0, 0);
      acc = __builtin_amdgcn_mfma_f32_16x16x32_bf16(a2, bfrag[bf][2], acc, 0, 0, 0);
      acc = __builtin_amdgcn_mfma_f32_16x16x32_bf16(a3, bfrag[bf][3], acc, 0, 0, 0);
      int kb = ct * 16 + quad * 4;
      #pragma unroll
      for (int r = 0; r < 4; ++r) {
        float s = fmaf(-2.f, acc[r], sq4[r]);
        if (bf == 0) { if (s < best0) { best0 = s; bk0 = kb + r; } }
        if (bf == 1) { if (s < best1) { best1 = s; bk1 = kb + r; } }
        if (bf == 2) { if (s < best2) { best2 = s; bk2 = kb + r; } }
        if (bf == 3) { if (s < best3) { best3 = s; bk3 = kb + r; } }
      }
    }
  }
  float bs[4] = {best0, best1, best2, best3};
  int bk[4] = {bk0, bk1, bk2, bk3};
  #pragma unroll
  for (int bf = 0; bf < 4; ++bf) {
    #pragma unroll
    for (int m = 16; m <= 32; m <<= 1) {
      float os = __shfl_xor(bs[bf], m, 64);
      int ok = __shfl_xor(bk[bf], m, 64);
      if (os < bs[bf] || (os == bs[bf] && ok < bk[bf])) { bs[bf] = os; bk[bf] = ok; }
    }
  }
  int myk = (quad == 0) ? bk[0] : (quad == 1) ? bk[1] : (quad == 2) ? bk[2] : bk[3];
  int n = base + quad * 16 + ln;
  int b = n >> hwb;
  int rem = n & ((1 << hwb) - 1);
  int y = rem >> wb, x = rem & ((1 << wb) - 1);
  int xcol = ipxw ? ((((x + 1) & 1) * ipxw) + ((x + 1) >> 1)) : x;
  const uint4* zr = (const uint4*)(z + (long)b * zImgS + (long)y * zRowS + (long)xcol * 128);
  uint4* qr = (uint4*)(zq + (long)b * qImgS + (long)y * qRowS + (long)x * 128);
  const uint4* er = (const uint4*)(emb + (long)myk * 128);
  float lsum = 0.f;
  #pragma unroll
  for (int j = 0; j < 16; ++j) {
    uint4 ue = er[j];
    uint4 uz = zr[j];
    qr[j] = ue;
    float ev[8], zv[8];
    unpack_u4(ue, ev);
    unpack_u4(uz, zv);
    #pragma unroll
    for (int e = 0; e < 8; ++e) {
      float dv = ev[e] - zv[e];
      lsum = fmaf(dv, dv, lsum);
    }
  }
  for (int o = 32; o > 0; o >>= 1) lsum += __shfl_down(lsum, o, 64);
  if (lane == 0) ws[wv] = lsum;
  __syncthreads();
  if (tid == 0)
    loss_part[bid] = ws[0] + ws[1] + ws[2] + ws[3];
}

// -------- MERGED launch: conv_t (blocks 0..511) || VQ bottom (512..767).
// The two stages are independent (both read zbp, write disjoint buffers);
// running them in one launch overlaps two underfilled, latency-bound
// kernels (2/CU + 1/CU -> 3/CU co-resident) without events/streams.
__global__ __launch_bounds__(256) void convt_vqb(
    const bf16* __restrict__ zbp, const bf16* __restrict__ Wttf,
    const float* __restrict__ beTf, bf16* __restrict__ ztp,
    const bf16* __restrict__ zb_in, const bf16* __restrict__ embB,
    const float* __restrict__ sqB, bf16* __restrict__ fqp_out,
    float* __restrict__ pBot) {
  const int bid = blockIdx.x;
  if (bid < 512) {
    mfma_conv_body<128, 128, 32, 2, 16, 128, 2, 33>(
        bid & 15, (bid >> 4) & 1, bid >> 5, threadIdx.x,
        zbp, zbp, 557568, 8448, Wttf, beTf, ztp, 131072, 4096, 128,
        30, 0, 0, 0);
  } else {
    vq_mfma_body(bid - 512, threadIdx.x, zb_in, 557568, 8448, embB, sqB,
                 fqp_out, 557568, 8448, pBot, 6, 12, 33);
  }
}

// ---------- conv2 (64 -> 128, s2): LDS-staged + T14, 4 waves (co-quartered)
__global__ __launch_bounds__(256) void conv2_lds(
    const bf16* __restrict__ in, const bf16* __restrict__ wf,
    const float* __restrict__ bias, bf16* __restrict__ outp) {
  __shared__ short8 lds8[2 * 130 * 9];   // 37440 B
  const int lane = threadIdx.x & 63;
  const int w = threadIdx.x >> 6;        // co-quarter (wave id, mc=w)
  const int ln = lane & 15, quad = lane >> 4;
  const int oh = blockIdx.x;             // output row 0..63
  const int b = blockIdx.z;

  const bf16* img = in + (long)b * 1081600;
  const short8* s0 = (const short8*)(img + (long)(2 * oh) * 8320);      // rows 2oh,2oh+1
  const short8* s1 = (const short8*)(img + (long)(2 * oh + 2) * 8320);  // rows 2oh+2,2oh+3

  float4v acc[2][4];   // [j (16-co frag)][bf (pos chunk)]
  #pragma unroll
  for (int j = 0; j < 2; ++j)
    #pragma unroll
    for (int bf = 0; bf < 4; ++bf) acc[j][bf] = {0.f, 0.f, 0.f, 0.f};

  auto compute = [&](int f) {
    #pragma unroll
    for (int tl = 0; tl < 8; ++tl) {
      const int t = 8 * f + tl;
      const int r = (t >> 2) & 1;        // row within phase
      const int dx = t & 3;
      const int pp = dx & 1, cb = dx >> 1;
      const int lbase = (r * 130 + pp * 65 + cb) * 9 + quad;
      #pragma unroll
      for (int kc = 0; kc < 2; ++kc) {
        const bf16* wk = wf + (long)((t * 4 + w) * 2 + kc) * 1024 + ln * 32 + quad * 8;
        short8 a0 = *(const short8*)(wk);          // j=0
        short8 a1 = *(const short8*)(wk + 512);    // j=1
        #pragma unroll
        for (int bf = 0; bf < 4; ++bf) {
          short8 bv = lds8[lbase + (bf * 16 + ln) * 9 + kc * 4];
          acc[0][bf] = __builtin_amdgcn_mfma_f32_16x16x32_bf16(a0, bv, acc[0][bf], 0, 0, 0);
          acc[1][bf] = __builtin_amdgcn_mfma_f32_16x16x32_bf16(a1, bv, acc[1][bf], 0, 0, 0);
        }
      }
    }
  };

  // stage phase 0 directly
  for (int i = threadIdx.x; i < 2080; i += 256) {   // 2 rows x 130 pos x 8
    lds8[(i >> 3) * 9 + (i & 7)] = s0[i];
  }
  // T14: issue phase-1 loads now (9 x 16B regs); latency hides under compute(0)
  short8 pre[9];
  #pragma unroll
  for (int it = 0; it < 9; ++it) {
    int i = threadIdx.x + it * 256;
    if (i < 2080) pre[it] = s1[i];
  }
  __syncthreads();
  compute(0);
  __syncthreads();
  #pragma unroll
  for (int it = 0; it < 9; ++it) {
    int i = threadIdx.x + it * 256;
    if (i < 2080) lds8[(i >> 3) * 9 + (i & 7)] = pre[it];
  }
  __syncthreads();
  compute(1);

  // store: zbp parity layout, row oh+1, col map x -> ((x+1)&1)*33 + ((x+1)>>1)
  bf16* outb = outp + (long)b * 557568 + (long)(oh + 1) * 8448;
  #pragma unroll
  for (int j = 0; j < 2; ++j) {
    int co = w * 32 + j * 16 + quad * 4;
    float4v bv4 = *(const float4v*)(bias + co);
    #pragma unroll
    for (int bf = 0; bf < 4; ++bf) {
      int x = bf * 16 + ln;
      int col = (((x + 1) & 1) * 33) + ((x + 1) >> 1);
      float4v v = acc[j][bf];
      ushort4v o;
      #pragma unroll
      for (int e = 0; e < 4; ++e)
        o[e] = f2bfbits(fmaxf(v[e] + bv4[e], 0.f));
      *(ushort4v*)(outb + (long)col * 128 + co) = o;
    }
  }
}

// ------ d1 (concat 256 -> 64): 8-wave blocks, wave = (class, row). Frozen.
__global__ __launch_bounds__(512) void mfma_d1_lds(
    const bf16* __restrict__ in1, const bf16* __restrict__ in2,
    const bf16* __restrict__ wf, const float* __restrict__ bias,
    bf16* __restrict__ outp) {
  __shared__ short8 lds8[264 * 17];   // 4 rows x 66 pos x 16 chunks, pad 17
  const int lane = threadIdx.x & 63, wv = threadIdx.x >> 6;   // 0..7
  const int ln = lane & 15, quad = lane >> 4;
  const int r0 = blockIdx.x * 2;     // output class-rows r0, r0+1
  const int b = blockIdx.z;
  const int cls = wv & 3, rr = wv >> 2;   // wave = (class, row)
  const int p = cls >> 1, q = cls & 1;

  const bf16* src1 = in1 + (long)b * 557568 + (long)r0 * 8448;  // rows r0..r0+3
  const bf16* src2 = in2 + (long)b * 557568 + (long)r0 * 8448;

  float4v acc[4][4];
  #pragma unroll
  for (int j = 0; j < 4; ++j)
    #pragma unroll
    for (int bf = 0; bf < 4; ++bf) acc[j][bf] = {0.f, 0.f, 0.f, 0.f};

  auto compute = [&](int phase) {
    #pragma unroll
    for (int t = 0; t < 4; ++t) {
      int dy = p - (t >> 1) + 1, dx = q - (t & 1) + 1;
      const bf16* wt = wf + (long)(cls * 4 + t) * 16384 + (long)(phase * 4) * 2048 +
                       ln * 32 + quad * 8;
      const int lbase = ((rr + dy) * 66 + dx) * 17 + quad;
      #pragma unroll
      for (int kc = 0; kc < 4; ++kc) {
        const bf16* wk = wt + kc * 2048;
        short8 a0 = *(const short8*)(wk);
        short8 a1 = *(const short8*)(wk + 512);
        short8 a2 = *(const short8*)(wk + 1024);
        short8 a3 = *(const short8*)(wk + 1536);
        #pragma unroll
        for (int bf = 0; bf < 4; ++bf) {
          short8 bv = lds8[lbase + kc * 4 + (bf * 16 + ln) * 17];
          acc[0][bf] = __builtin_amdgcn_mfma_f32_16x16x32_bf16(a0, bv, acc[0][bf], 0, 0, 0);
          acc[1][bf] = __builtin_amdgcn_mfma_f32_16x16x32_bf16(a1, bv, acc[1][bf], 0, 0, 0);
          acc[2][bf] = __builtin_amdgcn_mfma_f32_16x16x32_bf16(a2, bv, acc[2][bf], 0, 0, 0);
          acc[3][bf] = __builtin_amdgcn_mfma_f32_16x16x32_bf16(a3, bv, acc[3][bf], 0, 0, 0);
        }
      }
    }
  };

  // stage phase 0 (fqp): 264 pos x 16 chunks with 512 threads
  for (int i = threadIdx.x; i < 4224; i += 512) {
    lds8[(i >> 4) * 17 + (i & 15)] = *(const short8*)(src1 + (long)(i >> 4) * 128 + (i & 15) * 8);
  }
  // T14: issue phase-1 (eup) loads now; latency hides under compute(0)
  short8 pre[9];
  #pragma unroll
  for (int it = 0; it < 9; ++it) {
    int i = threadIdx.x + it * 512;
    if (i < 4224) pre[it] = *(const short8*)(src2 + (long)(i >> 4) * 128 + (i & 15) * 8);
  }
  __syncthreads();
  compute(0);
  __syncthreads();
  #pragma unroll
  for (int it = 0; it < 9; ++it) {
    int i = threadIdx.x + it * 512;
    if (i < 4224) lds8[(i >> 4) * 17 + (i & 15)] = pre[it];
  }
  __syncthreads();
  compute(1);

  bf16* outb = outp + (long)b * 1081600 + (long)(p + 1) * 8320 + (long)(q + 1) * 64 +
               (long)(r0 + rr) * 16640;
  #pragma unroll
  for (int j = 0; j < 4; ++j) {
    int co = j * 16 + quad * 4;
    float4v bv4 = *(const float4v*)(bias + co);
    #pragma unroll
    for (int bf = 0; bf < 4; ++bf) {
      float4v v = acc[j][bf];
      ushort4v o;
      #pragma unroll
      for (int e = 0; e < 4; ++e)
        o[e] = f2bfbits(fmaxf(v[e] + bv4[e], 0.f));
      *(ushort4v*)(outb + (long)(bf * 16 + ln) * 128 + co) = o;
    }
  }
}

// ---------- VQ, 16 positions/wave (small-N full-chip variant, top only).
__global__ __launch_bounds__(256) void vq_mfma16(
    const bf16* __restrict__ z, long zImgS, int zRowS,
    const bf16* __restrict__ emb, const float* __restrict__ embsq,
    bf16* __restrict__ zq, long qImgS, int qRowS,
    float* __restrict__ loss_part, int wb, int hwb) {
  __shared__ float ws[4];
  const int lane = threadIdx.x & 63, wv = threadIdx.x >> 6;
  const int ln = lane & 15, quad = lane >> 4;
  const int base = blockIdx.x * 64 + wv * 16;   // 16 positions per wave

  const int n = base + ln;
  const int b = n >> hwb;
  const int rem = n & ((1 << hwb) - 1);
  const int y = rem >> wb, x = rem & ((1 << wb) - 1);
  const bf16* zrow = z + (long)b * zImgS + (long)y * zRowS + (long)x * 128;
  short8 bfrag[4];
  #pragma unroll
  for (int kc = 0; kc < 4; ++kc)
    bfrag[kc] = *(const short8*)(zrow + kc * 32 + quad * 8);

  float best = 3.4e38f;
  int bk = 0;
  for (int ct = 0; ct < 32; ++ct) {
    const bf16* erow = emb + (long)(ct * 16 + ln) * 128 + quad * 8;
    short8 a0 = *(const short8*)(erow);
    short8 a1 = *(const short8*)(erow + 32);
    short8 a2 = *(const short8*)(erow + 64);
    short8 a3 = *(const short8*)(erow + 96);
    float4v sq4 = *(const float4v*)(embsq + ct * 16 + quad * 4);
    float4v acc = {0.f, 0.f, 0.f, 0.f};
    acc = __builtin_amdgcn_mfma_f32_16x16x32_bf16(a0, bfrag[0], acc, 0, 0, 0);
    acc = __builtin_amdgcn_mfma_f32_16x16x32_bf16(a1, bfrag[1], acc, 0, 0, 0);
    acc = __builtin_amdgcn_mfma_f32_16x16x32_bf16(a2, bfrag[2], acc, 0, 0, 0);
    acc = __builtin_amdgcn_mfma_f32_16x16x32_bf16(a3, bfrag[3], acc, 0, 0, 0);
    int kb = ct * 16 + quad * 4;
    #pragma unroll
    for (int r = 0; r < 4; ++r) {
      float s = fmaf(-2.f, acc[r], sq4[r]);
      if (s < best) { best = s; bk = kb + r; }
    }
  }
  // reduce across quads (lanes sharing ln)
  #pragma unroll
  for (int m = 16; m <= 32; m <<= 1) {
    float os = __shfl_xor(best, m, 64);
    int ok = __shfl_xor(bk, m, 64);
    if (os < best || (os == best && ok < bk)) { best = os; bk = ok; }
  }
  // copy + loss: quads split the 16 uint4 chunks of position n
  const uint4* zr = (const uint4*)zrow;
  uint4* qr = (uint4*)(zq + (long)b * qImgS + (long)y * qRowS + (long)x * 128);
  const uint4* er = (const uint4*)(emb + (long)bk * 128);
  float lsum = 0.f;
  #pragma unroll
  for (int t = 0; t < 4; ++t) {
    int j = quad * 4 + t;
    uint4 ue = er[j];
    uint4 uz = zr[j];
    qr[j] = ue;
    float ev[8], zv[8];
    unpack_u4(ue, ev);
    unpack_u4(uz, zv);
    #pragma unroll
    for (int e = 0; e < 8; ++e) {
      float dv = ev[e] - zv[e];
      lsum = fmaf(dv, dv, lsum);
    }
  }
  for (int o = 32; o > 0; o >>= 1) lsum += __shfl_down(lsum, o, 64);
  if (lane == 0) ws[wv] = lsum;
  __syncthreads();
  if (threadIdx.x == 0)
    loss_part[blockIdx.x] = ws[0] + ws[1] + ws[2] + ws[3];
}

// --------------------- final convT(64->3)+sigmoid via class-packed MFMA
__global__ __launch_bounds__(256) void final_convt_mfma(
    const bf16* __restrict__ hp, const bf16* __restrict__ wfin,
    const float* __restrict__ bf_, float* __restrict__ out) {
  const int lane = threadIdx.x & 63, wv = threadIdx.x >> 6;
  const int ln = lane & 15, quad = lane >> 4;
  const int base = blockIdx.x * 256 + wv * 64;   // 262144 positions total

  short8 afr[18];
  #pragma unroll
  for (int kc = 0; kc < 18; ++kc)
    afr[kc] = *(const short8*)(wfin + ln * 576 + kc * 32 + quad * 8);

  float4v acc[4];
  #pragma unroll
  for (int bf = 0; bf < 4; ++bf) acc[bf] = {0.f, 0.f, 0.f, 0.f};

  #pragma unroll
  for (int bf = 0; bf < 4; ++bf) {
    int n = base + bf * 16 + ln;
    int xx = n & 127, y = (n >> 7) & 127, b = n >> 14;
    const bf16* hb = hp + (long)b * 1081600 + (long)y * 8320 + (long)xx * 64;
    #pragma unroll
    for (int kc = 0; kc < 18; ++kc) {
      int d = kc >> 1;
      const bf16* bp = hb + (long)(d / 3) * 8320 + (d % 3) * 64 + (kc & 1) * 32 + quad * 8;
      short8 bv = *(const short8*)bp;
      acc[bf] = __builtin_amdgcn_mfma_f32_16x16x32_bf16(afr[kc], bv, acc[bf], 0, 0, 0);
    }
  }

  const int p = quad >> 1, q = quad & 1;
  float b0 = bf_[0], b1 = bf_[1], b2 = bf_[2];
  #pragma unroll
  for (int bf = 0; bf < 4; ++bf) {
    int n = base + bf * 16 + ln;
    int xx = n & 127, y = (n >> 7) & 127, b = n >> 14;
    long ob = (long)b * 196608 + (long)(2 * y + p) * 256 + (2 * xx + q);
    float v0 = acc[bf][0] + b0, v1 = acc[bf][1] + b1, v2 = acc[bf][2] + b2;
    out[ob]          = 1.f / (1.f + expf(-v0));
    out[ob + 65536]  = 1.f / (1.f + expf(-v1));
    out[ob + 131072] = 1.f / (1.f + expf(-v2));
  }
}

// ----------- loss finalize: reduce 2x256 per-block partials (no atomics)
__global__ void finalize_loss_kernel(const float* __restrict__ pTop,
                                     const float* __restrict__ pBot,
                                     float* __restrict__ out) {
  __shared__ float ws[8];
  const int t = threadIdx.x;           // 256 threads
  const int lane = t & 63, wv = t >> 6;
  float a = pTop[t];
  float b = pBot[t];
  #pragma unroll
  for (int o = 32; o > 0; o >>= 1) {
    a += __shfl_down(a, o, 64);
    b += __shfl_down(b, o, 64);
  }
  if (lane == 0) { ws[wv] = a; ws[4 + wv] = b; }
  __syncthreads();
  if (t == 0) {
    float lt = (ws[0] + ws[1] + ws[2] + ws[3]) * (1.5f / 2097152.f);
    float lb = (ws[4] + ws[5] + ws[6] + ws[7]) * (1.5f / 8388608.f);
    *out = lt + lb;
  }
}

// ------------------------------------------------------------------ launch
extern "C" void kernel_launch(void* const* d_in, const int* in_sizes, int n_in,
                              void* d_out, int out_size, void* d_ws, size_t ws_size,
                              hipStream_t stream) {
  float* out = (float*)d_out;
  char* base = (char*)d_ws;
  size_t off = 0;
  auto alloc = [&](size_t bytes) {
    void* pp = base + off;
    off = (off + bytes + 255) & ~(size_t)255;
    return pp;
  };

  int* flag = (int*)alloc(256);
  float* biasAll = (float*)alloc(515 * 4);
  float* beB1f = biasAll + 0;
  float* beB2f = biasAll + 64;
  float* beTf  = biasAll + 192;
  float* bdTf  = biasAll + 320;
  float* bd1f  = biasAll + 448;
  float* bd2f  = biasAll + 512;
  float* sqAll = (float*)alloc(1024 * 4);
  float* sqT = sqAll, *sqB = sqAll + 512;
  float* pTop = (float*)alloc(256 * 4);
  float* pBot = (float*)alloc(256 * 4);
  bf16* Wc1  = (bf16*)alloc((size_t)4096 * 2);
  bf16* Wt2f = (bf16*)alloc((size_t)131072 * 2);
  bf16* Wttf = (bf16*)alloc((size_t)262144 * 2);
  bf16* Wdtf = (bf16*)alloc((size_t)262144 * 2);
  bf16* Wd1f = (bf16*)alloc((size_t)262144 * 2);
  bf16* Wfin = (bf16*)alloc((size_t)9216 * 2);
  bf16* embTB = (bf16*)alloc((size_t)131072 * 2);
  bf16* embT = embTB, *embB = embTB + 65536;
  bf16* act1p = (bf16*)alloc((size_t)17305600 * 2);  // [16][130][2][65][64] parity
  bf16* zbp   = (bf16*)alloc((size_t)8921088 * 2);   // [16][66][2][33][128] parity
  bf16* zqtp  = (bf16*)alloc((size_t)2367488 * 2);   // [16][34][34][128]
  bf16* eup   = (bf16*)alloc((size_t)8921088 * 2);   // [16][66][66][128]
  bf16* fqp   = (bf16*)alloc((size_t)8921088 * 2);   // [16][66][66][128]
  bf16* hp    = (bf16*)alloc((size_t)17305600 * 2);  // [16][130][130][64]
  bf16* ztp   = (bf16*)alloc((size_t)2097152 * 2);   // [16][32][32][128]

  // 2 setup launches
  detect_dtype_kernel<<<1, 256, 0, stream>>>(d_in[0], flag);
  setup_all<<<5835, 256, 0, stream>>>(
      d_in[2], d_in[4], d_in[6], d_in[10], d_in[12], d_in[14],
      d_in[7], d_in[8], d_in[1], d_in[13], d_in[11], d_in[3],
      d_in[5], d_in[9],
      biasAll, embTB, sqAll, Wc1, Wfin, Wd1f, Wt2f, Wttf, Wdtf, flag,
      act1p, hp, zbp, eup, fqp, zqtp);

  // encoder: conv1 = LDS-staged im2col + MFMA GEMM (parity-split store)
  gemm1_lds<<<2048, 256, 0, stream>>>(d_in[0], flag, Wc1, beB1f, act1p);
  // conv2: LDS-staged + T14, 4 waves/block (co-quartered), 1024 x 256 thr
  conv2_lds<<<dim3(64, 1, 16), 256, 0, stream>>>(act1p, Wt2f, beB2f, zbp);

  // MERGED: conv_t (512 blocks) || VQ bottom (256 blocks) -- independent
  // stages, both read zbp; overlap fills 3 blocks/CU vs 2/CU + 1/CU serial
  convt_vqb<<<768, 256, 0, stream>>>(zbp, Wttf, beTf, ztp,
                                     zbp + 8448, embB, sqB, fqp + 8576, pBot);

  // VQ top (16384 positions, row-major): 16 pos/wave -> 256 blocks
  vq_mfma16<<<256, 256, 0, stream>>>(ztp, 131072, 4096, embT, sqT,
                                     zqtp + 4480, 147968, 4352, pTop, 5, 10);

  // decoder_top upsample: 4 classes in one launch (row-major in/out)
  mfma_conv<128, 128, 32, 1, 4, 128, 2, 0><<<dim3(64, 2, 16), 256, 0, stream>>>(
      zqtp, zqtp, 147968, 4352, Wdtf, bdTf, eup, 557568, 16896, 256, 4, 8448, 128, 0);

  // decoder conv d1: 8-wave blocks, wave=(class,row), 512 blocks x 512 thr
  mfma_d1_lds<<<dim3(32, 1, 16), 512, 0, stream>>>(fqp, eup, Wd1f, bd1f, hp);

  // final convT + sigmoid via MFMA -> fp32 NCHW output
  final_convt_mfma<<<1024, 256, 0, stream>>>(hp, Wfin, bd2f, out);
  finalize_loss_kernel<<<1, 256, 0, stream>>>(pTop, pBot, out + 3145728);
}

// Round 14
// 369.973 us; speedup vs baseline: 1.3215x; 1.0583x over previous
//
#include <hip/hip_runtime.h>
#include <hip/hip_bf16.h>
#include <cstddef>

typedef __hip_bfloat16 bf16;
typedef __attribute__((ext_vector_type(8))) short short8;
typedef __attribute__((ext_vector_type(4))) float float4v;
typedef __attribute__((ext_vector_type(4))) unsigned short ushort4v;

static __device__ __forceinline__ float b2f(bf16 v) { return __bfloat162float(v); }
static __device__ __forceinline__ float bits2f(unsigned int u) { return __uint_as_float(u); }
static __device__ __forceinline__ unsigned short f2bfbits(float f) {
  bf16 h = __float2bfloat16(f);
  return *reinterpret_cast<unsigned short*>(&h);
}
static __device__ __forceinline__ float ld_any(const void* p, long i, int flag) {
  return flag ? b2f(((const bf16*)p)[i]) : ((const float*)p)[i];
}
static __device__ __forceinline__ void unpack_u4(uint4 u, float* f) {
  f[0] = bits2f(u.x << 16); f[1] = bits2f(u.x & 0xffff0000u);
  f[2] = bits2f(u.y << 16); f[3] = bits2f(u.y & 0xffff0000u);
  f[4] = bits2f(u.z << 16); f[5] = bits2f(u.z & 0xffff0000u);
  f[6] = bits2f(u.w << 16); f[7] = bits2f(u.w & 0xffff0000u);
}

// --------------------------------------------------------- dtype detection
__global__ void detect_dtype_kernel(const void* __restrict__ x, int* __restrict__ flag) {
  __shared__ int ok;
  if (threadIdx.x == 0) ok = 1;
  __syncthreads();
  float v = b2f(((const bf16*)x)[threadIdx.x]);
  if (!(v >= 0.f && v <= 1.0009765625f)) ok = 0;
  __syncthreads();
  if (threadIdx.x == 0) *flag = ok;
}

// ------------------------------------------------- halo-ring zeroing helper
static __device__ __forceinline__ void halo_seg(bf16* p0, bf16* p1, bf16* p2,
                                                int np, int H, int W, int C8,
                                                long imgS, int gpi, int r) {
  int total = 16 * gpi;
  int which = r / total;
  if (which >= np) return;
  int rr = r - which * total;
  int img = rr / gpi, g = rr % gpi;
  int pos = g / C8, c8 = g % C8;
  int row, col;
  if (pos < W) { row = 0; col = pos; }
  else if (pos < 2 * W) { row = H - 1; col = pos - W; }
  else { int s = pos - 2 * W; row = 1 + (s >> 1); col = (s & 1) ? (W - 1) : 0; }
  bf16* base = (which == 0) ? p0 : ((which == 1) ? p1 : p2);
  uint4* dst = (uint4*)(base + (long)img * imgS + ((long)row * W + col) * (C8 * 8) + (long)c8 * 8);
  *dst = uint4{0u, 0u, 0u, 0u};
}

// ---------------- all converts / repacks + halo zeroing in one kernel.
__global__ __launch_bounds__(256) void setup_all(
    const void* s2, const void* s4, const void* s6,
    const void* s10, const void* s12, const void* s14,
    const void* sT, const void* sB, const void* c1s,
    const void* fins, const void* d1s, const void* t2s,
    const void* tts, const void* dts,
    float* __restrict__ biasAll, bf16* __restrict__ embTB,
    float* __restrict__ sqAll, bf16* __restrict__ Wc1,
    bf16* __restrict__ Wfin, bf16* __restrict__ Wd1f,
    bf16* __restrict__ Wt2f, bf16* __restrict__ Wttf,
    bf16* __restrict__ Wdtf, const int* __restrict__ flag,
    bf16* act1p, bf16* hp, bf16* zbp, bf16* eup, bf16* fqp, bf16* zqtp) {
  long i = (long)blockIdx.x * 256 + threadIdx.x;
  const int fl = *flag;
  // seg0: emb row sum-of-squares, wave-parallel [65536 = 1024 rows x 64 lanes]
  if (i < 65536) {
    int k = (int)(i >> 6), lane = (int)(i & 63);
    const void* s = (k < 512) ? sT : sB;
    long base = (long)(k & 511) * 128 + lane * 2;
    float v0 = b2f(__float2bfloat16(ld_any(s, base, fl)));
    float v1 = b2f(__float2bfloat16(ld_any(s, base + 1, fl)));
    float acc = fmaf(v1, v1, v0 * v0);
    #pragma unroll
    for (int o = 32; o > 0; o >>= 1) acc += __shfl_down(acc, o, 64);
    if (lane == 0) sqAll[k] = acc;
    return;
  }
  i -= 65536;
  // seg1: 6 conv biases -> one fp32 buffer [515]
  if (i < 515) {
    const void* s; long off;
    if (i < 64)       { s = s2;  off = i; }
    else if (i < 192) { s = s4;  off = i - 64; }
    else if (i < 320) { s = s6;  off = i - 192; }
    else if (i < 448) { s = s10; off = i - 320; }
    else if (i < 512) { s = s12; off = i - 448; }
    else              { s = s14; off = i - 512; }
    biasAll[i] = ld_any(s, off, fl);
    return;
  }
  i -= 515;
  // seg2: both codebooks -> contiguous bf16 [1024][128]
  if (i < 131072) {
    const void* s = (i < 65536) ? sT : sB;
    long off = i & 65535;
    embTB[i] = fl ? ((const bf16*)s)[off] : __float2bfloat16(((const float*)s)[off]);
    return;
  }
  i -= 131072;
  // seg3: conv1 weights [64][3][4][4] -> [co][k], K padded 48->64 [4096]
  if (i < 4096) {
    int co = (int)i >> 6, k = (int)i & 63;
    float v = (k < 48) ? ld_any(c1s, co * 48 + k, fl) : 0.f;
    Wc1[i] = __float2bfloat16(v);
    return;
  }
  i -= 4096;
  // seg4: final convT weights -> A[m=cls*4+co][d=dy*3+dx][64ci] [9216]
  if (i < 9216) {
    int m = (int)i / 576, rem = (int)i % 576;
    int d = rem >> 6, ci = rem & 63;
    int cls = m >> 2, co = m & 3;
    int p = cls >> 1, q = cls & 1;
    int dy = d / 3, dx = d % 3;
    int s_ = p - dy + 1, t_ = q - dx + 1;
    float v = 0.f;
    if (co < 3 && s_ >= 0 && s_ <= 1 && t_ >= 0 && t_ <= 1) {
      int kh = 2 * s_ + 1 - p, kw = 2 * t_ + 1 - q;
      v = ld_any(fins, ci * 48 + co * 16 + kh * 4 + kw, fl);
    }
    Wfin[i] = __float2bfloat16(v);
    return;
  }
  i -= 9216;
  // seg5: d1 weights [256ci][64co][4][4] -> frag [262144]
  if (i < 262144) {
    int low = (int)i & 511;
    int ln = low >> 5, cl = low & 31;
    int c2 = (int)(i >> 9);
    int j = c2 & 3;
    int kc = (c2 >> 2) & 7;
    int t = (c2 >> 5) & 3;
    int cls = c2 >> 7;
    int p = cls >> 1, q = cls & 1;
    int s_ = t >> 1, t2 = t & 1;
    int kh = 2 * s_ + 1 - p, kw = 2 * t2 + 1 - q;
    int co = j * 16 + ln, ci = kc * 32 + cl;
    Wd1f[i] = __float2bfloat16(ld_any(d1s, (long)ci * 1024 + co * 16 + kh * 4 + kw, fl));
    return;
  }
  i -= 262144;
  // seg6: conv2 weights OIHW[128][64][4][4] -> frag direct (MC=4,KC=2) [131072]
  if (i < 131072) {
    int low = (int)i & 511;
    int ln = low >> 5, cl = low & 31;
    int c2 = (int)(i >> 9);
    int j = c2 & 1, c3 = c2 >> 1;
    int kc = c3 & 1, c4 = c3 >> 1;
    int mc = c4 & 3, tg = c4 >> 2;
    int co = mc * 32 + j * 16 + ln, ci = kc * 32 + cl;
    Wt2f[i] = __float2bfloat16(ld_any(t2s, (long)co * 1024 + ci * 16 + tg, fl));
    return;
  }
  i -= 131072;
  // seg7: conv_t weights OIHW[128][128][4][4] -> frag direct (MC=4,KC=4) [262144]
  if (i < 262144) {
    int low = (int)i & 511;
    int ln = low >> 5, cl = low & 31;
    int c2 = (int)(i >> 9);
    int j = c2 & 1, c3 = c2 >> 1;
    int kc = c3 & 3, c4 = c3 >> 2;
    int mc = c4 & 3, tg = c4 >> 2;
    int co = mc * 32 + j * 16 + ln, ci = kc * 32 + cl;
    Wttf[i] = __float2bfloat16(ld_any(tts, (long)co * 2048 + ci * 16 + tg, fl));
    return;
  }
  i -= 262144;
  // seg8: convT dt weights [128ci][128co][4][4] -> class frag direct [262144]
  if (i < 262144) {
    int low = (int)i & 511;
    int ln = low >> 5, cl = low & 31;
    int c2 = (int)(i >> 9);
    int j = c2 & 1, c3 = c2 >> 1;
    int kc = c3 & 3, c4 = c3 >> 2;
    int mc = c4 & 3, tg = c4 >> 2;
    int co = mc * 32 + j * 16 + ln, ci = kc * 32 + cl;
    int cls = tg >> 2, st = tg & 3;
    int p = cls >> 1, q = cls & 1;
    int s_ = st >> 1, tt_ = st & 1;
    int kh = 2 * s_ + 1 - p, kw = 2 * tt_ + 1 - q;
    Wdtf[i] = __float2bfloat16(ld_any(dts, (long)ci * 2048 + co * 16 + kh * 4 + kw, fl));
    return;
  }
  i -= 262144;
  // seg9-11: halo-ring zeroing (independent of flag)
  if (i < 132096) { halo_seg(act1p, hp, nullptr, 2, 130, 130, 8, 1081600, 4128, (int)i); return; }
  i -= 132096;
  if (i < 199680) { halo_seg(zbp, eup, fqp, 3, 66, 66, 16, 557568, 4160, (int)i); return; }
  i -= 199680;
  if (i < 33792)  { halo_seg(zqtp, nullptr, nullptr, 1, 34, 34, 16, 147968, 2112, (int)i); }
}

// -------------------- conv1: LDS-staged im2col + MFMA GEMM.
__global__ __launch_bounds__(256) void gemm1_lds(
    const void* __restrict__ x, const int* __restrict__ flag,
    const bf16* __restrict__ w, const float* __restrict__ bias,
    bf16* __restrict__ act1p) {
  __shared__ unsigned short xs[3 * 4 * 260];   // [ci][r][px], px = iw+1
  const int lane = threadIdx.x & 63, wv = threadIdx.x >> 6;
  const int wm = wv & 1, wn = wv >> 1;
  const int ln = lane & 15, quad = lane >> 4;
  const int n0 = blockIdx.x * 128;
  const int oh = (n0 >> 7) & 127, b = n0 >> 14;
  const int fl = *flag;
  const int ih0 = 2 * oh - 1;

  for (int i = threadIdx.x; i < 3120; i += 256) {
    int px = i % 260;
    int t = i / 260;
    int r = t & 3, ci = t >> 2;
    int ih = ih0 + r;
    int iw = px - 1;
    float v = ((unsigned)ih < 256u && (unsigned)iw < 256u)
                ? ld_any(x, (((long)(b * 3 + ci)) << 16) + ((long)ih << 8) + iw, fl) : 0.f;
    xs[i] = f2bfbits(v);
  }
  __syncthreads();

  float4v acc[2][4];
  #pragma unroll
  for (int i = 0; i < 2; ++i)
    #pragma unroll
    for (int j = 0; j < 4; ++j) acc[i][j] = {0.f, 0.f, 0.f, 0.f};

  const int ow_base = wn * 64;
  #pragma unroll
  for (int kc = 0; kc < 2; ++kc) {
    const bf16* wk = w + (wm * 32 + ln) * 64 + kc * 32 + quad * 8;
    short8 a0 = *(const short8*)(wk);
    short8 a1 = *(const short8*)(wk + 16 * 64);
    const int k0 = kc * 32 + quad * 8;      // 0,8,...,56; >=48 is zero-pad
    const int ci = k0 >> 4;
    const int kh0 = (k0 & 15) >> 2;         // 0 or 2
    #pragma unroll
    for (int bf = 0; bf < 4; ++bf) {
      short8 bv;
      if (k0 >= 48) {
        bv = (short8){0, 0, 0, 0, 0, 0, 0, 0};
      } else {
        int ow = ow_base + bf * 16 + ln;
        union { uint2 u2[2]; short8 s8; } u;
        u.u2[0] = *(const uint2*)(xs + (ci * 4 + kh0) * 260 + ow * 2);
        u.u2[1] = *(const uint2*)(xs + (ci * 4 + kh0 + 1) * 260 + ow * 2);
        bv = u.s8;
      }
      acc[0][bf] = __builtin_amdgcn_mfma_f32_16x16x32_bf16(a0, bv, acc[0][bf], 0, 0, 0);
      acc[1][bf] = __builtin_amdgcn_mfma_f32_16x16x32_bf16(a1, bv, acc[1][bf], 0, 0, 0);
    }
  }
  #pragma unroll
  for (int mf = 0; mf < 2; ++mf) {
    int coB = wm * 32 + mf * 16 + quad * 4;
    float4v bv4 = *(const float4v*)(bias + coB);
    #pragma unroll
    for (int bf = 0; bf < 4; ++bf) {
      int ow = ow_base + bf * 16 + ln;
      int xx = ow + 1;   // parity-split column
      long oaddr = ((long)(b * 130 + oh + 1)) * 8320 +
                   (long)(((xx & 1) * 65) + (xx >> 1)) * 64 + coB;
      float4v v = acc[mf][bf];
      ushort4v o;
      #pragma unroll
      for (int e = 0; e < 4; ++e) o[e] = f2bfbits(fmaxf(v[e] + bv4[e], 0.f));
      *(ushort4v*)(act1p + oaddr) = o;
    }
  }
}

// ------------------------------------ MFMA implicit-GEMM tap conv (body)
template <int COUT, int CINT, int TC, int S, int NT, int INC, int NBF, int PXW>
static __device__ __forceinline__ void mfma_conv_body(
    int bx, int by, int bz, int tid,
    const bf16* __restrict__ in1, const bf16* __restrict__ in2,
    long inImgS, int inRowS,
    const bf16* __restrict__ wf, const float* __restrict__ bias,
    bf16* __restrict__ outp, long outImgS, int oRS, int oCS,
    int nxb, long po, long qo, int oPXW) {
  constexpr int TR = (2 * NBF * 16) / TC;
  constexpr int KC = CINT / 32;
  constexpr int MC = COUT / 32;
  constexpr int KSPLIT = (CINT > INC) ? (INC / 32) : KC;
  const int lane = tid & 63;
  const int wv = tid >> 6;
  const int wm = wv & 1, wn = wv >> 1;
  const int ln = lane & 15, quad = lane >> 4;
  const int cls = bx >> nxb;
  const int xb = bx & ((1u << nxb) - 1u);
  const int mTile = by * 64;
  const int mc = by * 2 + wm;
  const int oh0 = xb * TR;
  const int b = bz;
  const int p = cls >> 1, q = cls & 1;
  const long ooff = (long)(p + 1) * po + (long)(q + 1) * qo;

  long posOff[NBF];
  int rr[NBF], cc[NBF];
  #pragma unroll
  for (int bf = 0; bf < NBF; ++bf) {
    int n = wn * (NBF * 16) + bf * 16 + ln;
    int r = n / TC, c = n % TC;
    rr[bf] = r; cc[bf] = c;
    posOff[bf] = (long)(S * (oh0 + r)) * inRowS +
                 (PXW ? (long)c * INC : (long)(S * c) * INC);
  }
  const bf16* inb1 = in1 + (long)b * inImgS;
  const bf16* inb2 = in2 + (long)b * inImgS;

  float4v acc[2][NBF];
  #pragma unroll
  for (int i = 0; i < 2; ++i)
    #pragma unroll
    for (int j = 0; j < NBF; ++j) acc[i][j] = {0.f, 0.f, 0.f, 0.f};

  for (int t = 0; t < NT; ++t) {
    int dy, dx;
    if (S == 2) { dy = t >> 2; dx = t & 3; }
    else        { dy = p - (t >> 1) + 1; dx = q - (t & 1) + 1; }
    const int dxo = PXW ? ((dx & 1) * PXW + (dx >> 1)) : dx;
    const long tapOff = (long)dy * inRowS + (long)dxo * INC;
    const bf16* wt = wf + ((long)(cls * NT + t) * MC + mc) * (KC * 1024) + ln * 32 + quad * 8;
    #pragma unroll
    for (int kc = 0; kc < KC; ++kc) {
      short8 a0 = *(const short8*)(wt + kc * 1024);
      short8 a1 = *(const short8*)(wt + kc * 1024 + 512);
      const bf16* bp = (kc < KSPLIT) ? inb1 : inb2;
      int kOff = (kc < KSPLIT ? kc : kc - KSPLIT) * 32 + quad * 8;
      #pragma unroll
      for (int bf = 0; bf < NBF; ++bf) {
        short8 bv = *(const short8*)(bp + posOff[bf] + tapOff + kOff);
        acc[0][bf] = __builtin_amdgcn_mfma_f32_16x16x32_bf16(a0, bv, acc[0][bf], 0, 0, 0);
        acc[1][bf] = __builtin_amdgcn_mfma_f32_16x16x32_bf16(a1, bv, acc[1][bf], 0, 0, 0);
      }
    }
  }

  bf16* outb = outp + (long)b * outImgS + ooff;
  #pragma unroll
  for (int mf = 0; mf < 2; ++mf) {
    int coB = mTile + wm * 32 + mf * 16 + quad * 4;
    float4v bv4 = *(const float4v*)(bias + coB);
    #pragma unroll
    for (int bf = 0; bf < NBF; ++bf) {
      float4v v = acc[mf][bf];
      ushort4v o;
      #pragma unroll
      for (int e = 0; e < 4; ++e)
        o[e] = f2bfbits(fmaxf(v[e] + bv4[e], 0.f));
      long coff = oPXW ? (long)((((cc[bf] + 1) & 1) * oPXW) + ((cc[bf] + 1) >> 1)) * oCS
                       : (long)cc[bf] * oCS;
      long oaddr = (long)(oh0 + rr[bf]) * oRS + coff + oCS * 0 + coB;
      *(ushort4v*)(outb + oaddr) = o;
    }
  }
}

template <int COUT, int CINT, int TC, int S, int NT, int INC, int NBF, int PXW>
__global__ __launch_bounds__(256) void mfma_conv(
    const bf16* __restrict__ in1, const bf16* __restrict__ in2,
    long inImgS, int inRowS,
    const bf16* __restrict__ wf, const float* __restrict__ bias,
    bf16* __restrict__ outp, long outImgS, int oRS, int oCS,
    int nxb, long po, long qo, int oPXW) {
  mfma_conv_body<COUT, CINT, TC, S, NT, INC, NBF, PXW>(
      blockIdx.x, blockIdx.y, blockIdx.z, threadIdx.x,
      in1, in2, inImgS, inRowS, wf, bias, outp, outImgS, oRS, oCS,
      nxb, po, qo, oPXW);
}

// ---------------------------------------------- VQ 64 pos/wave (body)
// ILP-4 over 4 position fragments; per-block partial loss (no atomics).
// Codebook scan is LDS-staged: all 4 waves share one double-buffered
// 4 KB tile (256 thr x 16 B = one tile), T14 prefetch of tile ct+1 under
// compute of tile ct; XOR chunk swizzle (chunk ^ (row&7), both sides)
// makes the per-lane ds_read_b128 pattern 2-way (free). Replaces 4x
// redundant dependent L2 load chains per block with throughput LDS reads.
static __device__ __forceinline__ void vq_mfma_body(
    int bid, int tid,
    const bf16* __restrict__ z, long zImgS, int zRowS,
    const bf16* __restrict__ emb, const float* __restrict__ embsq,
    bf16* __restrict__ zq, long qImgS, int qRowS,
    float* __restrict__ loss_part, int wb, int hwb, int ipxw,
    short8 (*etile)[256], float* ws) {
  const int lane = tid & 63, wv = tid >> 6;
  const int ln = lane & 15, quad = lane >> 4;
  const int base = bid * 256 + wv * 64;

  short8 bfrag[4][4];
  #pragma unroll
  for (int bf = 0; bf < 4; ++bf) {
    int n = base + bf * 16 + ln;
    int b = n >> hwb;
    int rem = n & ((1 << hwb) - 1);
    int y = rem >> wb, x = rem & ((1 << wb) - 1);
    int xcol = ipxw ? ((((x + 1) & 1) * ipxw) + ((x + 1) >> 1)) : x;
    const bf16* zrow = z + (long)b * zImgS + (long)y * zRowS + (long)xcol * 128;
    #pragma unroll
    for (int kc = 0; kc < 4; ++kc)
      bfrag[bf][kc] = *(const short8*)(zrow + kc * 32 + quad * 8);
  }

  // stage tile 0: thread -> (row = tid>>4, chunk = tid&15), swizzled dest
  const int srow = tid >> 4, schunk = tid & 15;
  const int sdst = srow * 16 + (schunk ^ (srow & 7));
  etile[0][sdst] = *(const short8*)(emb + (long)srow * 128 + schunk * 8);

  float best0 = 3.4e38f, best1 = 3.4e38f, best2 = 3.4e38f, best3 = 3.4e38f;
  int bk0 = 0, bk1 = 0, bk2 = 0, bk3 = 0;
  const int lb = ln * 16;
  const int x7 = ln & 7;
  for (int ct = 0; ct < 32; ++ct) {
    if (ct == 0) __syncthreads();
    short8 nxt;
    if (ct < 31)
      nxt = *(const short8*)(emb + (long)((ct + 1) * 16 + srow) * 128 + schunk * 8);
    const short8* et = etile[ct & 1];
    short8 a0 = et[lb + ((quad + 0) ^ x7)];
    short8 a1 = et[lb + ((quad + 4) ^ x7)];
    short8 a2 = et[lb + ((quad + 8) ^ x7)];
    short8 a3 = et[lb + ((quad + 12) ^ x7)];
    float4v sq4 = *(const float4v*)(embsq + ct * 16 + quad * 4);
    #pragma unroll
    for (int bf = 0; bf < 4; ++bf) {
      float4v acc = {0.f, 0.f, 0.f, 0.f};
      acc = __builtin_amdgcn_mfma_f32_16x16x32_bf16(a0, bfrag[bf][0], acc, 0, 0, 0);
      acc = __builtin_amdgcn_mfma_f32_16x16x32_bf16(a1, bfrag[bf][1], acc, 0, 0, 0);
      acc = __builtin_amdgcn_mfma_f32_16x16x32_bf16(a2, bfrag[bf][2], acc, 0, 0, 0);
      acc = __builtin_amdgcn_mfma_f32_16x16x32_bf16(a3, bfrag[bf][3], acc, 0, 0, 0);
      int kb = ct * 16 + quad * 4;
      #pragma unroll
      for (int r = 0; r < 4; ++r) {
        float s = fmaf(-2.f, acc[r], sq4[r]);
        if (bf == 0) { if (s < best0) { best0 = s; bk0 = kb + r; } }
        if (bf == 1) { if (s < best1) { best1 = s; bk1 = kb + r; } }
        if (bf == 2) { if (s < best2) { best2 = s; bk2 = kb + r; } }
        if (bf == 3) { if (s < best3) { best3 = s; bk3 = kb + r; } }
      }
    }
    if (ct < 31) etile[(ct + 1) & 1][sdst] = nxt;
    __syncthreads();
  }
  float bs[4] = {best0, best1, best2, best3};
  int bk[4] = {bk0, bk1, bk2, bk3};
  #pragma unroll
  for (int bf = 0; bf < 4; ++bf) {
    #pragma unroll
    for (int m = 16; m <= 32; m <<= 1) {
      float os = __shfl_xor(bs[bf], m, 64);
      int ok = __shfl_xor(bk[bf], m, 64);
      if (os < bs[bf] || (os == bs[bf] && ok < bk[bf])) { bs[bf] = os; bk[bf] = ok; }
    }
  }
  int myk = (quad == 0) ? bk[0] : (quad == 1) ? bk[1] : (quad == 2) ? bk[2] : bk[3];
  int n = base + quad * 16 + ln;
  int b = n >> hwb;
  int rem = n & ((1 << hwb) - 1);
  int y = rem >> wb, x = rem & ((1 << wb) - 1);
  int xcol = ipxw ? ((((x + 1) & 1) * ipxw) + ((x + 1) >> 1)) : x;
  const uint4* zr = (const uint4*)(z + (long)b * zImgS + (long)y * zRowS + (long)xcol * 128);
  uint4* qr = (uint4*)(zq + (long)b * qImgS + (long)y * qRowS + (long)x * 128);
  const uint4* er = (const uint4*)(emb + (long)myk * 128);
  float lsum = 0.f;
  #pragma unroll
  for (int j = 0; j < 16; ++j) {
    uint4 ue = er[j];
    uint4 uz = zr[j];
    qr[j] = ue;
    float ev[8], zv[8];
    unpack_u4(ue, ev);
    unpack_u4(uz, zv);
    #pragma unroll
    for (int e = 0; e < 8; ++e) {
      float dv = ev[e] - zv[e];
      lsum = fmaf(dv, dv, lsum);
    }
  }
  for (int o = 32; o > 0; o >>= 1) lsum += __shfl_down(lsum, o, 64);
  if (lane == 0) ws[wv] = lsum;
  __syncthreads();
  if (tid == 0)
    loss_part[bid] = ws[0] + ws[1] + ws[2] + ws[3];
}

// -------- MERGED launch: conv_t (blocks 0..511) || VQ bottom (512..767).
// Independent stages (both read zbp, write disjoint buffers); overlapping
// fills 3 blocks/CU vs 2/CU + 1/CU serial. Branch is block-uniform so the
// VQ-side barriers are safe.
__global__ __launch_bounds__(256) void convt_vqb(
    const bf16* __restrict__ zbp, const bf16* __restrict__ Wttf,
    const float* __restrict__ beTf, bf16* __restrict__ ztp,
    const bf16* __restrict__ zb_in, const bf16* __restrict__ embB,
    const float* __restrict__ sqB, bf16* __restrict__ fqp_out,
    float* __restrict__ pBot) {
  __shared__ short8 etile[2][256];   // 8 KB codebook double-buffer (VQ half)
  __shared__ float ws[4];
  const int bid = blockIdx.x;
  if (bid < 512) {
    mfma_conv_body<128, 128, 32, 2, 16, 128, 2, 33>(
        bid & 15, (bid >> 4) & 1, bid >> 5, threadIdx.x,
        zbp, zbp, 557568, 8448, Wttf, beTf, ztp, 131072, 4096, 128,
        30, 0, 0, 0);
  } else {
    vq_mfma_body(bid - 512, threadIdx.x, zb_in, 557568, 8448, embB, sqB,
                 fqp_out, 557568, 8448, pBot, 6, 12, 33, etile, ws);
  }
}

// ---------- conv2 (64 -> 128, s2): LDS-staged + T14, 4 waves (co-quartered)
__global__ __launch_bounds__(256) void conv2_lds(
    const bf16* __restrict__ in, const bf16* __restrict__ wf,
    const float* __restrict__ bias, bf16* __restrict__ outp) {
  __shared__ short8 lds8[2 * 130 * 9];   // 37440 B
  const int lane = threadIdx.x & 63;
  const int w = threadIdx.x >> 6;        // co-quarter (wave id, mc=w)
  const int ln = lane & 15, quad = lane >> 4;
  const int oh = blockIdx.x;             // output row 0..63
  const int b = blockIdx.z;

  const bf16* img = in + (long)b * 1081600;
  const short8* s0 = (const short8*)(img + (long)(2 * oh) * 8320);      // rows 2oh,2oh+1
  const short8* s1 = (const short8*)(img + (long)(2 * oh + 2) * 8320);  // rows 2oh+2,2oh+3

  float4v acc[2][4];   // [j (16-co frag)][bf (pos chunk)]
  #pragma unroll
  for (int j = 0; j < 2; ++j)
    #pragma unroll
    for (int bf = 0; bf < 4; ++bf) acc[j][bf] = {0.f, 0.f, 0.f, 0.f};

  auto compute = [&](int f) {
    #pragma unroll
    for (int tl = 0; tl < 8; ++tl) {
      const int t = 8 * f + tl;
      const int r = (t >> 2) & 1;        // row within phase
      const int dx = t & 3;
      const int pp = dx & 1, cb = dx >> 1;
      const int lbase = (r * 130 + pp * 65 + cb) * 9 + quad;
      #pragma unroll
      for (int kc = 0; kc < 2; ++kc) {
        const bf16* wk = wf + (long)((t * 4 + w) * 2 + kc) * 1024 + ln * 32 + quad * 8;
        short8 a0 = *(const short8*)(wk);          // j=0
        short8 a1 = *(const short8*)(wk + 512);    // j=1
        #pragma unroll
        for (int bf = 0; bf < 4; ++bf) {
          short8 bv = lds8[lbase + (bf * 16 + ln) * 9 + kc * 4];
          acc[0][bf] = __builtin_amdgcn_mfma_f32_16x16x32_bf16(a0, bv, acc[0][bf], 0, 0, 0);
          acc[1][bf] = __builtin_amdgcn_mfma_f32_16x16x32_bf16(a1, bv, acc[1][bf], 0, 0, 0);
        }
      }
    }
  };

  // stage phase 0 directly
  for (int i = threadIdx.x; i < 2080; i += 256) {   // 2 rows x 130 pos x 8
    lds8[(i >> 3) * 9 + (i & 7)] = s0[i];
  }
  // T14: issue phase-1 loads now (9 x 16B regs); latency hides under compute(0)
  short8 pre[9];
  #pragma unroll
  for (int it = 0; it < 9; ++it) {
    int i = threadIdx.x + it * 256;
    if (i < 2080) pre[it] = s1[i];
  }
  __syncthreads();
  compute(0);
  __syncthreads();
  #pragma unroll
  for (int it = 0; it < 9; ++it) {
    int i = threadIdx.x + it * 256;
    if (i < 2080) lds8[(i >> 3) * 9 + (i & 7)] = pre[it];
  }
  __syncthreads();
  compute(1);

  // store: zbp parity layout, row oh+1, col map x -> ((x+1)&1)*33 + ((x+1)>>1)
  bf16* outb = outp + (long)b * 557568 + (long)(oh + 1) * 8448;
  #pragma unroll
  for (int j = 0; j < 2; ++j) {
    int co = w * 32 + j * 16 + quad * 4;
    float4v bv4 = *(const float4v*)(bias + co);
    #pragma unroll
    for (int bf = 0; bf < 4; ++bf) {
      int x = bf * 16 + ln;
      int col = (((x + 1) & 1) * 33) + ((x + 1) >> 1);
      float4v v = acc[j][bf];
      ushort4v o;
      #pragma unroll
      for (int e = 0; e < 4; ++e)
        o[e] = f2bfbits(fmaxf(v[e] + bv4[e], 0.f));
      *(ushort4v*)(outb + (long)col * 128 + co) = o;
    }
  }
}

// ------ d1 (concat 256 -> 64): 8-wave blocks, wave = (class, row). Frozen.
__global__ __launch_bounds__(512) void mfma_d1_lds(
    const bf16* __restrict__ in1, const bf16* __restrict__ in2,
    const bf16* __restrict__ wf, const float* __restrict__ bias,
    bf16* __restrict__ outp) {
  __shared__ short8 lds8[264 * 17];   // 4 rows x 66 pos x 16 chunks, pad 17
  const int lane = threadIdx.x & 63, wv = threadIdx.x >> 6;   // 0..7
  const int ln = lane & 15, quad = lane >> 4;
  const int r0 = blockIdx.x * 2;     // output class-rows r0, r0+1
  const int b = blockIdx.z;
  const int cls = wv & 3, rr = wv >> 2;   // wave = (class, row)
  const int p = cls >> 1, q = cls & 1;

  const bf16* src1 = in1 + (long)b * 557568 + (long)r0 * 8448;  // rows r0..r0+3
  const bf16* src2 = in2 + (long)b * 557568 + (long)r0 * 8448;

  float4v acc[4][4];
  #pragma unroll
  for (int j = 0; j < 4; ++j)
    #pragma unroll
    for (int bf = 0; bf < 4; ++bf) acc[j][bf] = {0.f, 0.f, 0.f, 0.f};

  auto compute = [&](int phase) {
    #pragma unroll
    for (int t = 0; t < 4; ++t) {
      int dy = p - (t >> 1) + 1, dx = q - (t & 1) + 1;
      const bf16* wt = wf + (long)(cls * 4 + t) * 16384 + (long)(phase * 4) * 2048 +
                       ln * 32 + quad * 8;
      const int lbase = ((rr + dy) * 66 + dx) * 17 + quad;
      #pragma unroll
      for (int kc = 0; kc < 4; ++kc) {
        const bf16* wk = wt + kc * 2048;
        short8 a0 = *(const short8*)(wk);
        short8 a1 = *(const short8*)(wk + 512);
        short8 a2 = *(const short8*)(wk + 1024);
        short8 a3 = *(const short8*)(wk + 1536);
        #pragma unroll
        for (int bf = 0; bf < 4; ++bf) {
          short8 bv = lds8[lbase + kc * 4 + (bf * 16 + ln) * 17];
          acc[0][bf] = __builtin_amdgcn_mfma_f32_16x16x32_bf16(a0, bv, acc[0][bf], 0, 0, 0);
          acc[1][bf] = __builtin_amdgcn_mfma_f32_16x16x32_bf16(a1, bv, acc[1][bf], 0, 0, 0);
          acc[2][bf] = __builtin_amdgcn_mfma_f32_16x16x32_bf16(a2, bv, acc[2][bf], 0, 0, 0);
          acc[3][bf] = __builtin_amdgcn_mfma_f32_16x16x32_bf16(a3, bv, acc[3][bf], 0, 0, 0);
        }
      }
    }
  };

  // stage phase 0 (fqp): 264 pos x 16 chunks with 512 threads
  for (int i = threadIdx.x; i < 4224; i += 512) {
    lds8[(i >> 4) * 17 + (i & 15)] = *(const short8*)(src1 + (long)(i >> 4) * 128 + (i & 15) * 8);
  }
  // T14: issue phase-1 (eup) loads now; latency hides under compute(0)
  short8 pre[9];
  #pragma unroll
  for (int it = 0; it < 9; ++it) {
    int i = threadIdx.x + it * 512;
    if (i < 4224) pre[it] = *(const short8*)(src2 + (long)(i >> 4) * 128 + (i & 15) * 8);
  }
  __syncthreads();
  compute(0);
  __syncthreads();
  #pragma unroll
  for (int it = 0; it < 9; ++it) {
    int i = threadIdx.x + it * 512;
    if (i < 4224) lds8[(i >> 4) * 17 + (i & 15)] = pre[it];
  }
  __syncthreads();
  compute(1);

  bf16* outb = outp + (long)b * 1081600 + (long)(p + 1) * 8320 + (long)(q + 1) * 64 +
               (long)(r0 + rr) * 16640;
  #pragma unroll
  for (int j = 0; j < 4; ++j) {
    int co = j * 16 + quad * 4;
    float4v bv4 = *(const float4v*)(bias + co);
    #pragma unroll
    for (int bf = 0; bf < 4; ++bf) {
      float4v v = acc[j][bf];
      ushort4v o;
      #pragma unroll
      for (int e = 0; e < 4; ++e)
        o[e] = f2bfbits(fmaxf(v[e] + bv4[e], 0.f));
      *(ushort4v*)(outb + (long)(bf * 16 + ln) * 128 + co) = o;
    }
  }
}

// ---------- VQ, 16 positions/wave (small-N full-chip variant, top only).
__global__ __launch_bounds__(256) void vq_mfma16(
    const bf16* __restrict__ z, long zImgS, int zRowS,
    const bf16* __restrict__ emb, const float* __restrict__ embsq,
    bf16* __restrict__ zq, long qImgS, int qRowS,
    float* __restrict__ loss_part, int wb, int hwb) {
  __shared__ float ws[4];
  const int lane = threadIdx.x & 63, wv = threadIdx.x >> 6;
  const int ln = lane & 15, quad = lane >> 4;
  const int base = blockIdx.x * 64 + wv * 16;   // 16 positions per wave

  const int n = base + ln;
  const int b = n >> hwb;
  const int rem = n & ((1 << hwb) - 1);
  const int y = rem >> wb, x = rem & ((1 << wb) - 1);
  const bf16* zrow = z + (long)b * zImgS + (long)y * zRowS + (long)x * 128;
  short8 bfrag[4];
  #pragma unroll
  for (int kc = 0; kc < 4; ++kc)
    bfrag[kc] = *(const short8*)(zrow + kc * 32 + quad * 8);

  float best = 3.4e38f;
  int bk = 0;
  for (int ct = 0; ct < 32; ++ct) {
    const bf16* erow = emb + (long)(ct * 16 + ln) * 128 + quad * 8;
    short8 a0 = *(const short8*)(erow);
    short8 a1 = *(const short8*)(erow + 32);
    short8 a2 = *(const short8*)(erow + 64);
    short8 a3 = *(const short8*)(erow + 96);
    float4v sq4 = *(const float4v*)(embsq + ct * 16 + quad * 4);
    float4v acc = {0.f, 0.f, 0.f, 0.f};
    acc = __builtin_amdgcn_mfma_f32_16x16x32_bf16(a0, bfrag[0], acc, 0, 0, 0);
    acc = __builtin_amdgcn_mfma_f32_16x16x32_bf16(a1, bfrag[1], acc, 0, 0, 0);
    acc = __builtin_amdgcn_mfma_f32_16x16x32_bf16(a2, bfrag[2], acc, 0, 0, 0);
    acc = __builtin_amdgcn_mfma_f32_16x16x32_bf16(a3, bfrag[3], acc, 0, 0, 0);
    int kb = ct * 16 + quad * 4;
    #pragma unroll
    for (int r = 0; r < 4; ++r) {
      float s = fmaf(-2.f, acc[r], sq4[r]);
      if (s < best) { best = s; bk = kb + r; }
    }
  }
  // reduce across quads (lanes sharing ln)
  #pragma unroll
  for (int m = 16; m <= 32; m <<= 1) {
    float os = __shfl_xor(best, m, 64);
    int ok = __shfl_xor(bk, m, 64);
    if (os < best || (os == best && ok < bk)) { best = os; bk = ok; }
  }
  // copy + loss: quads split the 16 uint4 chunks of position n
  const uint4* zr = (const uint4*)zrow;
  uint4* qr = (uint4*)(zq + (long)b * qImgS + (long)y * qRowS + (long)x * 128);
  const uint4* er = (const uint4*)(emb + (long)bk * 128);
  float lsum = 0.f;
  #pragma unroll
  for (int t = 0; t < 4; ++t) {
    int j = quad * 4 + t;
    uint4 ue = er[j];
    uint4 uz = zr[j];
    qr[j] = ue;
    float ev[8], zv[8];
    unpack_u4(ue, ev);
    unpack_u4(uz, zv);
    #pragma unroll
    for (int e = 0; e < 8; ++e) {
      float dv = ev[e] - zv[e];
      lsum = fmaf(dv, dv, lsum);
    }
  }
  for (int o = 32; o > 0; o >>= 1) lsum += __shfl_down(lsum, o, 64);
  if (lane == 0) ws[wv] = lsum;
  __syncthreads();
  if (threadIdx.x == 0)
    loss_part[blockIdx.x] = ws[0] + ws[1] + ws[2] + ws[3];
}

// --------------------- final convT(64->3)+sigmoid via class-packed MFMA
__global__ __launch_bounds__(256) void final_convt_mfma(
    const bf16* __restrict__ hp, const bf16* __restrict__ wfin,
    const float* __restrict__ bf_, float* __restrict__ out) {
  const int lane = threadIdx.x & 63, wv = threadIdx.x >> 6;
  const int ln = lane & 15, quad = lane >> 4;
  const int base = blockIdx.x * 256 + wv * 64;   // 262144 positions total

  short8 afr[18];
  #pragma unroll
  for (int kc = 0; kc < 18; ++kc)
    afr[kc] = *(const short8*)(wfin + ln * 576 + kc * 32 + quad * 8);

  float4v acc[4];
  #pragma unroll
  for (int bf = 0; bf < 4; ++bf) acc[bf] = {0.f, 0.f, 0.f, 0.f};

  #pragma unroll
  for (int bf = 0; bf < 4; ++bf) {
    int n = base + bf * 16 + ln;
    int xx = n & 127, y = (n >> 7) & 127, b = n >> 14;
    const bf16* hb = hp + (long)b * 1081600 + (long)y * 8320 + (long)xx * 64;
    #pragma unroll
    for (int kc = 0; kc < 18; ++kc) {
      int d = kc >> 1;
      const bf16* bp = hb + (long)(d / 3) * 8320 + (d % 3) * 64 + (kc & 1) * 32 + quad * 8;
      short8 bv = *(const short8*)bp;
      acc[bf] = __builtin_amdgcn_mfma_f32_16x16x32_bf16(afr[kc], bv, acc[bf], 0, 0, 0);
    }
  }

  const int p = quad >> 1, q = quad & 1;
  float b0 = bf_[0], b1 = bf_[1], b2 = bf_[2];
  #pragma unroll
  for (int bf = 0; bf < 4; ++bf) {
    int n = base + bf * 16 + ln;
    int xx = n & 127, y = (n >> 7) & 127, b = n >> 14;
    long ob = (long)b * 196608 + (long)(2 * y + p) * 256 + (2 * xx + q);
    float v0 = acc[bf][0] + b0, v1 = acc[bf][1] + b1, v2 = acc[bf][2] + b2;
    out[ob]          = 1.f / (1.f + expf(-v0));
    out[ob + 65536]  = 1.f / (1.f + expf(-v1));
    out[ob + 131072] = 1.f / (1.f + expf(-v2));
  }
}

// ----------- loss finalize: reduce 2x256 per-block partials (no atomics)
__global__ void finalize_loss_kernel(const float* __restrict__ pTop,
                                     const float* __restrict__ pBot,
                                     float* __restrict__ out) {
  __shared__ float ws[8];
  const int t = threadIdx.x;           // 256 threads
  const int lane = t & 63, wv = t >> 6;
  float a = pTop[t];
  float b = pBot[t];
  #pragma unroll
  for (int o = 32; o > 0; o >>= 1) {
    a += __shfl_down(a, o, 64);
    b += __shfl_down(b, o, 64);
  }
  if (lane == 0) { ws[wv] = a; ws[4 + wv] = b; }
  __syncthreads();
  if (t == 0) {
    float lt = (ws[0] + ws[1] + ws[2] + ws[3]) * (1.5f / 2097152.f);
    float lb = (ws[4] + ws[5] + ws[6] + ws[7]) * (1.5f / 8388608.f);
    *out = lt + lb;
  }
}

// ------------------------------------------------------------------ launch
extern "C" void kernel_launch(void* const* d_in, const int* in_sizes, int n_in,
                              void* d_out, int out_size, void* d_ws, size_t ws_size,
                              hipStream_t stream) {
  float* out = (float*)d_out;
  char* base = (char*)d_ws;
  size_t off = 0;
  auto alloc = [&](size_t bytes) {
    void* pp = base + off;
    off = (off + bytes + 255) & ~(size_t)255;
    return pp;
  };

  int* flag = (int*)alloc(256);
  float* biasAll = (float*)alloc(515 * 4);
  float* beB1f = biasAll + 0;
  float* beB2f = biasAll + 64;
  float* beTf  = biasAll + 192;
  float* bdTf  = biasAll + 320;
  float* bd1f  = biasAll + 448;
  float* bd2f  = biasAll + 512;
  float* sqAll = (float*)alloc(1024 * 4);
  float* sqT = sqAll, *sqB = sqAll + 512;
  float* pTop = (float*)alloc(256 * 4);
  float* pBot = (float*)alloc(256 * 4);
  bf16* Wc1  = (bf16*)alloc((size_t)4096 * 2);
  bf16* Wt2f = (bf16*)alloc((size_t)131072 * 2);
  bf16* Wttf = (bf16*)alloc((size_t)262144 * 2);
  bf16* Wdtf = (bf16*)alloc((size_t)262144 * 2);
  bf16* Wd1f = (bf16*)alloc((size_t)262144 * 2);
  bf16* Wfin = (bf16*)alloc((size_t)9216 * 2);
  bf16* embTB = (bf16*)alloc((size_t)131072 * 2);
  bf16* embT = embTB, *embB = embTB + 65536;
  bf16* act1p = (bf16*)alloc((size_t)17305600 * 2);  // [16][130][2][65][64] parity
  bf16* zbp   = (bf16*)alloc((size_t)8921088 * 2);   // [16][66][2][33][128] parity
  bf16* zqtp  = (bf16*)alloc((size_t)2367488 * 2);   // [16][34][34][128]
  bf16* eup   = (bf16*)alloc((size_t)8921088 * 2);   // [16][66][66][128]
  bf16* fqp   = (bf16*)alloc((size_t)8921088 * 2);   // [16][66][66][128]
  bf16* hp    = (bf16*)alloc((size_t)17305600 * 2);  // [16][130][130][64]
  bf16* ztp   = (bf16*)alloc((size_t)2097152 * 2);   // [16][32][32][128]

  // 2 setup launches
  detect_dtype_kernel<<<1, 256, 0, stream>>>(d_in[0], flag);
  setup_all<<<5835, 256, 0, stream>>>(
      d_in[2], d_in[4], d_in[6], d_in[10], d_in[12], d_in[14],
      d_in[7], d_in[8], d_in[1], d_in[13], d_in[11], d_in[3],
      d_in[5], d_in[9],
      biasAll, embTB, sqAll, Wc1, Wfin, Wd1f, Wt2f, Wttf, Wdtf, flag,
      act1p, hp, zbp, eup, fqp, zqtp);

  // encoder: conv1 = LDS-staged im2col + MFMA GEMM (parity-split store)
  gemm1_lds<<<2048, 256, 0, stream>>>(d_in[0], flag, Wc1, beB1f, act1p);
  // conv2: LDS-staged + T14, 4 waves/block (co-quartered), 1024 x 256 thr
  conv2_lds<<<dim3(64, 1, 16), 256, 0, stream>>>(act1p, Wt2f, beB2f, zbp);

  // MERGED: conv_t (512 blocks) || VQ bottom (256 blocks, LDS codebook scan)
  convt_vqb<<<768, 256, 0, stream>>>(zbp, Wttf, beTf, ztp,
                                     zbp + 8448, embB, sqB, fqp + 8576, pBot);

  // VQ top (16384 positions, row-major): 16 pos/wave -> 256 blocks
  vq_mfma16<<<256, 256, 0, stream>>>(ztp, 131072, 4096, embT, sqT,
                                     zqtp + 4480, 147968, 4352, pTop, 5, 10);

  // decoder_top upsample: 4 classes in one launch (row-major in/out)
  mfma_conv<128, 128, 32, 1, 4, 128, 2, 0><<<dim3(64, 2, 16), 256, 0, stream>>>(
      zqtp, zqtp, 147968, 4352, Wdtf, bdTf, eup, 557568, 16896, 256, 4, 8448, 128, 0);

  // decoder conv d1: 8-wave blocks, wave=(class,row), 512 blocks x 512 thr
  mfma_d1_lds<<<dim3(32, 1, 16), 512, 0, stream>>>(fqp, eup, Wd1f, bd1f, hp);

  // final convT + sigmoid via MFMA -> fp32 NCHW output
  final_convt_mfma<<<1024, 256, 0, stream>>>(hp, Wfin, bd2f, out);
  finalize_loss_kernel<<<1, 256, 0, stream>>>(pTop, pBot, out + 3145728);
}

// Round 15
// 367.599 us; speedup vs baseline: 1.3300x; 1.0065x over previous
//
#include <hip/hip_runtime.h>
#include <hip/hip_bf16.h>
#include <cstddef>

typedef __hip_bfloat16 bf16;
typedef __attribute__((ext_vector_type(8))) short short8;
typedef __attribute__((ext_vector_type(4))) float float4v;
typedef __attribute__((ext_vector_type(4))) unsigned short ushort4v;

static __device__ __forceinline__ float b2f(bf16 v) { return __bfloat162float(v); }
static __device__ __forceinline__ float bits2f(unsigned int u) { return __uint_as_float(u); }
static __device__ __forceinline__ unsigned short f2bfbits(float f) {
  bf16 h = __float2bfloat16(f);
  return *reinterpret_cast<unsigned short*>(&h);
}
static __device__ __forceinline__ float ld_any(const void* p, long i, int flag) {
  return flag ? b2f(((const bf16*)p)[i]) : ((const float*)p)[i];
}
static __device__ __forceinline__ void unpack_u4(uint4 u, float* f) {
  f[0] = bits2f(u.x << 16); f[1] = bits2f(u.x & 0xffff0000u);
  f[2] = bits2f(u.y << 16); f[3] = bits2f(u.y & 0xffff0000u);
  f[4] = bits2f(u.z << 16); f[5] = bits2f(u.z & 0xffff0000u);
  f[6] = bits2f(u.w << 16); f[7] = bits2f(u.w & 0xffff0000u);
}

// --------------------------------------------------------- dtype detection
__global__ void detect_dtype_kernel(const void* __restrict__ x, int* __restrict__ flag) {
  __shared__ int ok;
  if (threadIdx.x == 0) ok = 1;
  __syncthreads();
  float v = b2f(((const bf16*)x)[threadIdx.x]);
  if (!(v >= 0.f && v <= 1.0009765625f)) ok = 0;
  __syncthreads();
  if (threadIdx.x == 0) *flag = ok;
}

// ------------------------------------------------- halo-ring zeroing helper
static __device__ __forceinline__ void halo_seg(bf16* p0, bf16* p1, bf16* p2,
                                                int np, int H, int W, int C8,
                                                long imgS, int gpi, int r) {
  int total = 16 * gpi;
  int which = r / total;
  if (which >= np) return;
  int rr = r - which * total;
  int img = rr / gpi, g = rr % gpi;
  int pos = g / C8, c8 = g % C8;
  int row, col;
  if (pos < W) { row = 0; col = pos; }
  else if (pos < 2 * W) { row = H - 1; col = pos - W; }
  else { int s = pos - 2 * W; row = 1 + (s >> 1); col = (s & 1) ? (W - 1) : 0; }
  bf16* base = (which == 0) ? p0 : ((which == 1) ? p1 : p2);
  uint4* dst = (uint4*)(base + (long)img * imgS + ((long)row * W + col) * (C8 * 8) + (long)c8 * 8);
  *dst = uint4{0u, 0u, 0u, 0u};
}

// ---------------- setupA: small early converts gemm1 depends on (plus the
// tiny late tables): sqAll, biases, codebooks, Wc1, Wfin. [210435 threads]
__global__ __launch_bounds__(256) void setup_a(
    const void* s2, const void* s4, const void* s6,
    const void* s10, const void* s12, const void* s14,
    const void* sT, const void* sB, const void* c1s, const void* fins,
    float* __restrict__ biasAll, bf16* __restrict__ embTB,
    float* __restrict__ sqAll, bf16* __restrict__ Wc1,
    bf16* __restrict__ Wfin, const int* __restrict__ flag) {
  long i = (long)blockIdx.x * 256 + threadIdx.x;
  const int fl = *flag;
  // seg0: emb row sum-of-squares, wave-parallel [65536 = 1024 rows x 64 lanes]
  if (i < 65536) {
    int k = (int)(i >> 6), lane = (int)(i & 63);
    const void* s = (k < 512) ? sT : sB;
    long base = (long)(k & 511) * 128 + lane * 2;
    float v0 = b2f(__float2bfloat16(ld_any(s, base, fl)));
    float v1 = b2f(__float2bfloat16(ld_any(s, base + 1, fl)));
    float acc = fmaf(v1, v1, v0 * v0);
    #pragma unroll
    for (int o = 32; o > 0; o >>= 1) acc += __shfl_down(acc, o, 64);
    if (lane == 0) sqAll[k] = acc;
    return;
  }
  i -= 65536;
  // seg1: 6 conv biases -> one fp32 buffer [515]
  if (i < 515) {
    const void* s; long off;
    if (i < 64)       { s = s2;  off = i; }
    else if (i < 192) { s = s4;  off = i - 64; }
    else if (i < 320) { s = s6;  off = i - 192; }
    else if (i < 448) { s = s10; off = i - 320; }
    else if (i < 512) { s = s12; off = i - 448; }
    else              { s = s14; off = i - 512; }
    biasAll[i] = ld_any(s, off, fl);
    return;
  }
  i -= 515;
  // seg2: both codebooks -> contiguous bf16 [1024][128]
  if (i < 131072) {
    const void* s = (i < 65536) ? sT : sB;
    long off = i & 65535;
    embTB[i] = fl ? ((const bf16*)s)[off] : __float2bfloat16(((const float*)s)[off]);
    return;
  }
  i -= 131072;
  // seg3: conv1 weights [64][3][4][4] -> [co][k], K padded 48->64 [4096]
  if (i < 4096) {
    int co = (int)i >> 6, k = (int)i & 63;
    float v = (k < 48) ? ld_any(c1s, co * 48 + k, fl) : 0.f;
    Wc1[i] = __float2bfloat16(v);
    return;
  }
  i -= 4096;
  // seg4: final convT weights -> A[m=cls*4+co][d=dy*3+dx][64ci] [9216]
  if (i < 9216) {
    int m = (int)i / 576, rem = (int)i % 576;
    int d = rem >> 6, ci = rem & 63;
    int cls = m >> 2, co = m & 3;
    int p = cls >> 1, q = cls & 1;
    int dy = d / 3, dx = d % 3;
    int s_ = p - dy + 1, t_ = q - dx + 1;
    float v = 0.f;
    if (co < 3 && s_ >= 0 && s_ <= 1 && t_ >= 0 && t_ <= 1) {
      int kh = 2 * s_ + 1 - p, kw = 2 * t_ + 1 - q;
      v = ld_any(fins, ci * 48 + co * 16 + kh * 4 + kw, fl);
    }
    Wfin[i] = __float2bfloat16(v);
    return;
  }
}

// ------- heavy repacks + halo zeroing (runs concurrently with gemm1)
static __device__ __forceinline__ void setup_heavy(
    long i, int fl,
    const void* d1s, const void* t2s, const void* tts, const void* dts,
    bf16* __restrict__ Wd1f, bf16* __restrict__ Wt2f,
    bf16* __restrict__ Wttf, bf16* __restrict__ Wdtf,
    bf16* act1p, bf16* hp, bf16* zbp, bf16* eup, bf16* fqp, bf16* zqtp) {
  // seg5: d1 weights [256ci][64co][4][4] -> frag [262144]
  if (i < 262144) {
    int low = (int)i & 511;
    int ln = low >> 5, cl = low & 31;
    int c2 = (int)(i >> 9);
    int j = c2 & 3;
    int kc = (c2 >> 2) & 7;
    int t = (c2 >> 5) & 3;
    int cls = c2 >> 7;
    int p = cls >> 1, q = cls & 1;
    int s_ = t >> 1, t2 = t & 1;
    int kh = 2 * s_ + 1 - p, kw = 2 * t2 + 1 - q;
    int co = j * 16 + ln, ci = kc * 32 + cl;
    Wd1f[i] = __float2bfloat16(ld_any(d1s, (long)ci * 1024 + co * 16 + kh * 4 + kw, fl));
    return;
  }
  i -= 262144;
  // seg6: conv2 weights OIHW[128][64][4][4] -> frag direct (MC=4,KC=2) [131072]
  if (i < 131072) {
    int low = (int)i & 511;
    int ln = low >> 5, cl = low & 31;
    int c2 = (int)(i >> 9);
    int j = c2 & 1, c3 = c2 >> 1;
    int kc = c3 & 1, c4 = c3 >> 1;
    int mc = c4 & 3, tg = c4 >> 2;
    int co = mc * 32 + j * 16 + ln, ci = kc * 32 + cl;
    Wt2f[i] = __float2bfloat16(ld_any(t2s, (long)co * 1024 + ci * 16 + tg, fl));
    return;
  }
  i -= 131072;
  // seg7: conv_t weights OIHW[128][128][4][4] -> frag direct (MC=4,KC=4) [262144]
  if (i < 262144) {
    int low = (int)i & 511;
    int ln = low >> 5, cl = low & 31;
    int c2 = (int)(i >> 9);
    int j = c2 & 1, c3 = c2 >> 1;
    int kc = c3 & 3, c4 = c3 >> 2;
    int mc = c4 & 3, tg = c4 >> 2;
    int co = mc * 32 + j * 16 + ln, ci = kc * 32 + cl;
    Wttf[i] = __float2bfloat16(ld_any(tts, (long)co * 2048 + ci * 16 + tg, fl));
    return;
  }
  i -= 262144;
  // seg8: convT dt weights [128ci][128co][4][4] -> class frag direct [262144]
  if (i < 262144) {
    int low = (int)i & 511;
    int ln = low >> 5, cl = low & 31;
    int c2 = (int)(i >> 9);
    int j = c2 & 1, c3 = c2 >> 1;
    int kc = c3 & 3, c4 = c3 >> 2;
    int mc = c4 & 3, tg = c4 >> 2;
    int co = mc * 32 + j * 16 + ln, ci = kc * 32 + cl;
    int cls = tg >> 2, st = tg & 3;
    int p = cls >> 1, q = cls & 1;
    int s_ = st >> 1, tt_ = st & 1;
    int kh = 2 * s_ + 1 - p, kw = 2 * tt_ + 1 - q;
    Wdtf[i] = __float2bfloat16(ld_any(dts, (long)ci * 2048 + co * 16 + kh * 4 + kw, fl));
    return;
  }
  i -= 262144;
  // halo zeroing (independent of flag; disjoint from gemm1's interior writes)
  if (i < 132096) { halo_seg(act1p, hp, nullptr, 2, 130, 130, 8, 1081600, 4128, (int)i); return; }
  i -= 132096;
  if (i < 199680) { halo_seg(zbp, eup, fqp, 3, 66, 66, 16, 557568, 4160, (int)i); return; }
  i -= 199680;
  if (i < 33792)  { halo_seg(zqtp, nullptr, nullptr, 1, 34, 34, 16, 147968, 2112, (int)i); }
}

// -------------------- conv1 (blocks 0..2047) || heavy setup (2048..7059).
// gemm1 needs only Wc1/biasAll (setup_a); the weight repacks + halo rings
// it runs beside are consumed first by conv2 (next launch). Disjoint writes.
__global__ __launch_bounds__(256) void gemm1_plus(
    const void* __restrict__ x, const int* __restrict__ flag,
    const bf16* __restrict__ w, const float* __restrict__ bias,
    bf16* __restrict__ act1p,
    const void* d1s, const void* t2s, const void* tts, const void* dts,
    bf16* __restrict__ Wd1f, bf16* __restrict__ Wt2f,
    bf16* __restrict__ Wttf, bf16* __restrict__ Wdtf,
    bf16* hp, bf16* zbp, bf16* eup, bf16* fqp, bf16* zqtp) {
  __shared__ unsigned short xs[3 * 4 * 260];   // [ci][r][px], px = iw+1
  if (blockIdx.x >= 2048) {
    long i = (long)(blockIdx.x - 2048) * 256 + threadIdx.x;
    setup_heavy(i, *flag, d1s, t2s, tts, dts, Wd1f, Wt2f, Wttf, Wdtf,
                act1p, hp, zbp, eup, fqp, zqtp);
    return;
  }
  const int lane = threadIdx.x & 63, wv = threadIdx.x >> 6;
  const int wm = wv & 1, wn = wv >> 1;
  const int ln = lane & 15, quad = lane >> 4;
  const int n0 = blockIdx.x * 128;
  const int oh = (n0 >> 7) & 127, b = n0 >> 14;
  const int fl = *flag;
  const int ih0 = 2 * oh - 1;

  for (int i = threadIdx.x; i < 3120; i += 256) {
    int px = i % 260;
    int t = i / 260;
    int r = t & 3, ci = t >> 2;
    int ih = ih0 + r;
    int iw = px - 1;
    float v = ((unsigned)ih < 256u && (unsigned)iw < 256u)
                ? ld_any(x, (((long)(b * 3 + ci)) << 16) + ((long)ih << 8) + iw, fl) : 0.f;
    xs[i] = f2bfbits(v);
  }
  __syncthreads();

  float4v acc[2][4];
  #pragma unroll
  for (int i = 0; i < 2; ++i)
    #pragma unroll
    for (int j = 0; j < 4; ++j) acc[i][j] = {0.f, 0.f, 0.f, 0.f};

  const int ow_base = wn * 64;
  #pragma unroll
  for (int kc = 0; kc < 2; ++kc) {
    const bf16* wk = w + (wm * 32 + ln) * 64 + kc * 32 + quad * 8;
    short8 a0 = *(const short8*)(wk);
    short8 a1 = *(const short8*)(wk + 16 * 64);
    const int k0 = kc * 32 + quad * 8;      // 0,8,...,56; >=48 is zero-pad
    const int ci = k0 >> 4;
    const int kh0 = (k0 & 15) >> 2;         // 0 or 2
    #pragma unroll
    for (int bf = 0; bf < 4; ++bf) {
      short8 bv;
      if (k0 >= 48) {
        bv = (short8){0, 0, 0, 0, 0, 0, 0, 0};
      } else {
        int ow = ow_base + bf * 16 + ln;
        union { uint2 u2[2]; short8 s8; } u;
        u.u2[0] = *(const uint2*)(xs + (ci * 4 + kh0) * 260 + ow * 2);
        u.u2[1] = *(const uint2*)(xs + (ci * 4 + kh0 + 1) * 260 + ow * 2);
        bv = u.s8;
      }
      acc[0][bf] = __builtin_amdgcn_mfma_f32_16x16x32_bf16(a0, bv, acc[0][bf], 0, 0, 0);
      acc[1][bf] = __builtin_amdgcn_mfma_f32_16x16x32_bf16(a1, bv, acc[1][bf], 0, 0, 0);
    }
  }
  #pragma unroll
  for (int mf = 0; mf < 2; ++mf) {
    int coB = wm * 32 + mf * 16 + quad * 4;
    float4v bv4 = *(const float4v*)(bias + coB);
    #pragma unroll
    for (int bf = 0; bf < 4; ++bf) {
      int ow = ow_base + bf * 16 + ln;
      int xx = ow + 1;   // parity-split column
      long oaddr = ((long)(b * 130 + oh + 1)) * 8320 +
                   (long)(((xx & 1) * 65) + (xx >> 1)) * 64 + coB;
      float4v v = acc[mf][bf];
      ushort4v o;
      #pragma unroll
      for (int e = 0; e < 4; ++e) o[e] = f2bfbits(fmaxf(v[e] + bv4[e], 0.f));
      *(ushort4v*)(act1p + oaddr) = o;
    }
  }
}

// ------------------------------------ MFMA implicit-GEMM tap conv (body)
template <int COUT, int CINT, int TC, int S, int NT, int INC, int NBF, int PXW>
static __device__ __forceinline__ void mfma_conv_body(
    int bx, int by, int bz, int tid,
    const bf16* __restrict__ in1, const bf16* __restrict__ in2,
    long inImgS, int inRowS,
    const bf16* __restrict__ wf, const float* __restrict__ bias,
    bf16* __restrict__ outp, long outImgS, int oRS, int oCS,
    int nxb, long po, long qo, int oPXW) {
  constexpr int TR = (2 * NBF * 16) / TC;
  constexpr int KC = CINT / 32;
  constexpr int MC = COUT / 32;
  constexpr int KSPLIT = (CINT > INC) ? (INC / 32) : KC;
  const int lane = tid & 63;
  const int wv = tid >> 6;
  const int wm = wv & 1, wn = wv >> 1;
  const int ln = lane & 15, quad = lane >> 4;
  const int cls = bx >> nxb;
  const int xb = bx & ((1u << nxb) - 1u);
  const int mTile = by * 64;
  const int mc = by * 2 + wm;
  const int oh0 = xb * TR;
  const int b = bz;
  const int p = cls >> 1, q = cls & 1;
  const long ooff = (long)(p + 1) * po + (long)(q + 1) * qo;

  long posOff[NBF];
  int rr[NBF], cc[NBF];
  #pragma unroll
  for (int bf = 0; bf < NBF; ++bf) {
    int n = wn * (NBF * 16) + bf * 16 + ln;
    int r = n / TC, c = n % TC;
    rr[bf] = r; cc[bf] = c;
    posOff[bf] = (long)(S * (oh0 + r)) * inRowS +
                 (PXW ? (long)c * INC : (long)(S * c) * INC);
  }
  const bf16* inb1 = in1 + (long)b * inImgS;
  const bf16* inb2 = in2 + (long)b * inImgS;

  float4v acc[2][NBF];
  #pragma unroll
  for (int i = 0; i < 2; ++i)
    #pragma unroll
    for (int j = 0; j < NBF; ++j) acc[i][j] = {0.f, 0.f, 0.f, 0.f};

  for (int t = 0; t < NT; ++t) {
    int dy, dx;
    if (S == 2) { dy = t >> 2; dx = t & 3; }
    else        { dy = p - (t >> 1) + 1; dx = q - (t & 1) + 1; }
    const int dxo = PXW ? ((dx & 1) * PXW + (dx >> 1)) : dx;
    const long tapOff = (long)dy * inRowS + (long)dxo * INC;
    const bf16* wt = wf + ((long)(cls * NT + t) * MC + mc) * (KC * 1024) + ln * 32 + quad * 8;
    #pragma unroll
    for (int kc = 0; kc < KC; ++kc) {
      short8 a0 = *(const short8*)(wt + kc * 1024);
      short8 a1 = *(const short8*)(wt + kc * 1024 + 512);
      const bf16* bp = (kc < KSPLIT) ? inb1 : inb2;
      int kOff = (kc < KSPLIT ? kc : kc - KSPLIT) * 32 + quad * 8;
      #pragma unroll
      for (int bf = 0; bf < NBF; ++bf) {
        short8 bv = *(const short8*)(bp + posOff[bf] + tapOff + kOff);
        acc[0][bf] = __builtin_amdgcn_mfma_f32_16x16x32_bf16(a0, bv, acc[0][bf], 0, 0, 0);
        acc[1][bf] = __builtin_amdgcn_mfma_f32_16x16x32_bf16(a1, bv, acc[1][bf], 0, 0, 0);
      }
    }
  }

  bf16* outb = outp + (long)b * outImgS + ooff;
  #pragma unroll
  for (int mf = 0; mf < 2; ++mf) {
    int coB = mTile + wm * 32 + mf * 16 + quad * 4;
    float4v bv4 = *(const float4v*)(bias + coB);
    #pragma unroll
    for (int bf = 0; bf < NBF; ++bf) {
      float4v v = acc[mf][bf];
      ushort4v o;
      #pragma unroll
      for (int e = 0; e < 4; ++e)
        o[e] = f2bfbits(fmaxf(v[e] + bv4[e], 0.f));
      long coff = oPXW ? (long)((((cc[bf] + 1) & 1) * oPXW) + ((cc[bf] + 1) >> 1)) * oCS
                       : (long)cc[bf] * oCS;
      long oaddr = (long)(oh0 + rr[bf]) * oRS + coff + oCS * 0 + coB;
      *(ushort4v*)(outb + oaddr) = o;
    }
  }
}

template <int COUT, int CINT, int TC, int S, int NT, int INC, int NBF, int PXW>
__global__ __launch_bounds__(256) void mfma_conv(
    const bf16* __restrict__ in1, const bf16* __restrict__ in2,
    long inImgS, int inRowS,
    const bf16* __restrict__ wf, const float* __restrict__ bias,
    bf16* __restrict__ outp, long outImgS, int oRS, int oCS,
    int nxb, long po, long qo, int oPXW) {
  mfma_conv_body<COUT, CINT, TC, S, NT, INC, NBF, PXW>(
      blockIdx.x, blockIdx.y, blockIdx.z, threadIdx.x,
      in1, in2, inImgS, inRowS, wf, bias, outp, outImgS, oRS, oCS,
      nxb, po, qo, oPXW);
}

// ---------------------------------------------- VQ 64 pos/wave (body)
// LDS-staged double-buffered codebook scan (T14); per-block partial loss.
static __device__ __forceinline__ void vq_mfma_body(
    int bid, int tid,
    const bf16* __restrict__ z, long zImgS, int zRowS,
    const bf16* __restrict__ emb, const float* __restrict__ embsq,
    bf16* __restrict__ zq, long qImgS, int qRowS,
    float* __restrict__ loss_part, int wb, int hwb, int ipxw,
    short8 (*etile)[256], float* ws) {
  const int lane = tid & 63, wv = tid >> 6;
  const int ln = lane & 15, quad = lane >> 4;
  const int base = bid * 256 + wv * 64;

  short8 bfrag[4][4];
  #pragma unroll
  for (int bf = 0; bf < 4; ++bf) {
    int n = base + bf * 16 + ln;
    int b = n >> hwb;
    int rem = n & ((1 << hwb) - 1);
    int y = rem >> wb, x = rem & ((1 << wb) - 1);
    int xcol = ipxw ? ((((x + 1) & 1) * ipxw) + ((x + 1) >> 1)) : x;
    const bf16* zrow = z + (long)b * zImgS + (long)y * zRowS + (long)xcol * 128;
    #pragma unroll
    for (int kc = 0; kc < 4; ++kc)
      bfrag[bf][kc] = *(const short8*)(zrow + kc * 32 + quad * 8);
  }

  const int srow = tid >> 4, schunk = tid & 15;
  const int sdst = srow * 16 + (schunk ^ (srow & 7));
  etile[0][sdst] = *(const short8*)(emb + (long)srow * 128 + schunk * 8);

  float best0 = 3.4e38f, best1 = 3.4e38f, best2 = 3.4e38f, best3 = 3.4e38f;
  int bk0 = 0, bk1 = 0, bk2 = 0, bk3 = 0;
  const int lb = ln * 16;
  const int x7 = ln & 7;
  for (int ct = 0; ct < 32; ++ct) {
    if (ct == 0) __syncthreads();
    short8 nxt;
    if (ct < 31)
      nxt = *(const short8*)(emb + (long)((ct + 1) * 16 + srow) * 128 + schunk * 8);
    const short8* et = etile[ct & 1];
    short8 a0 = et[lb + ((quad + 0) ^ x7)];
    short8 a1 = et[lb + ((quad + 4) ^ x7)];
    short8 a2 = et[lb + ((quad + 8) ^ x7)];
    short8 a3 = et[lb + ((quad + 12) ^ x7)];
    float4v sq4 = *(const float4v*)(embsq + ct * 16 + quad * 4);
    #pragma unroll
    for (int bf = 0; bf < 4; ++bf) {
      float4v acc = {0.f, 0.f, 0.f, 0.f};
      acc = __builtin_amdgcn_mfma_f32_16x16x32_bf16(a0, bfrag[bf][0], acc, 0, 0, 0);
      acc = __builtin_amdgcn_mfma_f32_16x16x32_bf16(a1, bfrag[bf][1], acc, 0, 0, 0);
      acc = __builtin_amdgcn_mfma_f32_16x16x32_bf16(a2, bfrag[bf][2], acc, 0, 0, 0);
      acc = __builtin_amdgcn_mfma_f32_16x16x32_bf16(a3, bfrag[bf][3], acc, 0, 0, 0);
      int kb = ct * 16 + quad * 4;
      #pragma unroll
      for (int r = 0; r < 4; ++r) {
        float s = fmaf(-2.f, acc[r], sq4[r]);
        if (bf == 0) { if (s < best0) { best0 = s; bk0 = kb + r; } }
        if (bf == 1) { if (s < best1) { best1 = s; bk1 = kb + r; } }
        if (bf == 2) { if (s < best2) { best2 = s; bk2 = kb + r; } }
        if (bf == 3) { if (s < best3) { best3 = s; bk3 = kb + r; } }
      }
    }
    if (ct < 31) etile[(ct + 1) & 1][sdst] = nxt;
    __syncthreads();
  }
  float bs[4] = {best0, best1, best2, best3};
  int bk[4] = {bk0, bk1, bk2, bk3};
  #pragma unroll
  for (int bf = 0; bf < 4; ++bf) {
    #pragma unroll
    for (int m = 16; m <= 32; m <<= 1) {
      float os = __shfl_xor(bs[bf], m, 64);
      int ok = __shfl_xor(bk[bf], m, 64);
      if (os < bs[bf] || (os == bs[bf] && ok < bk[bf])) { bs[bf] = os; bk[bf] = ok; }
    }
  }
  int myk = (quad == 0) ? bk[0] : (quad == 1) ? bk[1] : (quad == 2) ? bk[2] : bk[3];
  int n = base + quad * 16 + ln;
  int b = n >> hwb;
  int rem = n & ((1 << hwb) - 1);
  int y = rem >> wb, x = rem & ((1 << wb) - 1);
  int xcol = ipxw ? ((((x + 1) & 1) * ipxw) + ((x + 1) >> 1)) : x;
  const uint4* zr = (const uint4*)(z + (long)b * zImgS + (long)y * zRowS + (long)xcol * 128);
  uint4* qr = (uint4*)(zq + (long)b * qImgS + (long)y * qRowS + (long)x * 128);
  const uint4* er = (const uint4*)(emb + (long)myk * 128);
  float lsum = 0.f;
  #pragma unroll
  for (int j = 0; j < 16; ++j) {
    uint4 ue = er[j];
    uint4 uz = zr[j];
    qr[j] = ue;
    float ev[8], zv[8];
    unpack_u4(ue, ev);
    unpack_u4(uz, zv);
    #pragma unroll
    for (int e = 0; e < 8; ++e) {
      float dv = ev[e] - zv[e];
      lsum = fmaf(dv, dv, lsum);
    }
  }
  for (int o = 32; o > 0; o >>= 1) lsum += __shfl_down(lsum, o, 64);
  if (lane == 0) ws[wv] = lsum;
  __syncthreads();
  if (tid == 0)
    loss_part[bid] = ws[0] + ws[1] + ws[2] + ws[3];
}

// -------- MERGED launch: conv_t (blocks 0..511) || VQ bottom (512..767).
__global__ __launch_bounds__(256) void convt_vqb(
    const bf16* __restrict__ zbp, const bf16* __restrict__ Wttf,
    const float* __restrict__ beTf, bf16* __restrict__ ztp,
    const bf16* __restrict__ zb_in, const bf16* __restrict__ embB,
    const float* __restrict__ sqB, bf16* __restrict__ fqp_out,
    float* __restrict__ pBot) {
  __shared__ short8 etile[2][256];   // 8 KB codebook double-buffer (VQ half)
  __shared__ float ws[4];
  const int bid = blockIdx.x;
  if (bid < 512) {
    mfma_conv_body<128, 128, 32, 2, 16, 128, 2, 33>(
        bid & 15, (bid >> 4) & 1, bid >> 5, threadIdx.x,
        zbp, zbp, 557568, 8448, Wttf, beTf, ztp, 131072, 4096, 128,
        30, 0, 0, 0);
  } else {
    vq_mfma_body(bid - 512, threadIdx.x, zb_in, 557568, 8448, embB, sqB,
                 fqp_out, 557568, 8448, pBot, 6, 12, 33, etile, ws);
  }
}

// ---------- conv2 (64 -> 128, s2): LDS-staged + T14, 4 waves (co-quartered)
__global__ __launch_bounds__(256) void conv2_lds(
    const bf16* __restrict__ in, const bf16* __restrict__ wf,
    const float* __restrict__ bias, bf16* __restrict__ outp) {
  __shared__ short8 lds8[2 * 130 * 9];   // 37440 B
  const int lane = threadIdx.x & 63;
  const int w = threadIdx.x >> 6;        // co-quarter (wave id, mc=w)
  const int ln = lane & 15, quad = lane >> 4;
  const int oh = blockIdx.x;             // output row 0..63
  const int b = blockIdx.z;

  const bf16* img = in + (long)b * 1081600;
  const short8* s0 = (const short8*)(img + (long)(2 * oh) * 8320);      // rows 2oh,2oh+1
  const short8* s1 = (const short8*)(img + (long)(2 * oh + 2) * 8320);  // rows 2oh+2,2oh+3

  float4v acc[2][4];   // [j (16-co frag)][bf (pos chunk)]
  #pragma unroll
  for (int j = 0; j < 2; ++j)
    #pragma unroll
    for (int bf = 0; bf < 4; ++bf) acc[j][bf] = {0.f, 0.f, 0.f, 0.f};

  auto compute = [&](int f) {
    #pragma unroll
    for (int tl = 0; tl < 8; ++tl) {
      const int t = 8 * f + tl;
      const int r = (t >> 2) & 1;        // row within phase
      const int dx = t & 3;
      const int pp = dx & 1, cb = dx >> 1;
      const int lbase = (r * 130 + pp * 65 + cb) * 9 + quad;
      #pragma unroll
      for (int kc = 0; kc < 2; ++kc) {
        const bf16* wk = wf + (long)((t * 4 + w) * 2 + kc) * 1024 + ln * 32 + quad * 8;
        short8 a0 = *(const short8*)(wk);          // j=0
        short8 a1 = *(const short8*)(wk + 512);    // j=1
        #pragma unroll
        for (int bf = 0; bf < 4; ++bf) {
          short8 bv = lds8[lbase + (bf * 16 + ln) * 9 + kc * 4];
          acc[0][bf] = __builtin_amdgcn_mfma_f32_16x16x32_bf16(a0, bv, acc[0][bf], 0, 0, 0);
          acc[1][bf] = __builtin_amdgcn_mfma_f32_16x16x32_bf16(a1, bv, acc[1][bf], 0, 0, 0);
        }
      }
    }
  };

  // stage phase 0 directly
  for (int i = threadIdx.x; i < 2080; i += 256) {   // 2 rows x 130 pos x 8
    lds8[(i >> 3) * 9 + (i & 7)] = s0[i];
  }
  // T14: issue phase-1 loads now (9 x 16B regs); latency hides under compute(0)
  short8 pre[9];
  #pragma unroll
  for (int it = 0; it < 9; ++it) {
    int i = threadIdx.x + it * 256;
    if (i < 2080) pre[it] = s1[i];
  }
  __syncthreads();
  compute(0);
  __syncthreads();
  #pragma unroll
  for (int it = 0; it < 9; ++it) {
    int i = threadIdx.x + it * 256;
    if (i < 2080) lds8[(i >> 3) * 9 + (i & 7)] = pre[it];
  }
  __syncthreads();
  compute(1);

  // store: zbp parity layout, row oh+1, col map x -> ((x+1)&1)*33 + ((x+1)>>1)
  bf16* outb = outp + (long)b * 557568 + (long)(oh + 1) * 8448;
  #pragma unroll
  for (int j = 0; j < 2; ++j) {
    int co = w * 32 + j * 16 + quad * 4;
    float4v bv4 = *(const float4v*)(bias + co);
    #pragma unroll
    for (int bf = 0; bf < 4; ++bf) {
      int x = bf * 16 + ln;
      int col = (((x + 1) & 1) * 33) + ((x + 1) >> 1);
      float4v v = acc[j][bf];
      ushort4v o;
      #pragma unroll
      for (int e = 0; e < 4; ++e)
        o[e] = f2bfbits(fmaxf(v[e] + bv4[e], 0.f));
      *(ushort4v*)(outb + (long)col * 128 + co) = o;
    }
  }
}

// ------ d1 (concat 256 -> 64): 8-wave blocks, wave = (class, row). Frozen.
__global__ __launch_bounds__(512) void mfma_d1_lds(
    const bf16* __restrict__ in1, const bf16* __restrict__ in2,
    const bf16* __restrict__ wf, const float* __restrict__ bias,
    bf16* __restrict__ outp) {
  __shared__ short8 lds8[264 * 17];   // 4 rows x 66 pos x 16 chunks, pad 17
  const int lane = threadIdx.x & 63, wv = threadIdx.x >> 6;   // 0..7
  const int ln = lane & 15, quad = lane >> 4;
  const int r0 = blockIdx.x * 2;     // output class-rows r0, r0+1
  const int b = blockIdx.z;
  const int cls = wv & 3, rr = wv >> 2;   // wave = (class, row)
  const int p = cls >> 1, q = cls & 1;

  const bf16* src1 = in1 + (long)b * 557568 + (long)r0 * 8448;  // rows r0..r0+3
  const bf16* src2 = in2 + (long)b * 557568 + (long)r0 * 8448;

  float4v acc[4][4];
  #pragma unroll
  for (int j = 0; j < 4; ++j)
    #pragma unroll
    for (int bf = 0; bf < 4; ++bf) acc[j][bf] = {0.f, 0.f, 0.f, 0.f};

  auto compute = [&](int phase) {
    #pragma unroll
    for (int t = 0; t < 4; ++t) {
      int dy = p - (t >> 1) + 1, dx = q - (t & 1) + 1;
      const bf16* wt = wf + (long)(cls * 4 + t) * 16384 + (long)(phase * 4) * 2048 +
                       ln * 32 + quad * 8;
      const int lbase = ((rr + dy) * 66 + dx) * 17 + quad;
      #pragma unroll
      for (int kc = 0; kc < 4; ++kc) {
        const bf16* wk = wt + kc * 2048;
        short8 a0 = *(const short8*)(wk);
        short8 a1 = *(const short8*)(wk + 512);
        short8 a2 = *(const short8*)(wk + 1024);
        short8 a3 = *(const short8*)(wk + 1536);
        #pragma unroll
        for (int bf = 0; bf < 4; ++bf) {
          short8 bv = lds8[lbase + kc * 4 + (bf * 16 + ln) * 17];
          acc[0][bf] = __builtin_amdgcn_mfma_f32_16x16x32_bf16(a0, bv, acc[0][bf], 0, 0, 0);
          acc[1][bf] = __builtin_amdgcn_mfma_f32_16x16x32_bf16(a1, bv, acc[1][bf], 0, 0, 0);
          acc[2][bf] = __builtin_amdgcn_mfma_f32_16x16x32_bf16(a2, bv, acc[2][bf], 0, 0, 0);
          acc[3][bf] = __builtin_amdgcn_mfma_f32_16x16x32_bf16(a3, bv, acc[3][bf], 0, 0, 0);
        }
      }
    }
  };

  // stage phase 0 (fqp): 264 pos x 16 chunks with 512 threads
  for (int i = threadIdx.x; i < 4224; i += 512) {
    lds8[(i >> 4) * 17 + (i & 15)] = *(const short8*)(src1 + (long)(i >> 4) * 128 + (i & 15) * 8);
  }
  // T14: issue phase-1 (eup) loads now; latency hides under compute(0)
  short8 pre[9];
  #pragma unroll
  for (int it = 0; it < 9; ++it) {
    int i = threadIdx.x + it * 512;
    if (i < 4224) pre[it] = *(const short8*)(src2 + (long)(i >> 4) * 128 + (i & 15) * 8);
  }
  __syncthreads();
  compute(0);
  __syncthreads();
  #pragma unroll
  for (int it = 0; it < 9; ++it) {
    int i = threadIdx.x + it * 512;
    if (i < 4224) lds8[(i >> 4) * 17 + (i & 15)] = pre[it];
  }
  __syncthreads();
  compute(1);

  bf16* outb = outp + (long)b * 1081600 + (long)(p + 1) * 8320 + (long)(q + 1) * 64 +
               (long)(r0 + rr) * 16640;
  #pragma unroll
  for (int j = 0; j < 4; ++j) {
    int co = j * 16 + quad * 4;
    float4v bv4 = *(const float4v*)(bias + co);
    #pragma unroll
    for (int bf = 0; bf < 4; ++bf) {
      float4v v = acc[j][bf];
      ushort4v o;
      #pragma unroll
      for (int e = 0; e < 4; ++e)
        o[e] = f2bfbits(fmaxf(v[e] + bv4[e], 0.f));
      *(ushort4v*)(outb + (long)(bf * 16 + ln) * 128 + co) = o;
    }
  }
}

// ---------- VQ, 16 positions/wave (small-N full-chip variant, top only).
__global__ __launch_bounds__(256) void vq_mfma16(
    const bf16* __restrict__ z, long zImgS, int zRowS,
    const bf16* __restrict__ emb, const float* __restrict__ embsq,
    bf16* __restrict__ zq, long qImgS, int qRowS,
    float* __restrict__ loss_part, int wb, int hwb) {
  __shared__ float ws[4];
  const int lane = threadIdx.x & 63, wv = threadIdx.x >> 6;
  const int ln = lane & 15, quad = lane >> 4;
  const int base = blockIdx.x * 64 + wv * 16;   // 16 positions per wave

  const int n = base + ln;
  const int b = n >> hwb;
  const int rem = n & ((1 << hwb) - 1);
  const int y = rem >> wb, x = rem & ((1 << wb) - 1);
  const bf16* zrow = z + (long)b * zImgS + (long)y * zRowS + (long)x * 128;
  short8 bfrag[4];
  #pragma unroll
  for (int kc = 0; kc < 4; ++kc)
    bfrag[kc] = *(const short8*)(zrow + kc * 32 + quad * 8);

  float best = 3.4e38f;
  int bk = 0;
  for (int ct = 0; ct < 32; ++ct) {
    const bf16* erow = emb + (long)(ct * 16 + ln) * 128 + quad * 8;
    short8 a0 = *(const short8*)(erow);
    short8 a1 = *(const short8*)(erow + 32);
    short8 a2 = *(const short8*)(erow + 64);
    short8 a3 = *(const short8*)(erow + 96);
    float4v sq4 = *(const float4v*)(embsq + ct * 16 + quad * 4);
    float4v acc = {0.f, 0.f, 0.f, 0.f};
    acc = __builtin_amdgcn_mfma_f32_16x16x32_bf16(a0, bfrag[0], acc, 0, 0, 0);
    acc = __builtin_amdgcn_mfma_f32_16x16x32_bf16(a1, bfrag[1], acc, 0, 0, 0);
    acc = __builtin_amdgcn_mfma_f32_16x16x32_bf16(a2, bfrag[2], acc, 0, 0, 0);
    acc = __builtin_amdgcn_mfma_f32_16x16x32_bf16(a3, bfrag[3], acc, 0, 0, 0);
    int kb = ct * 16 + quad * 4;
    #pragma unroll
    for (int r = 0; r < 4; ++r) {
      float s = fmaf(-2.f, acc[r], sq4[r]);
      if (s < best) { best = s; bk = kb + r; }
    }
  }
  // reduce across quads (lanes sharing ln)
  #pragma unroll
  for (int m = 16; m <= 32; m <<= 1) {
    float os = __shfl_xor(best, m, 64);
    int ok = __shfl_xor(bk, m, 64);
    if (os < best || (os == best && ok < bk)) { best = os; bk = ok; }
  }
  // copy + loss: quads split the 16 uint4 chunks of position n
  const uint4* zr = (const uint4*)zrow;
  uint4* qr = (uint4*)(zq + (long)b * qImgS + (long)y * qRowS + (long)x * 128);
  const uint4* er = (const uint4*)(emb + (long)bk * 128);
  float lsum = 0.f;
  #pragma unroll
  for (int t = 0; t < 4; ++t) {
    int j = quad * 4 + t;
    uint4 ue = er[j];
    uint4 uz = zr[j];
    qr[j] = ue;
    float ev[8], zv[8];
    unpack_u4(ue, ev);
    unpack_u4(uz, zv);
    #pragma unroll
    for (int e = 0; e < 8; ++e) {
      float dv = ev[e] - zv[e];
      lsum = fmaf(dv, dv, lsum);
    }
  }
  for (int o = 32; o > 0; o >>= 1) lsum += __shfl_down(lsum, o, 64);
  if (lane == 0) ws[wv] = lsum;
  __syncthreads();
  if (threadIdx.x == 0)
    loss_part[blockIdx.x] = ws[0] + ws[1] + ws[2] + ws[3];
}

// --------------------- final convT(64->3)+sigmoid (blocks 0..1023)
// block 1024: loss finalize (pTop/pBot ready since vq_top/convt_vqb).
__global__ __launch_bounds__(256) void final_convt_mfma(
    const bf16* __restrict__ hp, const bf16* __restrict__ wfin,
    const float* __restrict__ bf_, float* __restrict__ out,
    const float* __restrict__ pTop, const float* __restrict__ pBot) {
  if (blockIdx.x == 1024) {
    __shared__ float ws[8];
    const int t = threadIdx.x;           // 256 threads
    const int lane = t & 63, wv = t >> 6;
    float a = pTop[t];
    float b = pBot[t];
    #pragma unroll
    for (int o = 32; o > 0; o >>= 1) {
      a += __shfl_down(a, o, 64);
      b += __shfl_down(b, o, 64);
    }
    if (lane == 0) { ws[wv] = a; ws[4 + wv] = b; }
    __syncthreads();
    if (t == 0) {
      float lt = (ws[0] + ws[1] + ws[2] + ws[3]) * (1.5f / 2097152.f);
      float lb = (ws[4] + ws[5] + ws[6] + ws[7]) * (1.5f / 8388608.f);
      out[3145728] = lt + lb;
    }
    return;
  }
  const int lane = threadIdx.x & 63, wv = threadIdx.x >> 6;
  const int ln = lane & 15, quad = lane >> 4;
  const int base = blockIdx.x * 256 + wv * 64;   // 262144 positions total

  short8 afr[18];
  #pragma unroll
  for (int kc = 0; kc < 18; ++kc)
    afr[kc] = *(const short8*)(wfin + ln * 576 + kc * 32 + quad * 8);

  float4v acc[4];
  #pragma unroll
  for (int bf = 0; bf < 4; ++bf) acc[bf] = {0.f, 0.f, 0.f, 0.f};

  #pragma unroll
  for (int bf = 0; bf < 4; ++bf) {
    int n = base + bf * 16 + ln;
    int xx = n & 127, y = (n >> 7) & 127, b = n >> 14;
    const bf16* hb = hp + (long)b * 1081600 + (long)y * 8320 + (long)xx * 64;
    #pragma unroll
    for (int kc = 0; kc < 18; ++kc) {
      int d = kc >> 1;
      const bf16* bp = hb + (long)(d / 3) * 8320 + (d % 3) * 64 + (kc & 1) * 32 + quad * 8;
      short8 bv = *(const short8*)bp;
      acc[bf] = __builtin_amdgcn_mfma_f32_16x16x32_bf16(afr[kc], bv, acc[bf], 0, 0, 0);
    }
  }

  const int p = quad >> 1, q = quad & 1;
  float b0 = bf_[0], b1 = bf_[1], b2 = bf_[2];
  #pragma unroll
  for (int bf = 0; bf < 4; ++bf) {
    int n = base + bf * 16 + ln;
    int xx = n & 127, y = (n >> 7) & 127, b = n >> 14;
    long ob = (long)b * 196608 + (long)(2 * y + p) * 256 + (2 * xx + q);
    float v0 = acc[bf][0] + b0, v1 = acc[bf][1] + b1, v2 = acc[bf][2] + b2;
    out[ob]          = 1.f / (1.f + expf(-v0));
    out[ob + 65536]  = 1.f / (1.f + expf(-v1));
    out[ob + 131072] = 1.f / (1.f + expf(-v2));
  }
}

// ------------------------------------------------------------------ launch
extern "C" void kernel_launch(void* const* d_in, const int* in_sizes, int n_in,
                              void* d_out, int out_size, void* d_ws, size_t ws_size,
                              hipStream_t stream) {
  float* out = (float*)d_out;
  char* base = (char*)d_ws;
  size_t off = 0;
  auto alloc = [&](size_t bytes) {
    void* pp = base + off;
    off = (off + bytes + 255) & ~(size_t)255;
    return pp;
  };

  int* flag = (int*)alloc(256);
  float* biasAll = (float*)alloc(515 * 4);
  float* beB1f = biasAll + 0;
  float* beB2f = biasAll + 64;
  float* beTf  = biasAll + 192;
  float* bdTf  = biasAll + 320;
  float* bd1f  = biasAll + 448;
  float* bd2f  = biasAll + 512;
  float* sqAll = (float*)alloc(1024 * 4);
  float* sqT = sqAll, *sqB = sqAll + 512;
  float* pTop = (float*)alloc(256 * 4);
  float* pBot = (float*)alloc(256 * 4);
  bf16* Wc1  = (bf16*)alloc((size_t)4096 * 2);
  bf16* Wt2f = (bf16*)alloc((size_t)131072 * 2);
  bf16* Wttf = (bf16*)alloc((size_t)262144 * 2);
  bf16* Wdtf = (bf16*)alloc((size_t)262144 * 2);
  bf16* Wd1f = (bf16*)alloc((size_t)262144 * 2);
  bf16* Wfin = (bf16*)alloc((size_t)9216 * 2);
  bf16* embTB = (bf16*)alloc((size_t)131072 * 2);
  bf16* embT = embTB, *embB = embTB + 65536;
  bf16* act1p = (bf16*)alloc((size_t)17305600 * 2);  // [16][130][2][65][64] parity
  bf16* zbp   = (bf16*)alloc((size_t)8921088 * 2);   // [16][66][2][33][128] parity
  bf16* zqtp  = (bf16*)alloc((size_t)2367488 * 2);   // [16][34][34][128]
  bf16* eup   = (bf16*)alloc((size_t)8921088 * 2);   // [16][66][66][128]
  bf16* fqp   = (bf16*)alloc((size_t)8921088 * 2);   // [16][66][66][128]
  bf16* hp    = (bf16*)alloc((size_t)17305600 * 2);  // [16][130][130][64]
  bf16* ztp   = (bf16*)alloc((size_t)2097152 * 2);   // [16][32][32][128]

  detect_dtype_kernel<<<1, 256, 0, stream>>>(d_in[0], flag);
  // setupA: only what gemm1 + late tiny tables need (sq, bias, emb, Wc1, Wfin)
  setup_a<<<823, 256, 0, stream>>>(
      d_in[2], d_in[4], d_in[6], d_in[10], d_in[12], d_in[14],
      d_in[7], d_in[8], d_in[1], d_in[13],
      biasAll, embTB, sqAll, Wc1, Wfin, flag);

  // conv1 (2048 blocks) || heavy weight repacks + halo zeroing (5012 blocks)
  gemm1_plus<<<7060, 256, 0, stream>>>(
      d_in[0], flag, Wc1, beB1f, act1p,
      d_in[11], d_in[3], d_in[5], d_in[9],
      Wd1f, Wt2f, Wttf, Wdtf, hp, zbp, eup, fqp, zqtp);

  // conv2: LDS-staged + T14, 4 waves/block (co-quartered), 1024 x 256 thr
  conv2_lds<<<dim3(64, 1, 16), 256, 0, stream>>>(act1p, Wt2f, beB2f, zbp);

  // MERGED: conv_t (512 blocks) || VQ bottom (256 blocks, LDS codebook scan)
  convt_vqb<<<768, 256, 0, stream>>>(zbp, Wttf, beTf, ztp,
                                     zbp + 8448, embB, sqB, fqp + 8576, pBot);

  // VQ top (16384 positions, row-major): 16 pos/wave -> 256 blocks
  vq_mfma16<<<256, 256, 0, stream>>>(ztp, 131072, 4096, embT, sqT,
                                     zqtp + 4480, 147968, 4352, pTop, 5, 10);

  // decoder_top upsample: 4 classes in one launch (row-major in/out)
  mfma_conv<128, 128, 32, 1, 4, 128, 2, 0><<<dim3(64, 2, 16), 256, 0, stream>>>(
      zqtp, zqtp, 147968, 4352, Wdtf, bdTf, eup, 557568, 16896, 256, 4, 8448, 128, 0);

  // decoder conv d1: 8-wave blocks, wave=(class,row), 512 blocks x 512 thr
  mfma_d1_lds<<<dim3(32, 1, 16), 512, 0, stream>>>(fqp, eup, Wd1f, bd1f, hp);

  // final convT + sigmoid (1024 blocks) + loss finalize (block 1024)
  final_convt_mfma<<<1025, 256, 0, stream>>>(hp, Wfin, bd2f, out, pTop, pBot);
}